// Round 5
// baseline (290.365 us; speedup 1.0000x reference)
//
#include <hip/hip_runtime.h>
#include <hip/hip_bf16.h>
#include <math.h>

// Problem constants (setup_inputs)
#define BQ   2
#define LQ   4096
#define CQ   1024
#define NHQ  16
#define DHQ  64
#define KSEL 1638
#define KPAD 1664
#define MTOT (BQ*KSEL)   // 3276
#define MPAD 3328        // 26*128

typedef short s16x8 __attribute__((ext_vector_type(8)));
typedef float fx4   __attribute__((ext_vector_type(4)));

#define MFMA16(a,b,c) __builtin_amdgcn_mfma_f32_16x16x32_bf16(a,b,c,0,0,0)

__device__ __forceinline__ float b2f(unsigned short u) {
  union { float f; unsigned int i; } cv; cv.i = ((unsigned int)u) << 16; return cv.f;
}
__device__ __forceinline__ unsigned short f2b(float f) {
  union { float f; unsigned int i; } cv; cv.f = f;
  unsigned int x = cv.i;
  return (unsigned short)((x + 0x7fffu + ((x >> 16) & 1u)) >> 16);
}
__device__ __forceinline__ unsigned int fbits(float f) {
  union { float f; unsigned int i; } cv; cv.f = f; return cv.i;
}
// packed f32x2 -> bf16x2 (RNE), single VALU op
__device__ __forceinline__ unsigned int cvtpk_bf16(float a, float b) {
  unsigned int r;
  asm("v_cvt_pk_bf16_f32 %0, %1, %2" : "=v"(r) : "v"(a), "v"(b));
  return r;
}
__device__ __forceinline__ void async16(const void* g, void* l) {
  __builtin_amdgcn_global_load_lds((const __attribute__((address_space(1))) void*)g,
                                   (__attribute__((address_space(3))) void*)l, 16, 0, 0);
}
// raw 2^x (q is pre-scaled by log2(e) in k_normrope, M is in log2 units)
__device__ __forceinline__ float fexp2(float x) {
#if __has_builtin(__builtin_amdgcn_exp2f)
  return __builtin_amdgcn_exp2f(x);
#else
  return __expf(x * 0.69314718055994531f);
#endif
}

// ---------------- mean (fp64, 2-stage) ----------------
__global__ __launch_bounds__(256) void k_mean_part(const float* __restrict__ x,
                                                   double* __restrict__ part) {
  int bid = blockIdx.x;                    // 256 blocks: [b(2)][ch(32)][cb(4)]
  int cb = bid & 3, ch = (bid >> 2) & 31, b = bid >> 7;
  int c = cb * 256 + threadIdx.x;
  const float* p = x + ((size_t)b * LQ + (size_t)ch * 128) * CQ + c;
  double s = 0.0;
  for (int r = 0; r < 128; ++r) s += (double)p[(size_t)r * CQ];
  part[((size_t)b * 32 + ch) * CQ + c] = s;
}

__global__ __launch_bounds__(256) void k_mean_reduce(const double* __restrict__ part,
                                                     double* __restrict__ mean) {
  int g = blockIdx.x * 256 + threadIdx.x;  // 2048 = B*C
  int b = g >> 10, c = g & 1023;
  double s = 0.0;
  for (int ch = 0; ch < 32; ++ch) s += part[((size_t)b * 32 + ch) * CQ + c];
  mean[g] = s * (1.0 / 4096.0);
}

// ---------------- mse (fp64) + base output (x + upsample(cached)) + x->bf16 ----------------
__global__ __launch_bounds__(256) void k_mse_base(const float* __restrict__ x,
                                                  const float* __restrict__ cached,
                                                  const double* __restrict__ mean,
                                                  double* __restrict__ mse,
                                                  float* __restrict__ out,
                                                  unsigned short* __restrict__ xb) {
  int bl = blockIdx.x; int b = bl >> 12, l = bl & 4095;
  int hh = l >> 6, ww = l & 63;
  size_t xoff = ((size_t)b * LQ + l) * CQ;
  size_t uoff = (((size_t)b * 32 + (hh >> 1)) * 32 + (ww >> 1)) * CQ;
  const double* mrow = mean + (size_t)b * CQ;
  int c0 = threadIdx.x * 4;
  float4 xv = *(const float4*)(x + xoff + c0);
  float4 uv = *(const float4*)(cached + uoff + c0);
  float4 ov;
  ov.x = xv.x + uv.x; ov.y = xv.y + uv.y; ov.z = xv.z + uv.z; ov.w = xv.w + uv.w;
  *(float4*)(out + xoff + c0) = ov;
  ushort4 xo;
  xo.x = f2b(xv.x); xo.y = f2b(xv.y); xo.z = f2b(xv.z); xo.w = f2b(xv.w);
  ((ushort4*)xb)[(xoff + c0) >> 2] = xo;
  double d0 = (double)xv.x - mrow[c0];
  double d1 = (double)xv.y - mrow[c0 + 1];
  double d2 = (double)xv.z - mrow[c0 + 2];
  double d3 = (double)xv.w - mrow[c0 + 3];
  double ss = d0 * d0 + d1 * d1 + d2 * d2 + d3 * d3;
  for (int o = 1; o < 64; o <<= 1) ss += __shfl_xor(ss, o);
  __shared__ double ws4[4];
  if ((threadIdx.x & 63) == 0) ws4[threadIdx.x >> 6] = ss;
  __syncthreads();
  if (threadIdx.x == 0) mse[(size_t)b * LQ + l] = ws4[0] + ws4[1] + ws4[2] + ws4[3];
}

// ---------------- top-k (blocks 0,1) + fused weight fp32->bf16 conversion (blocks >=2) ----
__global__ __launch_bounds__(1024) void k_topk(const double* __restrict__ mse,
                                               int* __restrict__ idx_sel,
                                               const float* __restrict__ wqkv,
                                               const float* __restrict__ wproj,
                                               unsigned short* __restrict__ wqb,
                                               unsigned short* __restrict__ wpb) {
  if (blockIdx.x >= 2) {   // conversion path: 1024 blocks x 1024 thr x 1 float4
    int i = (blockIdx.x - 2) * 1024 + threadIdx.x;
    const float* s; unsigned short* d; int off;
    if (i < 786432) { s = wqkv;  d = wqb; off = i; }
    else            { s = wproj; d = wpb; off = i - 786432; }
    float4 v = ((const float4*)s)[off];
    ushort4 o;
    o.x = f2b(v.x); o.y = f2b(v.y); o.z = f2b(v.z); o.w = f2b(v.w);
    ((ushort4*)d)[off] = o;
    return;
  }
  __shared__ unsigned long long u[4096];       // 32 KB
  __shared__ unsigned int whist[16 * 257];     // 16.4 KB, stride 257 => cross-wave bank skew
  __shared__ unsigned int wtot[4];
  __shared__ unsigned long long sh_prefix;
  __shared__ int sh_rem, sh_rem2, sh_bsel, sh_cnt, sh_eqcnt;
  __shared__ int eqbuf[256];
  int b = blockIdx.x, t = threadIdx.x;
  int wv = t >> 6, laneid = t & 63;
  for (int p = 0; p < 4; ++p) {
    int i = p * 1024 + t;
    u[i] = (unsigned long long)__double_as_longlong(mse[(size_t)b * LQ + i]);
  }
  if (t == 0) { sh_prefix = 0ULL; sh_rem = KSEL; sh_cnt = 0; sh_eqcnt = 0; }
  __syncthreads();
  for (int shift = 56; shift >= 0; shift -= 8) {
    for (int z = t; z < 16 * 257; z += 1024) whist[z] = 0u;
    __syncthreads();
    unsigned long long pref = sh_prefix;
#pragma unroll
    for (int p = 0; p < 4; ++p) {
      int i = p * 1024 + t;
      unsigned long long v = u[i];
      bool cand = (shift == 56) || ((v >> ((shift + 8) & 63)) == pref);
      if (cand) atomicAdd(&whist[wv * 257 + ((unsigned int)(v >> shift) & 255u)], 1u);
    }
    __syncthreads();
    unsigned int myc = 0, mysc = 0;
    if (t < 256) {            // combine the 16 wave hists for my bin (bin = 255 - t)
      unsigned int s = 0;
      int bin = 255 - t;
#pragma unroll
      for (int wvi = 0; wvi < 16; ++wvi) s += whist[wvi * 257 + bin];
      myc = s;
      mysc = myc;
#pragma unroll
      for (int o = 1; o < 64; o <<= 1) {
        unsigned int v2 = __shfl_up(mysc, o);
        if (laneid >= o) mysc += v2;
      }
      if (laneid == 63) wtot[wv] = mysc;
    }
    __syncthreads();
    if (t < 256) {
      unsigned int basep = 0;
      for (int wvi = 0; wvi < wv; ++wvi) basep += wtot[wvi];
      unsigned int incl = basep + mysc;       // count of keys in bins >= my bin
      unsigned int excl = incl - myc;         // count of keys in bins >  my bin
      unsigned int rem = (unsigned int)sh_rem;
      if (excl < rem && rem <= incl) {        // exactly one thread crosses
        sh_bsel = 255 - t;
        sh_rem2 = (int)(rem - excl);
      }
    }
    __syncthreads();
    if (t == 0) {
      sh_prefix = (sh_prefix << 8) | (unsigned long long)sh_bsel;
      sh_rem = sh_rem2;
    }
    __syncthreads();
  }
  unsigned long long T = sh_prefix;
  int rem_eq = sh_rem;
#pragma unroll
  for (int p = 0; p < 4; ++p) {
    int i = p * 1024 + t;
    unsigned long long v = u[i];
    bool win = (v > T);
    unsigned long long mask = __ballot(win);
    int total = __popcll(mask);
    int base = 0;
    if (laneid == 0 && total > 0) base = atomicAdd(&sh_cnt, total);
    base = __shfl(base, 0);
    if (win) {
      int lpos = __popcll(mask & ((1ULL << laneid) - 1ULL));
      idx_sel[b * KPAD + base + lpos] = i;
    }
    if (v == T) {
      int e = atomicAdd(&sh_eqcnt, 1);
      if (e < 256) eqbuf[e] = i;
    }
  }
  __syncthreads();
  if (t == 0) {
    int n = sh_eqcnt; if (n > 256) n = 256;
    for (int a = 1; a < n; ++a) {           // ascending index sort (ties: smallest index wins)
      int key = eqbuf[a]; int c = a - 1;
      while (c >= 0 && eqbuf[c] > key) { eqbuf[c + 1] = eqbuf[c]; --c; }
      eqbuf[c + 1] = key;
    }
    int base = sh_cnt;
    for (int a = 0; a < rem_eq && a < n; ++a) idx_sel[b * KPAD + base + a] = eqbuf[a];
    for (int a = KSEL; a < KPAD; ++a) idx_sel[b * KPAD + a] = 0;
  }
}

// ---------------- qkv GEMM (128x128, BK=32) with depth-2 prefetch (3 LDS buffers) ----------
__global__ __launch_bounds__(256) void k_gemmA(const unsigned short* __restrict__ Asrc,
                                               const unsigned short* __restrict__ Bmat,
                                               const int* __restrict__ idx_sel,
                                               unsigned short* __restrict__ Cbf) {
  int bm = blockIdx.x % 26, bn = blockIdx.x / 26;
  int tid = threadIdx.x;
  int w = tid >> 6, lane = tid & 63, quad = lane >> 4, l15 = lane & 15;
  int wm = w & 1, wn = w >> 1;
  __shared__ __align__(16) unsigned char sm[3][16384];   // A [128][32]bf16, B [128][32]bf16

  const unsigned short* gA[2];
  const unsigned short* gB[2];
#pragma unroll
  for (int p = 0; p < 2; ++p) {
    int e = p * 256 + tid; int row = e >> 2, kc = e & 3;
    int m = bm * 128 + row; if (m >= MTOT) m = MTOT - 1;
    int bb = m / KSEL; int ii = m - bb * KSEL;
    int lsel = idx_sel[bb * KPAD + ii];
    gA[p] = Asrc + ((size_t)bb * LQ + lsel) * CQ + kc * 8;
    gB[p] = Bmat + (size_t)(bn * 128 + row) * CQ + kc * 8;
  }

  fx4 acc[4][4];
#pragma unroll
  for (int a = 0; a < 4; ++a)
#pragma unroll
    for (int c = 0; c < 4; ++c) acc[a][c] = (fx4){0.f, 0.f, 0.f, 0.f};

#define STAGE_A(boff, it) do { int ke = (it) * 32;                                  \
    _Pragma("unroll")                                                               \
    for (int p = 0; p < 2; ++p) {                                                   \
      async16(gA[p] + ke, sm[0] + (boff) + p * 4096 + w * 1024);                    \
      async16(gB[p] + ke, sm[0] + (boff) + 8192 + p * 4096 + w * 1024);             \
    } } while (0)

  STAGE_A(0, 0);
  STAGE_A(16384, 1);
  for (int it = 0; it < 32; ++it) {
    int cur = it % 3;
    if (it + 2 < 32) STAGE_A(((it + 2) % 3) * 16384, it + 2);
    if (it <= 29)      asm volatile("s_waitcnt vmcnt(8)");
    else if (it == 30) asm volatile("s_waitcnt vmcnt(4)");
    else               asm volatile("s_waitcnt vmcnt(0)");
    __builtin_amdgcn_s_barrier();
    const unsigned char* smb = sm[0] + cur * 16384;
    s16x8 af[4], bf[4];
#pragma unroll
    for (int mt = 0; mt < 4; ++mt)
      af[mt] = *(const s16x8*)(smb + ((wm * 64 + mt * 16 + l15) * 64 + quad * 16));
#pragma unroll
    for (int nt = 0; nt < 4; ++nt)
      bf[nt] = *(const s16x8*)(smb + 8192 + ((wn * 64 + nt * 16 + l15) * 64 + quad * 16));
    __builtin_amdgcn_s_setprio(1);
#pragma unroll
    for (int mt = 0; mt < 4; ++mt)
#pragma unroll
      for (int nt = 0; nt < 4; ++nt)
        acc[mt][nt] = MFMA16(af[mt], bf[nt], acc[mt][nt]);
    __builtin_amdgcn_s_setprio(0);
    __builtin_amdgcn_s_barrier();    // all waves done reading cur before it's re-staged
  }
#undef STAGE_A

#pragma unroll
  for (int mt = 0; mt < 4; ++mt)
#pragma unroll
    for (int nt = 0; nt < 4; ++nt) {
      int n = bn * 128 + wn * 64 + nt * 16 + l15;
      int mbase = bm * 128 + wm * 64 + mt * 16 + quad * 4;
      fx4 vv = acc[mt][nt];
#pragma unroll
      for (int r = 0; r < 4; ++r) {
        int m = mbase + r;
        if (m < MTOT) Cbf[(size_t)m * 3072 + n] = f2b(vv[r]);
      }
    }
}

// ---------------- proj GEMM (64x64, BK=64) : 832 blocks, dbuf prefetch ----------------
__global__ __launch_bounds__(256) void k_gemmB(const unsigned short* __restrict__ Asrc,
                                               const unsigned short* __restrict__ Bmat,
                                               const int* __restrict__ idx_sel,
                                               float* __restrict__ Cf,
                                               const float* __restrict__ xin,
                                               const float* __restrict__ bproj) {
  int bid = blockIdx.x;
  int swz = (bid & 7) * 104 + (bid >> 3);   // XCD-contiguous chunks (832 = 8*104)
  int bm = swz % 52, bn = swz / 52;
  int tid = threadIdx.x;
  int w = tid >> 6, lane = tid & 63, quad = lane >> 4, l15 = lane & 15;
  int wm = w & 1, wn = w >> 1;
  __shared__ __align__(16) unsigned char sm[2][16384];   // A [64][64]bf16, B [64][64]bf16

  const unsigned short* g4[4];
#pragma unroll
  for (int p = 0; p < 4; ++p) {
    int e = (p & 1) * 256 + tid; int row = e >> 3, kc = e & 7;
    if (p < 2) {
      int m = bm * 64 + row; if (m >= MTOT) m = MTOT - 1;
      int bb = m / KSEL; int ii = m - bb * KSEL;
      g4[p] = Asrc + ((size_t)bb * KPAD + ii) * CQ + kc * 8;
    } else {
      g4[p] = Bmat + (size_t)(bn * 64 + row) * CQ + kc * 8;
    }
  }

  fx4 acc[2][2];
#pragma unroll
  for (int a = 0; a < 2; ++a)
#pragma unroll
    for (int c = 0; c < 2; ++c) acc[a][c] = (fx4){0.f, 0.f, 0.f, 0.f};

#define STAGE_B(buf, it) do { int ke = (it) * 64;                                   \
    _Pragma("unroll")                                                               \
    for (int p = 0; p < 4; ++p)                                                     \
      async16(g4[p] + ke, sm[buf] + p * 4096 + w * 1024);                           \
    } while (0)

  STAGE_B(0, 0);
  for (int it = 0; it < 16; ++it) {
    int cur = it & 1;
    if (it < 15) STAGE_B(cur ^ 1, it + 1);
    if (it < 15) asm volatile("s_waitcnt vmcnt(4)");
    else         asm volatile("s_waitcnt vmcnt(0)");
    __builtin_amdgcn_s_barrier();
    const unsigned char* smb = sm[cur];
#pragma unroll
    for (int kk = 0; kk < 2; ++kk) {
      s16x8 af[2], bf2[2];
#pragma unroll
      for (int mt = 0; mt < 2; ++mt)
        af[mt] = *(const s16x8*)(smb + ((wm * 32 + mt * 16 + l15) * 64 + kk * 32 + quad * 8) * 2);
#pragma unroll
      for (int nt = 0; nt < 2; ++nt)
        bf2[nt] = *(const s16x8*)(smb + 8192 + ((wn * 32 + nt * 16 + l15) * 64 + kk * 32 + quad * 8) * 2);
#pragma unroll
      for (int mt = 0; mt < 2; ++mt)
#pragma unroll
        for (int nt = 0; nt < 2; ++nt)
          acc[mt][nt] = MFMA16(af[mt], bf2[nt], acc[mt][nt]);
    }
    __builtin_amdgcn_s_barrier();    // all waves done reading cur before it's re-staged
  }
#undef STAGE_B

#pragma unroll
  for (int mt = 0; mt < 2; ++mt)
#pragma unroll
    for (int nt = 0; nt < 2; ++nt) {
      int n = bn * 64 + wn * 32 + nt * 16 + l15;
      int mbase = bm * 64 + wm * 32 + mt * 16 + quad * 4;
      fx4 vv = acc[mt][nt];
      float bp = bproj[n];
#pragma unroll
      for (int r = 0; r < 4; ++r) {
        int m = mbase + r;
        if (m < MTOT) {
          int bb = m / KSEL; int ii = m - bb * KSEL;
          int lsel = idx_sel[bb * KPAD + ii];
          size_t off = ((size_t)bb * LQ + lsel) * CQ + n;
          Cf[off] = xin[off] + vv[r] + bp;
        }
      }
    }
}

// ---------------- l2norm + scale + rope -> q,k ; v -> Vt (transposed) ----------------
__global__ __launch_bounds__(256) void k_normrope(const unsigned short* __restrict__ qkv,
                                                  const int* __restrict__ idx_sel,
                                                  const float* __restrict__ qbias,
                                                  const float* __restrict__ vbias,
                                                  const float* __restrict__ sml,
                                                  const float* __restrict__ rope,
                                                  unsigned short* __restrict__ qo,
                                                  unsigned short* __restrict__ ko,
                                                  unsigned short* __restrict__ vt) {
  int bid = blockIdx.x;                       // 26*16*2
  int tile = bid % 26; int h = (bid / 26) & 15; int b = bid / (26 * 16);
  int tid = threadIdx.x; int w = tid >> 6; int d = tid & 63;
  __shared__ unsigned short vtile[64 * 68];
  float scale = expf(fminf(sml[h], 4.6051702f)) * 1.4426950408889634f;
  float qb = qbias[h * 64 + d];
  float vb = vbias[h * 64 + d];
  for (int pass = 0; pass < 16; ++pass) {
    int il = pass * 4 + w;
    int i = tile * 64 + il;
    float vraw = 0.f;
    if (i < KSEL) {
      int lsel = idx_sel[b * KPAD + i];
      size_t base = ((size_t)(b * KSEL + i)) * 3072 + h * 64 + d;
      int tt = d >> 1;
      float r0 = rope[(size_t)lsel * 32 + tt];
      float r1 = rope[(size_t)LQ * 32 + (size_t)lsel * 32 + tt];
      // q
      float qv = b2f(qkv[base]) + qb;
      float ss = qv * qv;
      for (int o = 1; o < 64; o <<= 1) ss += __shfl_xor(ss, o);
      float qn = qv / fmaxf(sqrtf(ss), 1e-12f) * scale;
      float qp = __shfl_xor(qn, 1);
      float qr = (d & 1) ? (r1 * qp + r0 * qn) : (r0 * qn - r1 * qp);
      qo[((size_t)(b * NHQ + h) * KPAD + i) * 64 + d] = f2b(qr);
      // k
      float kv = b2f(qkv[base + 1024]);
      float ks = kv * kv;
      for (int o = 1; o < 64; o <<= 1) ks += __shfl_xor(ks, o);
      float kn = kv / fmaxf(sqrtf(ks), 1e-12f);
      float kp = __shfl_xor(kn, 1);
      float kr = (d & 1) ? (r1 * kp + r0 * kn) : (r0 * kn - r1 * kp);
      ko[((size_t)(b * NHQ + h) * KPAD + i) * 64 + d] = f2b(kr);
      vraw = b2f(qkv[base + 2048]) + vb;
    }
    vtile[d * 68 + il] = f2b(vraw);
  }
  __syncthreads();
  int row = tid >> 2, c0 = (tid & 3) * 16;
  s16x8 o0, o1;
#pragma unroll
  for (int jj = 0; jj < 8; ++jj) {
    o0[jj] = (short)vtile[row * 68 + c0 + jj];
    o1[jj] = (short)vtile[row * 68 + c0 + 8 + jj];
  }
  size_t doff = ((size_t)((b * NHQ + h) * 64 + row)) * KPAD + (size_t)tile * 64 + c0;
  *(s16x8*)(vt + doff) = o0;
  *(s16x8*)(vt + doff + 8) = o1;
}

// ---------------- flash attention ----------------
// R11: TLP attack. (1) P buffer halved: write/consume P in two js-halves of 32 j
// (Pq [4][32*40] = 10240 B) -> LDS 28672 -> 5 blocks/CU (was 4). (2) z=4 part
// split (1664 blocks, tiles 7/7/6/6) so the grid feeds 5 residents. VGPR must
// stay <=64 (occupancy quantum) -> __launch_bounds__(256,8) enforces it.
__global__ __launch_bounds__(256, 8) void k_attn(const unsigned short* __restrict__ qb,
                                                 const unsigned short* __restrict__ kb,
                                                 const unsigned short* __restrict__ vtb,
                                                 const float* __restrict__ sml,
                                                 unsigned short* __restrict__ pO,
                                                 float* __restrict__ pl) {
  int qt = blockIdx.x; int bh = blockIdx.y; int part = blockIdx.z;
  int b = bh >> 4, h = bh & 15;
  int t0, t1;
  if (part < 2) { t0 = part * 7; t1 = t0 + 7; }
  else          { t0 = 14 + (part - 2) * 6; t1 = t0 + 6; }
  int q0 = qt * 128;
  int tid = threadIdx.x, w = tid >> 6, lane = tid & 63, quad = lane >> 4, l15 = lane & 15;
  float M = __expf(fminf(sml[h], 4.6051702f)) * 1.4426950408889634f;  // log2-domain shift
  __shared__ __align__(16) unsigned short Kt[64 * 72];     //  9216 B
  __shared__ __align__(16) unsigned short Vt[64 * 72];     //  9216 B
  __shared__ __align__(16) unsigned short Pq[4][32 * 40];  // 10240 B (total 28672 -> 5 blk/CU)
  unsigned short* Pw = Pq[w];
  const unsigned short* qbase = qb + (size_t)(b * NHQ + h) * KPAD * 64;
  const unsigned short* kbase = kb + (size_t)(b * NHQ + h) * KPAD * 64;
  const unsigned short* vbase = vtb + (size_t)(b * NHQ + h) * 64 * KPAD;

  // staging geometry: 512 s16x8 chunks per K (and V) tile, 2 per thread
  int r0 = tid >> 3, c0 = tid & 7;            // chunk 0: rows 0..31
  int r1 = 32 + r0, c1 = c0;                  // chunk 1: rows 32..63

  // Q as B-operand: n=l15 -> q row; k = kb2*32 + quad*8
  s16x8 qf[2][2];
#pragma unroll
  for (int qtile = 0; qtile < 2; ++qtile)
#pragma unroll
    for (int kb2 = 0; kb2 < 2; ++kb2) {
      int row = q0 + w * 32 + qtile * 16 + l15;
      qf[qtile][kb2] = *(const s16x8*)(qbase + (size_t)row * 64 + kb2 * 32 + quad * 8);
    }

  float lsum[2] = {0.f, 0.f};
  fx4 oacc[2][4];
#pragma unroll
  for (int qtile = 0; qtile < 2; ++qtile)
#pragma unroll
    for (int dt = 0; dt < 4; ++dt) oacc[qtile][dt] = (fx4){0.f, 0.f, 0.f, 0.f};

  // prologue: issue tile t0's loads (T14 async-STAGE split)
  s16x8 kn0, kn1, vn0, vn1;
  {
    int j0 = t0 * 64;
    kn0 = *(const s16x8*)(kbase + (size_t)(j0 + r0) * 64 + c0 * 8);
    kn1 = *(const s16x8*)(kbase + (size_t)(j0 + r1) * 64 + c1 * 8);
    vn0 = *(const s16x8*)(vbase + (size_t)r0 * KPAD + j0 + c0 * 8);
    vn1 = *(const s16x8*)(vbase + (size_t)r1 * KPAD + j0 + c1 * 8);
  }

  for (int t = t0; t < t1; ++t) {
    int j0 = t * 64;
    bool tail = (j0 + 64 > KSEL);
    __builtin_amdgcn_s_barrier();    // all waves done reading prev Kt/Vt
    *(s16x8*)(Kt + r0 * 72 + c0 * 8) = kn0;
    *(s16x8*)(Kt + r1 * 72 + c1 * 8) = kn1;
    *(s16x8*)(Vt + r0 * 72 + c0 * 8) = vn0;
    *(s16x8*)(Vt + r1 * 72 + c1 * 8) = vn1;
    // issue next tile's loads; they stay in flight under this tile's compute
    if (t + 1 < t1) {
      int jn = (t + 1) * 64;
      kn0 = *(const s16x8*)(kbase + (size_t)(jn + r0) * 64 + c0 * 8);
      kn1 = *(const s16x8*)(kbase + (size_t)(jn + r1) * 64 + c1 * 8);
      vn0 = *(const s16x8*)(vbase + (size_t)r0 * KPAD + jn + c0 * 8);
      vn1 = *(const s16x8*)(vbase + (size_t)r1 * KPAD + jn + c1 * 8);
    }
    asm volatile("s_waitcnt lgkmcnt(0)" ::: "memory");   // ds_writes visible
    __builtin_amdgcn_s_barrier();

    // S^T (full K=64)
    fx4 sacc[2][4];
#pragma unroll
    for (int qtile = 0; qtile < 2; ++qtile)
#pragma unroll
      for (int jj = 0; jj < 4; ++jj) sacc[qtile][jj] = (fx4){0.f, 0.f, 0.f, 0.f};
    __builtin_amdgcn_s_setprio(1);
#pragma unroll
    for (int jj = 0; jj < 4; ++jj) {
      int jl = jj * 16 + l15;
      s16x8 kf0 = *(const s16x8*)(Kt + jl * 72 + quad * 8);
      s16x8 kf1 = *(const s16x8*)(Kt + jl * 72 + 32 + quad * 8);
      sacc[0][jj] = MFMA16(kf0, qf[0][0], sacc[0][jj]);
      sacc[1][jj] = MFMA16(kf0, qf[1][0], sacc[1][jj]);
      sacc[0][jj] = MFMA16(kf1, qf[0][1], sacc[0][jj]);
      sacc[1][jj] = MFMA16(kf1, qf[1][1], sacc[1][jj]);
    }
    __builtin_amdgcn_s_setprio(0);

    // two js-halves: exp+pack+write 32 j -> PV on that half (Pw holds 32 j)
#pragma unroll
    for (int js = 0; js < 2; ++js) {
#pragma unroll
      for (int qtile = 0; qtile < 2; ++qtile)
#pragma unroll
        for (int jg = 0; jg < 2; ++jg) {
          int jj = js * 2 + jg;
          int jbase = j0 + jj * 16 + quad * 4;
          fx4 sv = sacc[qtile][jj];
          float p0 = fexp2(sv[0] - M);
          float p1 = fexp2(sv[1] - M);
          float p2 = fexp2(sv[2] - M);
          float p3 = fexp2(sv[3] - M);
          if (tail) {
            if (jbase + 0 >= KSEL) p0 = 0.f;
            if (jbase + 1 >= KSEL) p1 = 0.f;
            if (jbase + 2 >= KSEL) p2 = 0.f;
            if (jbase + 3 >= KSEL) p3 = 0.f;
          }
          lsum[qtile] += (p0 + p1) + (p2 + p3);
          *(uint2*)(Pw + (qtile * 16 + l15) * 40 + jg * 16 + quad * 4) =
              make_uint2(cvtpk_bf16(p0, p1), cvtpk_bf16(p2, p3));
        }
      // PV half: A=P (wave-private LDS), B=V (LDS)
      __builtin_amdgcn_s_setprio(1);
      {
        s16x8 pf0 = *(const s16x8*)(Pw + l15 * 40 + quad * 8);
        s16x8 pf1 = *(const s16x8*)(Pw + (16 + l15) * 40 + quad * 8);
#pragma unroll
        for (int dt = 0; dt < 4; ++dt) {
          s16x8 vf = *(const s16x8*)(Vt + (dt * 16 + l15) * 72 + js * 32 + quad * 8);
          oacc[0][dt] = MFMA16(pf0, vf, oacc[0][dt]);
          oacc[1][dt] = MFMA16(pf1, vf, oacc[1][dt]);
        }
      }
      __builtin_amdgcn_s_setprio(0);
    }
  }

  // combine quad-partitioned j-sums (lanes l15, +16, +32, +48 hold disjoint j sets)
#pragma unroll
  for (int qtile = 0; qtile < 2; ++qtile) {
    float s = lsum[qtile];
    s += __shfl_xor(s, 16);
    s += __shfl_xor(s, 32);
    lsum[qtile] = s;
  }

  size_t pbase = (((size_t)part * 2 + b) * NHQ + h) * KPAD;
#pragma unroll
  for (int qtile = 0; qtile < 2; ++qtile) {
    int gqb = q0 + w * 32 + qtile * 16;
    if (quad == 0) pl[pbase + gqb + l15] = lsum[qtile];
  }

  // transpose O through the wave-private P buffer (two 32-col halves) -> coalesced stores
#pragma unroll
  for (int half = 0; half < 2; ++half) {
    __builtin_amdgcn_s_barrier();   // reuse: waves in lockstep here anyway (cheap)
#pragma unroll
    for (int qtile = 0; qtile < 2; ++qtile)
#pragma unroll
      for (int dt = 0; dt < 2; ++dt)
#pragma unroll
        for (int r = 0; r < 4; ++r)
          Pw[(qtile * 16 + quad * 4 + r) * 40 + dt * 16 + l15] =
              f2b(oacc[qtile][half * 2 + dt][r]);
    asm volatile("s_waitcnt lgkmcnt(0)" ::: "memory");
#pragma unroll
    for (int pass = 0; pass < 2; ++pass) {
      int row = pass * 16 + (lane >> 2), chunk = lane & 3;
      s16x8 vv = *(const s16x8*)(Pw + row * 40 + chunk * 8);
      *(s16x8*)(pO + (pbase + q0 + w * 32 + row) * 64 + half * 32 + chunk * 8) = vv;
    }
  }
}

// ---------------- combine the four j-parts: o = sum(O_p)/sum(l_p) -> ob (bf16) -------------
__global__ __launch_bounds__(256) void k_comb(const unsigned short* __restrict__ pO,
                                              const float* __restrict__ pl,
                                              unsigned short* __restrict__ ob) {
  size_t g = (size_t)blockIdx.x * 256 + threadIdx.x;   // 2*16*1664*64 = 3407872
  int d = (int)(g & 63);
  size_t row = g >> 6;              // (b*16+h)*1664 + gq
  int gq = (int)(row % KPAD);
  int bhh = (int)(row / KPAD);
  int b = bhh >> 4, h = bhh & 15;
  float osum = 0.f, lsumv = 0.f;
#pragma unroll
  for (int p = 0; p < 4; ++p) {
    osum += b2f(pO[g + (size_t)p * 3407872]);
    lsumv += pl[row + (size_t)p * 53248];
  }
  float o = osum / lsumv;
  ob[((size_t)(b * KPAD + gq)) * CQ + h * 64 + d] = f2b(o);
}

extern "C" void kernel_launch(void* const* d_in, const int* in_sizes, int n_in,
                              void* d_out, int out_size, void* d_ws, size_t ws_size,
                              hipStream_t stream) {
  const float* x      = (const float*)d_in[0];
  const float* cached = (const float*)d_in[1];
  const float* wqkv   = (const float*)d_in[2];
  const float* qbias  = (const float*)d_in[3];
  const float* vbias  = (const float*)d_in[4];
  const float* wproj  = (const float*)d_in[5];
  const float* bproj  = (const float*)d_in[6];
  const float* sml    = (const float*)d_in[7];
  const float* rope   = (const float*)d_in[8];
  float* out = (float*)d_out;
  char* ws = (char*)d_ws;

  double* meanpart        = (double*)(ws);                    // 524288
  double* mean            = (double*)(ws + 524288);           // 16384
  double* mse             = (double*)(ws + 540672);           // 65536
  int* idx_sel            = (int*)(ws + 606208);              // 13312 -> 619520
  // overlap zone [619520, 44135424): x_bf + wqkv_bf + qkv (dead after k_normrope)
  unsigned short* x_bf    = (unsigned short*)(ws + 619520);   // 16777216
  unsigned short* wqkv_bf = (unsigned short*)(ws + 17396736); // 6291456
  unsigned short* qkv     = (unsigned short*)(ws + 23688192); // 20447232 -> 44135424
  // attn partials (4 parts) reuse the dead x_bf/wqkv_bf/qkv region
  unsigned short* pO      = (unsigned short*)(ws + 619520);   // 27262976
  float* pl               = (float*)(ws + 27882496);          // 851968 -> 28734464
  unsigned short* wproj_bf= (unsigned short*)(ws + 44135424); // 2097152
  unsigned short* qo      = (unsigned short*)(ws + 46232576); // 6815744
  unsigned short* ko      = (unsigned short*)(ws + 53048320); // 6815744
  unsigned short* vt      = (unsigned short*)(ws + 59864064); // 6815744
  unsigned short* ob      = (unsigned short*)(ws + 66679808); // 6815744 -> 73495552

  hipLaunchKernelGGL(k_mean_part, dim3(256), dim3(256), 0, stream, x, meanpart);
  hipLaunchKernelGGL(k_mean_reduce, dim3(8), dim3(256), 0, stream, meanpart, mean);
  hipLaunchKernelGGL(k_mse_base, dim3(8192), dim3(256), 0, stream, x, cached, mean, mse,
                     out, x_bf);
  hipLaunchKernelGGL(k_topk, dim3(2 + 1024), dim3(1024), 0, stream, mse, idx_sel,
                     wqkv, wproj, wqkv_bf, wproj_bf);
  hipLaunchKernelGGL(k_gemmA, dim3(26 * 24), dim3(256), 0, stream,
                     x_bf, wqkv_bf, idx_sel, qkv);
  hipLaunchKernelGGL(k_normrope, dim3(26 * 16 * BQ), dim3(256), 0, stream,
                     qkv, idx_sel, qbias, vbias, sml, rope, qo, ko, vt);
  hipLaunchKernelGGL(k_attn, dim3(13, BQ * NHQ, 4), dim3(256), 0, stream,
                     qo, ko, vt, sml, pO, pl);
  hipLaunchKernelGGL(k_comb, dim3(13312), dim3(256), 0, stream, pO, pl, ob);
  hipLaunchKernelGGL(k_gemmB, dim3(832), dim3(256), 0, stream,
                     ob, wproj_bf, idx_sel, out, x, bproj);
}

// Round 6
// 279.479 us; speedup vs baseline: 1.0390x; 1.0390x over previous
//
#include <hip/hip_runtime.h>
#include <hip/hip_bf16.h>
#include <math.h>

// Problem constants (setup_inputs)
#define BQ   2
#define LQ   4096
#define CQ   1024
#define NHQ  16
#define DHQ  64
#define KSEL 1638
#define KPAD 1664
#define MTOT (BQ*KSEL)   // 3276
#define MPAD 3328        // 26*128

typedef short s16x8 __attribute__((ext_vector_type(8)));
typedef float fx4   __attribute__((ext_vector_type(4)));

#define MFMA16(a,b,c) __builtin_amdgcn_mfma_f32_16x16x32_bf16(a,b,c,0,0,0)

__device__ __forceinline__ float b2f(unsigned short u) {
  union { float f; unsigned int i; } cv; cv.i = ((unsigned int)u) << 16; return cv.f;
}
__device__ __forceinline__ unsigned short f2b(float f) {
  union { float f; unsigned int i; } cv; cv.f = f;
  unsigned int x = cv.i;
  return (unsigned short)((x + 0x7fffu + ((x >> 16) & 1u)) >> 16);
}
__device__ __forceinline__ unsigned int fbits(float f) {
  union { float f; unsigned int i; } cv; cv.f = f; return cv.i;
}
// packed f32x2 -> bf16x2 (RNE), single VALU op
__device__ __forceinline__ unsigned int cvtpk_bf16(float a, float b) {
  unsigned int r;
  asm("v_cvt_pk_bf16_f32 %0, %1, %2" : "=v"(r) : "v"(a), "v"(b));
  return r;
}
__device__ __forceinline__ void async16(const void* g, void* l) {
  __builtin_amdgcn_global_load_lds((const __attribute__((address_space(1))) void*)g,
                                   (__attribute__((address_space(3))) void*)l, 16, 0, 0);
}
// raw 2^x (q is pre-scaled by log2(e) in k_normrope, M is in log2 units)
__device__ __forceinline__ float fexp2(float x) {
#if __has_builtin(__builtin_amdgcn_exp2f)
  return __builtin_amdgcn_exp2f(x);
#else
  return __expf(x * 0.69314718055994531f);
#endif
}

// ---------------- mean (fp64, 2-stage) ----------------
__global__ __launch_bounds__(256) void k_mean_part(const float* __restrict__ x,
                                                   double* __restrict__ part) {
  int bid = blockIdx.x;                    // 256 blocks: [b(2)][ch(32)][cb(4)]
  int cb = bid & 3, ch = (bid >> 2) & 31, b = bid >> 7;
  int c = cb * 256 + threadIdx.x;
  const float* p = x + ((size_t)b * LQ + (size_t)ch * 128) * CQ + c;
  double s = 0.0;
  for (int r = 0; r < 128; ++r) s += (double)p[(size_t)r * CQ];
  part[((size_t)b * 32 + ch) * CQ + c] = s;
}

__global__ __launch_bounds__(256) void k_mean_reduce(const double* __restrict__ part,
                                                     double* __restrict__ mean) {
  int g = blockIdx.x * 256 + threadIdx.x;  // 2048 = B*C
  int b = g >> 10, c = g & 1023;
  double s = 0.0;
  for (int ch = 0; ch < 32; ++ch) s += part[((size_t)b * 32 + ch) * CQ + c];
  mean[g] = s * (1.0 / 4096.0);
}

// ---------------- mse (fp64) + base output (x + upsample(cached)) + x->bf16 ----------------
__global__ __launch_bounds__(256) void k_mse_base(const float* __restrict__ x,
                                                  const float* __restrict__ cached,
                                                  const double* __restrict__ mean,
                                                  double* __restrict__ mse,
                                                  float* __restrict__ out,
                                                  unsigned short* __restrict__ xb) {
  int bl = blockIdx.x; int b = bl >> 12, l = bl & 4095;
  int hh = l >> 6, ww = l & 63;
  size_t xoff = ((size_t)b * LQ + l) * CQ;
  size_t uoff = (((size_t)b * 32 + (hh >> 1)) * 32 + (ww >> 1)) * CQ;
  const double* mrow = mean + (size_t)b * CQ;
  int c0 = threadIdx.x * 4;
  float4 xv = *(const float4*)(x + xoff + c0);
  float4 uv = *(const float4*)(cached + uoff + c0);
  float4 ov;
  ov.x = xv.x + uv.x; ov.y = xv.y + uv.y; ov.z = xv.z + uv.z; ov.w = xv.w + uv.w;
  *(float4*)(out + xoff + c0) = ov;
  ushort4 xo;
  xo.x = f2b(xv.x); xo.y = f2b(xv.y); xo.z = f2b(xv.z); xo.w = f2b(xv.w);
  ((ushort4*)xb)[(xoff + c0) >> 2] = xo;
  double d0 = (double)xv.x - mrow[c0];
  double d1 = (double)xv.y - mrow[c0 + 1];
  double d2 = (double)xv.z - mrow[c0 + 2];
  double d3 = (double)xv.w - mrow[c0 + 3];
  double ss = d0 * d0 + d1 * d1 + d2 * d2 + d3 * d3;
  for (int o = 1; o < 64; o <<= 1) ss += __shfl_xor(ss, o);
  __shared__ double ws4[4];
  if ((threadIdx.x & 63) == 0) ws4[threadIdx.x >> 6] = ss;
  __syncthreads();
  if (threadIdx.x == 0) mse[(size_t)b * LQ + l] = ws4[0] + ws4[1] + ws4[2] + ws4[3];
}

// ---------------- top-k (blocks 0,1) + fused weight fp32->bf16 conversion (blocks >=2) ----
__global__ __launch_bounds__(1024) void k_topk(const double* __restrict__ mse,
                                               int* __restrict__ idx_sel,
                                               const float* __restrict__ wqkv,
                                               const float* __restrict__ wproj,
                                               unsigned short* __restrict__ wqb,
                                               unsigned short* __restrict__ wpb) {
  if (blockIdx.x >= 2) {   // conversion path: 1024 blocks x 1024 thr x 1 float4
    int i = (blockIdx.x - 2) * 1024 + threadIdx.x;
    const float* s; unsigned short* d; int off;
    if (i < 786432) { s = wqkv;  d = wqb; off = i; }
    else            { s = wproj; d = wpb; off = i - 786432; }
    float4 v = ((const float4*)s)[off];
    ushort4 o;
    o.x = f2b(v.x); o.y = f2b(v.y); o.z = f2b(v.z); o.w = f2b(v.w);
    ((ushort4*)d)[off] = o;
    return;
  }
  __shared__ unsigned long long u[4096];       // 32 KB
  __shared__ unsigned int whist[16 * 257];     // 16.4 KB, stride 257 => cross-wave bank skew
  __shared__ unsigned int wtot[4];
  __shared__ unsigned long long sh_prefix;
  __shared__ int sh_rem, sh_rem2, sh_bsel, sh_cnt, sh_eqcnt;
  __shared__ int eqbuf[256];
  int b = blockIdx.x, t = threadIdx.x;
  int wv = t >> 6, laneid = t & 63;
  for (int p = 0; p < 4; ++p) {
    int i = p * 1024 + t;
    u[i] = (unsigned long long)__double_as_longlong(mse[(size_t)b * LQ + i]);
  }
  if (t == 0) { sh_prefix = 0ULL; sh_rem = KSEL; sh_cnt = 0; sh_eqcnt = 0; }
  __syncthreads();
  for (int shift = 56; shift >= 0; shift -= 8) {
    for (int z = t; z < 16 * 257; z += 1024) whist[z] = 0u;
    __syncthreads();
    unsigned long long pref = sh_prefix;
#pragma unroll
    for (int p = 0; p < 4; ++p) {
      int i = p * 1024 + t;
      unsigned long long v = u[i];
      bool cand = (shift == 56) || ((v >> ((shift + 8) & 63)) == pref);
      if (cand) atomicAdd(&whist[wv * 257 + ((unsigned int)(v >> shift) & 255u)], 1u);
    }
    __syncthreads();
    unsigned int myc = 0, mysc = 0;
    if (t < 256) {            // combine the 16 wave hists for my bin (bin = 255 - t)
      unsigned int s = 0;
      int bin = 255 - t;
#pragma unroll
      for (int wvi = 0; wvi < 16; ++wvi) s += whist[wvi * 257 + bin];
      myc = s;
      mysc = myc;
#pragma unroll
      for (int o = 1; o < 64; o <<= 1) {
        unsigned int v2 = __shfl_up(mysc, o);
        if (laneid >= o) mysc += v2;
      }
      if (laneid == 63) wtot[wv] = mysc;
    }
    __syncthreads();
    if (t < 256) {
      unsigned int basep = 0;
      for (int wvi = 0; wvi < wv; ++wvi) basep += wtot[wvi];
      unsigned int incl = basep + mysc;       // count of keys in bins >= my bin
      unsigned int excl = incl - myc;         // count of keys in bins >  my bin
      unsigned int rem = (unsigned int)sh_rem;
      if (excl < rem && rem <= incl) {        // exactly one thread crosses
        sh_bsel = 255 - t;
        sh_rem2 = (int)(rem - excl);
      }
    }
    __syncthreads();
    if (t == 0) {
      sh_prefix = (sh_prefix << 8) | (unsigned long long)sh_bsel;
      sh_rem = sh_rem2;
    }
    __syncthreads();
  }
  unsigned long long T = sh_prefix;
  int rem_eq = sh_rem;
#pragma unroll
  for (int p = 0; p < 4; ++p) {
    int i = p * 1024 + t;
    unsigned long long v = u[i];
    bool win = (v > T);
    unsigned long long mask = __ballot(win);
    int total = __popcll(mask);
    int base = 0;
    if (laneid == 0 && total > 0) base = atomicAdd(&sh_cnt, total);
    base = __shfl(base, 0);
    if (win) {
      int lpos = __popcll(mask & ((1ULL << laneid) - 1ULL));
      idx_sel[b * KPAD + base + lpos] = i;
    }
    if (v == T) {
      int e = atomicAdd(&sh_eqcnt, 1);
      if (e < 256) eqbuf[e] = i;
    }
  }
  __syncthreads();
  if (t == 0) {
    int n = sh_eqcnt; if (n > 256) n = 256;
    for (int a = 1; a < n; ++a) {           // ascending index sort (ties: smallest index wins)
      int key = eqbuf[a]; int c = a - 1;
      while (c >= 0 && eqbuf[c] > key) { eqbuf[c + 1] = eqbuf[c]; --c; }
      eqbuf[c + 1] = key;
    }
    int base = sh_cnt;
    for (int a = 0; a < rem_eq && a < n; ++a) idx_sel[b * KPAD + base + a] = eqbuf[a];
    for (int a = KSEL; a < KPAD; ++a) idx_sel[b * KPAD + a] = 0;
  }
}

// ---------------- qkv GEMM (64x128, BK=32), 1248 blocks, dbuf prefetch ----------------
// R12: 128x128 grid was 624 blocks = 2.44/CU (same under-occupancy disease gemmB
// had pre-R8). 64x128 tiles -> 52x24 = 1248 blocks (4.9/CU), 2x12KB LDS buffers
// (6 blk/CU capacity), per-thread vmcnt(3) depth-1 pipeline.
__global__ __launch_bounds__(256) void k_gemmA(const unsigned short* __restrict__ Asrc,
                                               const unsigned short* __restrict__ Bmat,
                                               const int* __restrict__ idx_sel,
                                               unsigned short* __restrict__ Cbf) {
  int bm = blockIdx.x % 52, bn = blockIdx.x / 52;
  int tid = threadIdx.x;
  int w = tid >> 6, lane = tid & 63, quad = lane >> 4, l15 = lane & 15;
  int wm = w & 1, wn = w >> 1;
  __shared__ __align__(16) unsigned char sm[2][12288];   // A [64][32]bf16, B [128][32]bf16

  const unsigned short* gA;
  {
    int row = tid >> 2, kc = tid & 3;
    int m = bm * 64 + row; if (m >= MTOT) m = MTOT - 1;
    int bb = m / KSEL; int ii = m - bb * KSEL;
    int lsel = idx_sel[bb * KPAD + ii];
    gA = Asrc + ((size_t)bb * LQ + lsel) * CQ + kc * 8;
  }
  const unsigned short* gB[2];
#pragma unroll
  for (int p = 0; p < 2; ++p) {
    int e = p * 256 + tid; int row = e >> 2, kc = e & 3;
    gB[p] = Bmat + (size_t)(bn * 128 + row) * CQ + kc * 8;
  }

  fx4 acc[2][4];
#pragma unroll
  for (int a = 0; a < 2; ++a)
#pragma unroll
    for (int c = 0; c < 4; ++c) acc[a][c] = (fx4){0.f, 0.f, 0.f, 0.f};

#define STAGE_A(buf, it) do { int ke = (it) * 32;                                   \
    async16(gA + ke, sm[buf] + tid * 16);                                           \
    async16(gB[0] + ke, sm[buf] + 4096 + tid * 16);                                 \
    async16(gB[1] + ke, sm[buf] + 8192 + tid * 16); } while (0)

  STAGE_A(0, 0);
  for (int it = 0; it < 32; ++it) {
    int cur = it & 1;
    if (it < 31) STAGE_A(cur ^ 1, it + 1);
    if (it < 31) asm volatile("s_waitcnt vmcnt(3)");
    else         asm volatile("s_waitcnt vmcnt(0)");
    __builtin_amdgcn_s_barrier();
    const unsigned char* smb = sm[cur];
    s16x8 af[2], bf[4];
#pragma unroll
    for (int mt = 0; mt < 2; ++mt)
      af[mt] = *(const s16x8*)(smb + ((wm * 32 + mt * 16 + l15) * 32 + quad * 8) * 2);
#pragma unroll
    for (int nt = 0; nt < 4; ++nt)
      bf[nt] = *(const s16x8*)(smb + 4096 + ((wn * 64 + nt * 16 + l15) * 32 + quad * 8) * 2);
    __builtin_amdgcn_s_setprio(1);
#pragma unroll
    for (int mt = 0; mt < 2; ++mt)
#pragma unroll
      for (int nt = 0; nt < 4; ++nt)
        acc[mt][nt] = MFMA16(af[mt], bf[nt], acc[mt][nt]);
    __builtin_amdgcn_s_setprio(0);
    __builtin_amdgcn_s_barrier();    // all waves done reading cur before it's re-staged
  }
#undef STAGE_A

#pragma unroll
  for (int mt = 0; mt < 2; ++mt)
#pragma unroll
    for (int nt = 0; nt < 4; ++nt) {
      int n = bn * 128 + wn * 64 + nt * 16 + l15;
      int mbase = bm * 64 + wm * 32 + mt * 16 + quad * 4;
      fx4 vv = acc[mt][nt];
#pragma unroll
      for (int r = 0; r < 4; ++r) {
        int m = mbase + r;
        if (m < MTOT) Cbf[(size_t)m * 3072 + n] = f2b(vv[r]);
      }
    }
}

// ---------------- proj GEMM (64x64, BK=64) : 832 blocks, dbuf prefetch ----------------
__global__ __launch_bounds__(256) void k_gemmB(const unsigned short* __restrict__ Asrc,
                                               const unsigned short* __restrict__ Bmat,
                                               const int* __restrict__ idx_sel,
                                               float* __restrict__ Cf,
                                               const float* __restrict__ xin,
                                               const float* __restrict__ bproj) {
  int bid = blockIdx.x;
  int swz = (bid & 7) * 104 + (bid >> 3);   // XCD-contiguous chunks (832 = 8*104)
  int bm = swz % 52, bn = swz / 52;
  int tid = threadIdx.x;
  int w = tid >> 6, lane = tid & 63, quad = lane >> 4, l15 = lane & 15;
  int wm = w & 1, wn = w >> 1;
  __shared__ __align__(16) unsigned char sm[2][16384];   // A [64][64]bf16, B [64][64]bf16

  const unsigned short* g4[4];
#pragma unroll
  for (int p = 0; p < 4; ++p) {
    int e = (p & 1) * 256 + tid; int row = e >> 3, kc = e & 7;
    if (p < 2) {
      int m = bm * 64 + row; if (m >= MTOT) m = MTOT - 1;
      int bb = m / KSEL; int ii = m - bb * KSEL;
      g4[p] = Asrc + ((size_t)bb * KPAD + ii) * CQ + kc * 8;
    } else {
      g4[p] = Bmat + (size_t)(bn * 64 + row) * CQ + kc * 8;
    }
  }

  fx4 acc[2][2];
#pragma unroll
  for (int a = 0; a < 2; ++a)
#pragma unroll
    for (int c = 0; c < 2; ++c) acc[a][c] = (fx4){0.f, 0.f, 0.f, 0.f};

#define STAGE_B(buf, it) do { int ke = (it) * 64;                                   \
    _Pragma("unroll")                                                               \
    for (int p = 0; p < 4; ++p)                                                     \
      async16(g4[p] + ke, sm[buf] + p * 4096 + w * 1024);                           \
    } while (0)

  STAGE_B(0, 0);
  for (int it = 0; it < 16; ++it) {
    int cur = it & 1;
    if (it < 15) STAGE_B(cur ^ 1, it + 1);
    if (it < 15) asm volatile("s_waitcnt vmcnt(4)");
    else         asm volatile("s_waitcnt vmcnt(0)");
    __builtin_amdgcn_s_barrier();
    const unsigned char* smb = sm[cur];
#pragma unroll
    for (int kk = 0; kk < 2; ++kk) {
      s16x8 af[2], bf2[2];
#pragma unroll
      for (int mt = 0; mt < 2; ++mt)
        af[mt] = *(const s16x8*)(smb + ((wm * 32 + mt * 16 + l15) * 64 + kk * 32 + quad * 8) * 2);
#pragma unroll
      for (int nt = 0; nt < 2; ++nt)
        bf2[nt] = *(const s16x8*)(smb + 8192 + ((wn * 32 + nt * 16 + l15) * 64 + kk * 32 + quad * 8) * 2);
#pragma unroll
      for (int mt = 0; mt < 2; ++mt)
#pragma unroll
        for (int nt = 0; nt < 2; ++nt)
          acc[mt][nt] = MFMA16(af[mt], bf2[nt], acc[mt][nt]);
    }
    __builtin_amdgcn_s_barrier();    // all waves done reading cur before it's re-staged
  }
#undef STAGE_B

#pragma unroll
  for (int mt = 0; mt < 2; ++mt)
#pragma unroll
    for (int nt = 0; nt < 2; ++nt) {
      int n = bn * 64 + wn * 32 + nt * 16 + l15;
      int mbase = bm * 64 + wm * 32 + mt * 16 + quad * 4;
      fx4 vv = acc[mt][nt];
      float bp = bproj[n];
#pragma unroll
      for (int r = 0; r < 4; ++r) {
        int m = mbase + r;
        if (m < MTOT) {
          int bb = m / KSEL; int ii = m - bb * KSEL;
          int lsel = idx_sel[bb * KPAD + ii];
          size_t off = ((size_t)bb * LQ + lsel) * CQ + n;
          Cf[off] = xin[off] + vv[r] + bp;
        }
      }
    }
}

// ---------------- l2norm + scale + rope -> q,k ; v -> Vt (transposed) ----------------
// R12 (G13): vectorized. Each 32-lane half-wave owns one token; lane holds the
// (even,odd) d-pair as a uint -> 4B/lane loads+stores, 32-wide shfl reduce, and
// the rope rotation pair is IN-LANE (no shfl_xor(,1)). 8 passes instead of 16.
__global__ __launch_bounds__(256) void k_normrope(const unsigned short* __restrict__ qkv,
                                                  const int* __restrict__ idx_sel,
                                                  const float* __restrict__ qbias,
                                                  const float* __restrict__ vbias,
                                                  const float* __restrict__ sml,
                                                  const float* __restrict__ rope,
                                                  unsigned short* __restrict__ qo,
                                                  unsigned short* __restrict__ ko,
                                                  unsigned short* __restrict__ vt) {
  int bid = blockIdx.x;                       // 26*16*2
  int tile = bid % 26; int h = (bid / 26) & 15; int b = bid / (26 * 16);
  int tid = threadIdx.x; int w = tid >> 6; int lane = tid & 63;
  int tk = lane >> 5, dl = lane & 31;         // token-half, d-pair index
  int d0 = dl * 2;
  __shared__ unsigned short vtile[64 * 68];
  float scale = expf(fminf(sml[h], 4.6051702f)) * 1.4426950408889634f;
  float2 qb2 = *(const float2*)(qbias + h * 64 + d0);
  float2 vb2 = *(const float2*)(vbias + h * 64 + d0);
  for (int pass = 0; pass < 8; ++pass) {
    int il = pass * 8 + w * 2 + tk;
    int i = tile * 64 + il;
    float v0 = 0.f, v1 = 0.f;
    if (i < KSEL) {
      int lsel = idx_sel[b * KPAD + i];
      size_t base = ((size_t)(b * KSEL + i)) * 3072 + h * 64 + d0;
      float r0 = rope[(size_t)lsel * 32 + dl];
      float r1 = rope[(size_t)LQ * 32 + (size_t)lsel * 32 + dl];
      // q
      unsigned int qw = *(const unsigned int*)(qkv + base);
      float q0 = b2f((unsigned short)qw) + qb2.x;
      float q1 = b2f((unsigned short)(qw >> 16)) + qb2.y;
      float ss = q0 * q0 + q1 * q1;
#pragma unroll
      for (int o = 1; o < 32; o <<= 1) ss += __shfl_xor(ss, o);
      float rn = scale / fmaxf(sqrtf(ss), 1e-12f);
      float qn0 = q0 * rn, qn1 = q1 * rn;
      *(unsigned int*)(qo + ((size_t)(b * NHQ + h) * KPAD + i) * 64 + d0) =
          cvtpk_bf16(r0 * qn0 - r1 * qn1, r1 * qn0 + r0 * qn1);
      // k
      unsigned int kw = *(const unsigned int*)(qkv + base + 1024);
      float k0 = b2f((unsigned short)kw);
      float k1 = b2f((unsigned short)(kw >> 16));
      float ks = k0 * k0 + k1 * k1;
#pragma unroll
      for (int o = 1; o < 32; o <<= 1) ks += __shfl_xor(ks, o);
      float rkn = 1.0f / fmaxf(sqrtf(ks), 1e-12f);
      float kn0 = k0 * rkn, kn1 = k1 * rkn;
      *(unsigned int*)(ko + ((size_t)(b * NHQ + h) * KPAD + i) * 64 + d0) =
          cvtpk_bf16(r0 * kn0 - r1 * kn1, r1 * kn0 + r0 * kn1);
      // v
      unsigned int vw = *(const unsigned int*)(qkv + base + 2048);
      v0 = b2f((unsigned short)vw) + vb2.x;
      v1 = b2f((unsigned short)(vw >> 16)) + vb2.y;
    }
    vtile[d0 * 68 + il] = f2b(v0);
    vtile[(d0 + 1) * 68 + il] = f2b(v1);
  }
  __syncthreads();
  int row = tid >> 2, c0 = (tid & 3) * 16;
  s16x8 o0, o1;
#pragma unroll
  for (int jj = 0; jj < 8; ++jj) {
    o0[jj] = (short)vtile[row * 68 + c0 + jj];
    o1[jj] = (short)vtile[row * 68 + c0 + 8 + jj];
  }
  size_t doff = ((size_t)((b * NHQ + h) * 64 + row)) * KPAD + (size_t)tile * 64 + c0;
  *(s16x8*)(vt + doff) = o0;
  *(s16x8*)(vt + doff + 8) = o1;
}

// ---------------- flash attention (R4 best version: z=2, 13 tiles/block) ----------------
__global__ __launch_bounds__(256, 4) void k_attn(const unsigned short* __restrict__ qb,
                                                 const unsigned short* __restrict__ kb,
                                                 const unsigned short* __restrict__ vtb,
                                                 const float* __restrict__ sml,
                                                 unsigned short* __restrict__ pO,
                                                 float* __restrict__ pl) {
  int qt = blockIdx.x; int bh = blockIdx.y; int part = blockIdx.z;
  int b = bh >> 4, h = bh & 15;
  int t0 = part * 13, t1 = t0 + 13;
  int q0 = qt * 128;
  int tid = threadIdx.x, w = tid >> 6, lane = tid & 63, quad = lane >> 4, l15 = lane & 15;
  float M = __expf(fminf(sml[h], 4.6051702f)) * 1.4426950408889634f;  // log2-domain shift
  __shared__ __align__(16) unsigned short Kt[64 * 72];     //  9216 B
  __shared__ __align__(16) unsigned short Vt[64 * 72];     //  9216 B
  __shared__ __align__(16) unsigned short Pq[4][32 * 72];  // 18432 B (total 36864 -> 4 blk/CU)
  unsigned short* Pw = Pq[w];
  const unsigned short* qbase = qb + (size_t)(b * NHQ + h) * KPAD * 64;
  const unsigned short* kbase = kb + (size_t)(b * NHQ + h) * KPAD * 64;
  const unsigned short* vbase = vtb + (size_t)(b * NHQ + h) * 64 * KPAD;

  // staging geometry: 512 s16x8 chunks per K (and V) tile, 2 per thread
  int r0 = tid >> 3, c0 = tid & 7;            // chunk 0: rows 0..31
  int r1 = 32 + r0, c1 = c0;                  // chunk 1: rows 32..63

  // Q as B-operand: n=l15 -> q row; k = kb2*32 + quad*8
  s16x8 qf[2][2];
#pragma unroll
  for (int qtile = 0; qtile < 2; ++qtile)
#pragma unroll
    for (int kb2 = 0; kb2 < 2; ++kb2) {
      int row = q0 + w * 32 + qtile * 16 + l15;
      qf[qtile][kb2] = *(const s16x8*)(qbase + (size_t)row * 64 + kb2 * 32 + quad * 8);
    }

  float lsum[2] = {0.f, 0.f};
  fx4 oacc[2][4];
#pragma unroll
  for (int qtile = 0; qtile < 2; ++qtile)
#pragma unroll
    for (int dt = 0; dt < 4; ++dt) oacc[qtile][dt] = (fx4){0.f, 0.f, 0.f, 0.f};

  // prologue: issue tile t0's loads (T14 async-STAGE split)
  s16x8 kn0, kn1, vn0, vn1;
  {
    int j0 = t0 * 64;
    kn0 = *(const s16x8*)(kbase + (size_t)(j0 + r0) * 64 + c0 * 8);
    kn1 = *(const s16x8*)(kbase + (size_t)(j0 + r1) * 64 + c1 * 8);
    vn0 = *(const s16x8*)(vbase + (size_t)r0 * KPAD + j0 + c0 * 8);
    vn1 = *(const s16x8*)(vbase + (size_t)r1 * KPAD + j0 + c1 * 8);
  }

  for (int t = t0; t < t1; ++t) {
    int j0 = t * 64;
    bool tail = (j0 + 64 > KSEL);
    __builtin_amdgcn_s_barrier();    // all waves done reading prev Kt/Vt
    *(s16x8*)(Kt + r0 * 72 + c0 * 8) = kn0;
    *(s16x8*)(Kt + r1 * 72 + c1 * 8) = kn1;
    *(s16x8*)(Vt + r0 * 72 + c0 * 8) = vn0;
    *(s16x8*)(Vt + r1 * 72 + c1 * 8) = vn1;
    // issue next tile's loads; they stay in flight under this tile's compute
    if (t + 1 < t1) {
      int jn = (t + 1) * 64;
      kn0 = *(const s16x8*)(kbase + (size_t)(jn + r0) * 64 + c0 * 8);
      kn1 = *(const s16x8*)(kbase + (size_t)(jn + r1) * 64 + c1 * 8);
      vn0 = *(const s16x8*)(vbase + (size_t)r0 * KPAD + jn + c0 * 8);
      vn1 = *(const s16x8*)(vbase + (size_t)r1 * KPAD + jn + c1 * 8);
    }
    asm volatile("s_waitcnt lgkmcnt(0)" ::: "memory");   // ds_writes visible
    __builtin_amdgcn_s_barrier();

    // S^T -> exp2 -> wave-private P -> PV
    fx4 sacc[2][4];
#pragma unroll
    for (int qtile = 0; qtile < 2; ++qtile)
#pragma unroll
      for (int jj = 0; jj < 4; ++jj) sacc[qtile][jj] = (fx4){0.f, 0.f, 0.f, 0.f};
    __builtin_amdgcn_s_setprio(1);
#pragma unroll
    for (int jj = 0; jj < 4; ++jj) {
      int jl = jj * 16 + l15;
      s16x8 kf0 = *(const s16x8*)(Kt + jl * 72 + quad * 8);
      s16x8 kf1 = *(const s16x8*)(Kt + jl * 72 + 32 + quad * 8);
      sacc[0][jj] = MFMA16(kf0, qf[0][0], sacc[0][jj]);
      sacc[1][jj] = MFMA16(kf0, qf[1][0], sacc[1][jj]);
      sacc[0][jj] = MFMA16(kf1, qf[0][1], sacc[0][jj]);
      sacc[1][jj] = MFMA16(kf1, qf[1][1], sacc[1][jj]);
    }
    __builtin_amdgcn_s_setprio(0);
#pragma unroll
    for (int qtile = 0; qtile < 2; ++qtile)
#pragma unroll
      for (int jj = 0; jj < 4; ++jj) {
        int jbase = j0 + jj * 16 + quad * 4;
        fx4 sv = sacc[qtile][jj];
        float p0 = fexp2(sv[0] - M);
        float p1 = fexp2(sv[1] - M);
        float p2 = fexp2(sv[2] - M);
        float p3 = fexp2(sv[3] - M);
        if (tail) {
          if (jbase + 0 >= KSEL) p0 = 0.f;
          if (jbase + 1 >= KSEL) p1 = 0.f;
          if (jbase + 2 >= KSEL) p2 = 0.f;
          if (jbase + 3 >= KSEL) p3 = 0.f;
        }
        lsum[qtile] += (p0 + p1) + (p2 + p3);
        *(uint2*)(Pw + (qtile * 16 + l15) * 72 + jj * 16 + quad * 4) =
            make_uint2(cvtpk_bf16(p0, p1), cvtpk_bf16(p2, p3));
      }
    // PV: A=P (wave-private LDS), B=V (LDS)
    __builtin_amdgcn_s_setprio(1);
#pragma unroll
    for (int js = 0; js < 2; ++js) {
      s16x8 pf0 = *(const s16x8*)(Pw + l15 * 72 + js * 32 + quad * 8);
      s16x8 pf1 = *(const s16x8*)(Pw + (16 + l15) * 72 + js * 32 + quad * 8);
#pragma unroll
      for (int dt = 0; dt < 4; ++dt) {
        s16x8 vf = *(const s16x8*)(Vt + (dt * 16 + l15) * 72 + js * 32 + quad * 8);
        oacc[0][dt] = MFMA16(pf0, vf, oacc[0][dt]);
        oacc[1][dt] = MFMA16(pf1, vf, oacc[1][dt]);
      }
    }
    __builtin_amdgcn_s_setprio(0);
  }

  // combine quad-partitioned j-sums (lanes l15, +16, +32, +48 hold disjoint j sets)
#pragma unroll
  for (int qtile = 0; qtile < 2; ++qtile) {
    float s = lsum[qtile];
    s += __shfl_xor(s, 16);
    s += __shfl_xor(s, 32);
    lsum[qtile] = s;
  }

  size_t pbase = (((size_t)part * 2 + b) * NHQ + h) * KPAD;
#pragma unroll
  for (int qtile = 0; qtile < 2; ++qtile) {
    int gqb = q0 + w * 32 + qtile * 16;
    if (quad == 0) pl[pbase + gqb + l15] = lsum[qtile];
  }

  // transpose O through the (now free) wave-private P buffer -> coalesced stores
#pragma unroll
  for (int qtile = 0; qtile < 2; ++qtile)
#pragma unroll
    for (int dt = 0; dt < 4; ++dt)
#pragma unroll
      for (int r = 0; r < 4; ++r)
        Pw[(qtile * 16 + quad * 4 + r) * 72 + dt * 16 + l15] = f2b(oacc[qtile][dt][r]);
#pragma unroll
  for (int pass = 0; pass < 4; ++pass) {
    int row = pass * 8 + (lane >> 3), chunk = lane & 7;
    s16x8 vv = *(const s16x8*)(Pw + row * 72 + chunk * 8);
    *(s16x8*)(pO + (pbase + q0 + w * 32 + row) * 64 + chunk * 8) = vv;
  }
}

// ---------------- combine the two j-halves: o = (Oa+Ob)/(la+lb) -> ob (bf16) ----------------
__global__ __launch_bounds__(256) void k_comb(const unsigned short* __restrict__ pO,
                                              const float* __restrict__ pl,
                                              unsigned short* __restrict__ ob) {
  size_t g = (size_t)blockIdx.x * 256 + threadIdx.x;   // 2*16*1664*64 = 3407872
  int d = (int)(g & 63);
  size_t row = g >> 6;              // (b*16+h)*1664 + gq
  int gq = (int)(row % KPAD);
  int bhh = (int)(row / KPAD);
  int b = bhh >> 4, h = bhh & 15;
  float oa = b2f(pO[g]);
  float obv = b2f(pO[g + 3407872]);
  float la = pl[row], lb = pl[row + 53248];
  float o = (oa + obv) / (la + lb);
  ob[((size_t)(b * KPAD + gq)) * CQ + h * 64 + d] = f2b(o);
}

extern "C" void kernel_launch(void* const* d_in, const int* in_sizes, int n_in,
                              void* d_out, int out_size, void* d_ws, size_t ws_size,
                              hipStream_t stream) {
  const float* x      = (const float*)d_in[0];
  const float* cached = (const float*)d_in[1];
  const float* wqkv   = (const float*)d_in[2];
  const float* qbias  = (const float*)d_in[3];
  const float* vbias  = (const float*)d_in[4];
  const float* wproj  = (const float*)d_in[5];
  const float* bproj  = (const float*)d_in[6];
  const float* sml    = (const float*)d_in[7];
  const float* rope   = (const float*)d_in[8];
  float* out = (float*)d_out;
  char* ws = (char*)d_ws;

  double* meanpart        = (double*)(ws);                    // 524288
  double* mean            = (double*)(ws + 524288);           // 16384
  double* mse             = (double*)(ws + 540672);           // 65536
  int* idx_sel            = (int*)(ws + 606208);              // 13312 -> 619520
  // overlap zone [619520, 44135424): x_bf + wqkv_bf + qkv (dead after k_normrope)
  unsigned short* x_bf    = (unsigned short*)(ws + 619520);   // 16777216
  unsigned short* wqkv_bf = (unsigned short*)(ws + 17396736); // 6291456
  unsigned short* qkv     = (unsigned short*)(ws + 23688192); // 20447232 -> 44135424
  // attn partials reuse the dead x_bf region
  unsigned short* pO      = (unsigned short*)(ws + 619520);   // 13631488
  float* pl               = (float*)(ws + 14251008);          // 425984 -> 14676992
  unsigned short* wproj_bf= (unsigned short*)(ws + 44135424); // 2097152
  unsigned short* qo      = (unsigned short*)(ws + 46232576); // 6815744
  unsigned short* ko      = (unsigned short*)(ws + 53048320); // 6815744
  unsigned short* vt      = (unsigned short*)(ws + 59864064); // 6815744
  unsigned short* ob      = (unsigned short*)(ws + 66679808); // 6815744 -> 73495552

  hipLaunchKernelGGL(k_mean_part, dim3(256), dim3(256), 0, stream, x, meanpart);
  hipLaunchKernelGGL(k_mean_reduce, dim3(8), dim3(256), 0, stream, meanpart, mean);
  hipLaunchKernelGGL(k_mse_base, dim3(8192), dim3(256), 0, stream, x, cached, mean, mse,
                     out, x_bf);
  hipLaunchKernelGGL(k_topk, dim3(2 + 1024), dim3(1024), 0, stream, mse, idx_sel,
                     wqkv, wproj, wqkv_bf, wproj_bf);
  hipLaunchKernelGGL(k_gemmA, dim3(52 * 24), dim3(256), 0, stream,
                     x_bf, wqkv_bf, idx_sel, qkv);
  hipLaunchKernelGGL(k_normrope, dim3(26 * 16 * BQ), dim3(256), 0, stream,
                     qkv, idx_sel, qbias, vbias, sml, rope, qo, ko, vt);
  hipLaunchKernelGGL(k_attn, dim3(13, BQ * NHQ, 2), dim3(256), 0, stream,
                     qo, ko, vt, sml, pO, pl);
  hipLaunchKernelGGL(k_comb, dim3(13312), dim3(256), 0, stream, pO, pl, ob);
  hipLaunchKernelGGL(k_gemmB, dim3(832), dim3(256), 0, stream,
                     ob, wproj_bf, idx_sel, out, x, bproj);
}

// Round 9
// 277.245 us; speedup vs baseline: 1.0473x; 1.0081x over previous
//
#include <hip/hip_runtime.h>
#include <hip/hip_bf16.h>
#include <math.h>

// Problem constants (setup_inputs)
#define BQ   2
#define LQ   4096
#define CQ   1024
#define NHQ  16
#define DHQ  64
#define KSEL 1638
#define KPAD 1664
#define MTOT (BQ*KSEL)   // 3276
#define MPAD 3328        // 26*128

typedef short s16x8 __attribute__((ext_vector_type(8)));
typedef float fx4   __attribute__((ext_vector_type(4)));

#define MFMA16(a,b,c) __builtin_amdgcn_mfma_f32_16x16x32_bf16(a,b,c,0,0,0)

__device__ __forceinline__ float b2f(unsigned short u) {
  union { float f; unsigned int i; } cv; cv.i = ((unsigned int)u) << 16; return cv.f;
}
__device__ __forceinline__ unsigned short f2b(float f) {
  union { float f; unsigned int i; } cv; cv.f = f;
  unsigned int x = cv.i;
  return (unsigned short)((x + 0x7fffu + ((x >> 16) & 1u)) >> 16);
}
__device__ __forceinline__ unsigned int fbits(float f) {
  union { float f; unsigned int i; } cv; cv.f = f; return cv.i;
}
// packed f32x2 -> bf16x2 (RNE), single VALU op
__device__ __forceinline__ unsigned int cvtpk_bf16(float a, float b) {
  unsigned int r;
  asm("v_cvt_pk_bf16_f32 %0, %1, %2" : "=v"(r) : "v"(a), "v"(b));
  return r;
}
__device__ __forceinline__ void async16(const void* g, void* l) {
  __builtin_amdgcn_global_load_lds((const __attribute__((address_space(1))) void*)g,
                                   (__attribute__((address_space(3))) void*)l, 16, 0, 0);
}
// raw 2^x (q is pre-scaled by log2(e) in k_normrope, M is in log2 units)
__device__ __forceinline__ float fexp2(float x) {
#if __has_builtin(__builtin_amdgcn_exp2f)
  return __builtin_amdgcn_exp2f(x);
#else
  return __expf(x * 0.69314718055994531f);
#endif
}

// ---------------- mean (fp64, 2-stage) ----------------
__global__ __launch_bounds__(256) void k_mean_part(const float* __restrict__ x,
                                                   double* __restrict__ part) {
  int bid = blockIdx.x;                    // 256 blocks: [b(2)][ch(32)][cb(4)]
  int cb = bid & 3, ch = (bid >> 2) & 31, b = bid >> 7;
  int c = cb * 256 + threadIdx.x;
  const float* p = x + ((size_t)b * LQ + (size_t)ch * 128) * CQ + c;
  double s = 0.0;
  for (int r = 0; r < 128; ++r) s += (double)p[(size_t)r * CQ];
  part[((size_t)b * 32 + ch) * CQ + c] = s;
}

__global__ __launch_bounds__(256) void k_mean_reduce(const double* __restrict__ part,
                                                     double* __restrict__ mean) {
  int g = blockIdx.x * 256 + threadIdx.x;  // 2048 = B*C
  int b = g >> 10, c = g & 1023;
  double s = 0.0;
  for (int ch = 0; ch < 32; ++ch) s += part[((size_t)b * 32 + ch) * CQ + c];
  mean[g] = s * (1.0 / 4096.0);
}

// ---------------- mse (fp64) + base output (x + upsample(cached)) + x->bf16 ----------------
__global__ __launch_bounds__(256) void k_mse_base(const float* __restrict__ x,
                                                  const float* __restrict__ cached,
                                                  const double* __restrict__ mean,
                                                  double* __restrict__ mse,
                                                  float* __restrict__ out,
                                                  unsigned short* __restrict__ xb) {
  int bl = blockIdx.x; int b = bl >> 12, l = bl & 4095;
  int hh = l >> 6, ww = l & 63;
  size_t xoff = ((size_t)b * LQ + l) * CQ;
  size_t uoff = (((size_t)b * 32 + (hh >> 1)) * 32 + (ww >> 1)) * CQ;
  const double* mrow = mean + (size_t)b * CQ;
  int c0 = threadIdx.x * 4;
  float4 xv = *(const float4*)(x + xoff + c0);
  float4 uv = *(const float4*)(cached + uoff + c0);
  float4 ov;
  ov.x = xv.x + uv.x; ov.y = xv.y + uv.y; ov.z = xv.z + uv.z; ov.w = xv.w + uv.w;
  *(float4*)(out + xoff + c0) = ov;
  ushort4 xo;
  xo.x = f2b(xv.x); xo.y = f2b(xv.y); xo.z = f2b(xv.z); xo.w = f2b(xv.w);
  ((ushort4*)xb)[(xoff + c0) >> 2] = xo;
  double d0 = (double)xv.x - mrow[c0];
  double d1 = (double)xv.y - mrow[c0 + 1];
  double d2 = (double)xv.z - mrow[c0 + 2];
  double d3 = (double)xv.w - mrow[c0 + 3];
  double ss = d0 * d0 + d1 * d1 + d2 * d2 + d3 * d3;
  for (int o = 1; o < 64; o <<= 1) ss += __shfl_xor(ss, o);
  __shared__ double ws4[4];
  if ((threadIdx.x & 63) == 0) ws4[threadIdx.x >> 6] = ss;
  __syncthreads();
  if (threadIdx.x == 0) mse[(size_t)b * LQ + l] = ws4[0] + ws4[1] + ws4[2] + ws4[3];
}

// ---------------- top-k (blocks 0,1) + fused weight fp32->bf16 conversion (blocks >=2) ----
__global__ __launch_bounds__(1024) void k_topk(const double* __restrict__ mse,
                                               int* __restrict__ idx_sel,
                                               const float* __restrict__ wqkv,
                                               const float* __restrict__ wproj,
                                               unsigned short* __restrict__ wqb,
                                               unsigned short* __restrict__ wpb) {
  if (blockIdx.x >= 2) {   // conversion path: 1024 blocks x 1024 thr x 1 float4
    int i = (blockIdx.x - 2) * 1024 + threadIdx.x;
    const float* s; unsigned short* d; int off;
    if (i < 786432) { s = wqkv;  d = wqb; off = i; }
    else            { s = wproj; d = wpb; off = i - 786432; }
    float4 v = ((const float4*)s)[off];
    ushort4 o;
    o.x = f2b(v.x); o.y = f2b(v.y); o.z = f2b(v.z); o.w = f2b(v.w);
    ((ushort4*)d)[off] = o;
    return;
  }
  __shared__ unsigned long long u[4096];       // 32 KB
  __shared__ unsigned int whist[16 * 257];     // 16.4 KB, stride 257 => cross-wave bank skew
  __shared__ unsigned int wtot[4];
  __shared__ unsigned long long sh_prefix;
  __shared__ int sh_rem, sh_rem2, sh_bsel, sh_cnt, sh_eqcnt;
  __shared__ int eqbuf[256];
  int b = blockIdx.x, t = threadIdx.x;
  int wv = t >> 6, laneid = t & 63;
  for (int p = 0; p < 4; ++p) {
    int i = p * 1024 + t;
    u[i] = (unsigned long long)__double_as_longlong(mse[(size_t)b * LQ + i]);
  }
  if (t == 0) { sh_prefix = 0ULL; sh_rem = KSEL; sh_cnt = 0; sh_eqcnt = 0; }
  __syncthreads();
  for (int shift = 56; shift >= 0; shift -= 8) {
    for (int z = t; z < 16 * 257; z += 1024) whist[z] = 0u;
    __syncthreads();
    unsigned long long pref = sh_prefix;
#pragma unroll
    for (int p = 0; p < 4; ++p) {
      int i = p * 1024 + t;
      unsigned long long v = u[i];
      bool cand = (shift == 56) || ((v >> ((shift + 8) & 63)) == pref);
      if (cand) atomicAdd(&whist[wv * 257 + ((unsigned int)(v >> shift) & 255u)], 1u);
    }
    __syncthreads();
    unsigned int myc = 0, mysc = 0;
    if (t < 256) {            // combine the 16 wave hists for my bin (bin = 255 - t)
      unsigned int s = 0;
      int bin = 255 - t;
#pragma unroll
      for (int wvi = 0; wvi < 16; ++wvi) s += whist[wvi * 257 + bin];
      myc = s;
      mysc = myc;
#pragma unroll
      for (int o = 1; o < 64; o <<= 1) {
        unsigned int v2 = __shfl_up(mysc, o);
        if (laneid >= o) mysc += v2;
      }
      if (laneid == 63) wtot[wv] = mysc;
    }
    __syncthreads();
    if (t < 256) {
      unsigned int basep = 0;
      for (int wvi = 0; wvi < wv; ++wvi) basep += wtot[wvi];
      unsigned int incl = basep + mysc;       // count of keys in bins >= my bin
      unsigned int excl = incl - myc;         // count of keys in bins >  my bin
      unsigned int rem = (unsigned int)sh_rem;
      if (excl < rem && rem <= incl) {        // exactly one thread crosses
        sh_bsel = 255 - t;
        sh_rem2 = (int)(rem - excl);
      }
    }
    __syncthreads();
    if (t == 0) {
      sh_prefix = (sh_prefix << 8) | (unsigned long long)sh_bsel;
      sh_rem = sh_rem2;
    }
    __syncthreads();
  }
  unsigned long long T = sh_prefix;
  int rem_eq = sh_rem;
#pragma unroll
  for (int p = 0; p < 4; ++p) {
    int i = p * 1024 + t;
    unsigned long long v = u[i];
    bool win = (v > T);
    unsigned long long mask = __ballot(win);
    int total = __popcll(mask);
    int base = 0;
    if (laneid == 0 && total > 0) base = atomicAdd(&sh_cnt, total);
    base = __shfl(base, 0);
    if (win) {
      int lpos = __popcll(mask & ((1ULL << laneid) - 1ULL));
      idx_sel[b * KPAD + base + lpos] = i;
    }
    if (v == T) {
      int e = atomicAdd(&sh_eqcnt, 1);
      if (e < 256) eqbuf[e] = i;
    }
  }
  __syncthreads();
  if (t == 0) {
    int n = sh_eqcnt; if (n > 256) n = 256;
    for (int a = 1; a < n; ++a) {           // ascending index sort (ties: smallest index wins)
      int key = eqbuf[a]; int c = a - 1;
      while (c >= 0 && eqbuf[c] > key) { eqbuf[c + 1] = eqbuf[c]; --c; }
      eqbuf[c + 1] = key;
    }
    int base = sh_cnt;
    for (int a = 0; a < rem_eq && a < n; ++a) idx_sel[b * KPAD + base + a] = eqbuf[a];
    for (int a = KSEL; a < KPAD; ++a) idx_sel[b * KPAD + a] = 0;
  }
}

// ---------------- qkv GEMM (64x128, BK=32), 1248 blocks, dbuf prefetch ----------------
// R15: + XCD-aware block swizzle (1248 = 8*156, bijective): neighbor tiles that
// share B-panels land on the same XCD's L2.
__global__ __launch_bounds__(256) void k_gemmA(const unsigned short* __restrict__ Asrc,
                                               const unsigned short* __restrict__ Bmat,
                                               const int* __restrict__ idx_sel,
                                               unsigned short* __restrict__ Cbf) {
  int bid = blockIdx.x;
  int swz = (bid & 7) * 156 + (bid >> 3);   // XCD-contiguous chunks
  int bm = swz % 52, bn = swz / 52;
  int tid = threadIdx.x;
  int w = tid >> 6, lane = tid & 63, quad = lane >> 4, l15 = lane & 15;
  int wm = w & 1, wn = w >> 1;
  __shared__ __align__(16) unsigned char sm[2][12288];   // A [64][32]bf16, B [128][32]bf16

  const unsigned short* gA;
  {
    int row = tid >> 2, kc = tid & 3;
    int m = bm * 64 + row; if (m >= MTOT) m = MTOT - 1;
    int bb = m / KSEL; int ii = m - bb * KSEL;
    int lsel = idx_sel[bb * KPAD + ii];
    gA = Asrc + ((size_t)bb * LQ + lsel) * CQ + kc * 8;
  }
  const unsigned short* gB[2];
#pragma unroll
  for (int p = 0; p < 2; ++p) {
    int e = p * 256 + tid; int row = e >> 2, kc = e & 3;
    gB[p] = Bmat + (size_t)(bn * 128 + row) * CQ + kc * 8;
  }

  fx4 acc[2][4];
#pragma unroll
  for (int a = 0; a < 2; ++a)
#pragma unroll
    for (int c = 0; c < 4; ++c) acc[a][c] = (fx4){0.f, 0.f, 0.f, 0.f};

#define STAGE_A(buf, it) do { int ke = (it) * 32;                                   \
    async16(gA + ke, sm[buf] + tid * 16);                                           \
    async16(gB[0] + ke, sm[buf] + 4096 + tid * 16);                                 \
    async16(gB[1] + ke, sm[buf] + 8192 + tid * 16); } while (0)

  STAGE_A(0, 0);
  for (int it = 0; it < 32; ++it) {
    int cur = it & 1;
    if (it < 31) STAGE_A(cur ^ 1, it + 1);
    if (it < 31) asm volatile("s_waitcnt vmcnt(3)");
    else         asm volatile("s_waitcnt vmcnt(0)");
    __builtin_amdgcn_s_barrier();
    const unsigned char* smb = sm[cur];
    s16x8 af[2], bf[4];
#pragma unroll
    for (int mt = 0; mt < 2; ++mt)
      af[mt] = *(const s16x8*)(smb + ((wm * 32 + mt * 16 + l15) * 32 + quad * 8) * 2);
#pragma unroll
    for (int nt = 0; nt < 4; ++nt)
      bf[nt] = *(const s16x8*)(smb + 4096 + ((wn * 64 + nt * 16 + l15) * 32 + quad * 8) * 2);
    __builtin_amdgcn_s_setprio(1);
#pragma unroll
    for (int mt = 0; mt < 2; ++mt)
#pragma unroll
      for (int nt = 0; nt < 4; ++nt)
        acc[mt][nt] = MFMA16(af[mt], bf[nt], acc[mt][nt]);
    __builtin_amdgcn_s_setprio(0);
    __builtin_amdgcn_s_barrier();    // all waves done reading cur before it's re-staged
  }
#undef STAGE_A

#pragma unroll
  for (int mt = 0; mt < 2; ++mt)
#pragma unroll
    for (int nt = 0; nt < 4; ++nt) {
      int n = bn * 128 + wn * 64 + nt * 16 + l15;
      int mbase = bm * 64 + wm * 32 + mt * 16 + quad * 4;
      fx4 vv = acc[mt][nt];
#pragma unroll
      for (int r = 0; r < 4; ++r) {
        int m = mbase + r;
        if (m < MTOT) Cbf[(size_t)m * 3072 + n] = f2b(vv[r]);
      }
    }
}

// ---------------- proj GEMM (64x64, BK=64) : 832 blocks, dbuf prefetch ----------------
__global__ __launch_bounds__(256) void k_gemmB(const unsigned short* __restrict__ Asrc,
                                               const unsigned short* __restrict__ Bmat,
                                               const int* __restrict__ idx_sel,
                                               float* __restrict__ Cf,
                                               const float* __restrict__ xin,
                                               const float* __restrict__ bproj) {
  int bid = blockIdx.x;
  int swz = (bid & 7) * 104 + (bid >> 3);   // XCD-contiguous chunks (832 = 8*104)
  int bm = swz % 52, bn = swz / 52;
  int tid = threadIdx.x;
  int w = tid >> 6, lane = tid & 63, quad = lane >> 4, l15 = lane & 15;
  int wm = w & 1, wn = w >> 1;
  __shared__ __align__(16) unsigned char sm[2][16384];   // A [64][64]bf16, B [64][64]bf16

  const unsigned short* g4[4];
#pragma unroll
  for (int p = 0; p < 4; ++p) {
    int e = (p & 1) * 256 + tid; int row = e >> 3, kc = e & 7;
    if (p < 2) {
      int m = bm * 64 + row; if (m >= MTOT) m = MTOT - 1;
      int bb = m / KSEL; int ii = m - bb * KSEL;
      g4[p] = Asrc + ((size_t)bb * KPAD + ii) * CQ + kc * 8;
    } else {
      g4[p] = Bmat + (size_t)(bn * 64 + row) * CQ + kc * 8;
    }
  }

  fx4 acc[2][2];
#pragma unroll
  for (int a = 0; a < 2; ++a)
#pragma unroll
    for (int c = 0; c < 2; ++c) acc[a][c] = (fx4){0.f, 0.f, 0.f, 0.f};

#define STAGE_B(buf, it) do { int ke = (it) * 64;                                   \
    _Pragma("unroll")                                                               \
    for (int p = 0; p < 4; ++p)                                                     \
      async16(g4[p] + ke, sm[buf] + p * 4096 + w * 1024);                           \
    } while (0)

  STAGE_B(0, 0);
  for (int it = 0; it < 16; ++it) {
    int cur = it & 1;
    if (it < 15) STAGE_B(cur ^ 1, it + 1);
    if (it < 15) asm volatile("s_waitcnt vmcnt(4)");
    else         asm volatile("s_waitcnt vmcnt(0)");
    __builtin_amdgcn_s_barrier();
    const unsigned char* smb = sm[cur];
#pragma unroll
    for (int kk = 0; kk < 2; ++kk) {
      s16x8 af[2], bf2[2];
#pragma unroll
      for (int mt = 0; mt < 2; ++mt)
        af[mt] = *(const s16x8*)(smb + ((wm * 32 + mt * 16 + l15) * 64 + kk * 32 + quad * 8) * 2);
#pragma unroll
      for (int nt = 0; nt < 2; ++nt)
        bf2[nt] = *(const s16x8*)(smb + 8192 + ((wn * 32 + nt * 16 + l15) * 64 + kk * 32 + quad * 8) * 2);
#pragma unroll
      for (int mt = 0; mt < 2; ++mt)
#pragma unroll
        for (int nt = 0; nt < 2; ++nt)
          acc[mt][nt] = MFMA16(af[mt], bf2[nt], acc[mt][nt]);
    }
    __builtin_amdgcn_s_barrier();    // all waves done reading cur before it's re-staged
  }
#undef STAGE_B

#pragma unroll
  for (int mt = 0; mt < 2; ++mt)
#pragma unroll
    for (int nt = 0; nt < 2; ++nt) {
      int n = bn * 64 + wn * 32 + nt * 16 + l15;
      int mbase = bm * 64 + wm * 32 + mt * 16 + quad * 4;
      fx4 vv = acc[mt][nt];
      float bp = bproj[n];
#pragma unroll
      for (int r = 0; r < 4; ++r) {
        int m = mbase + r;
        if (m < MTOT) {
          int bb = m / KSEL; int ii = m - bb * KSEL;
          int lsel = idx_sel[bb * KPAD + ii];
          size_t off = ((size_t)bb * LQ + lsel) * CQ + n;
          Cf[off] = xin[off] + vv[r] + bp;
        }
      }
    }
}

// ---------------- l2norm + scale + rope -> q,k ; v -> Vt (transposed) ----------------
__global__ __launch_bounds__(256) void k_normrope(const unsigned short* __restrict__ qkv,
                                                  const int* __restrict__ idx_sel,
                                                  const float* __restrict__ qbias,
                                                  const float* __restrict__ vbias,
                                                  const float* __restrict__ sml,
                                                  const float* __restrict__ rope,
                                                  unsigned short* __restrict__ qo,
                                                  unsigned short* __restrict__ ko,
                                                  unsigned short* __restrict__ vt) {
  int bid = blockIdx.x;                       // 26*16*2
  int tile = bid % 26; int h = (bid / 26) & 15; int b = bid / (26 * 16);
  int tid = threadIdx.x; int w = tid >> 6; int lane = tid & 63;
  int tk = lane >> 5, dl = lane & 31;         // token-half, d-pair index
  int d0 = dl * 2;
  __shared__ unsigned short vtile[64 * 68];
  float scale = expf(fminf(sml[h], 4.6051702f)) * 1.4426950408889634f;
  float2 qb2 = *(const float2*)(qbias + h * 64 + d0);
  float2 vb2 = *(const float2*)(vbias + h * 64 + d0);
  for (int pass = 0; pass < 8; ++pass) {
    int il = pass * 8 + w * 2 + tk;
    int i = tile * 64 + il;
    float v0 = 0.f, v1 = 0.f;
    if (i < KSEL) {
      int lsel = idx_sel[b * KPAD + i];
      size_t base = ((size_t)(b * KSEL + i)) * 3072 + h * 64 + d0;
      float r0 = rope[(size_t)lsel * 32 + dl];
      float r1 = rope[(size_t)LQ * 32 + (size_t)lsel * 32 + dl];
      // q
      unsigned int qw = *(const unsigned int*)(qkv + base);
      float q0 = b2f((unsigned short)qw) + qb2.x;
      float q1 = b2f((unsigned short)(qw >> 16)) + qb2.y;
      float ss = q0 * q0 + q1 * q1;
#pragma unroll
      for (int o = 1; o < 32; o <<= 1) ss += __shfl_xor(ss, o);
      float rn = scale / fmaxf(sqrtf(ss), 1e-12f);
      float qn0 = q0 * rn, qn1 = q1 * rn;
      *(unsigned int*)(qo + ((size_t)(b * NHQ + h) * KPAD + i) * 64 + d0) =
          cvtpk_bf16(r0 * qn0 - r1 * qn1, r1 * qn0 + r0 * qn1);
      // k
      unsigned int kw = *(const unsigned int*)(qkv + base + 1024);
      float k0 = b2f((unsigned short)kw);
      float k1 = b2f((unsigned short)(kw >> 16));
      float ks = k0 * k0 + k1 * k1;
#pragma unroll
      for (int o = 1; o < 32; o <<= 1) ks += __shfl_xor(ks, o);
      float rkn = 1.0f / fmaxf(sqrtf(ks), 1e-12f);
      float kn0 = k0 * rkn, kn1 = k1 * rkn;
      *(unsigned int*)(ko + ((size_t)(b * NHQ + h) * KPAD + i) * 64 + d0) =
          cvtpk_bf16(r0 * kn0 - r1 * kn1, r1 * kn0 + r0 * kn1);
      // v
      unsigned int vw = *(const unsigned int*)(qkv + base + 2048);
      v0 = b2f((unsigned short)vw) + vb2.x;
      v1 = b2f((unsigned short)(vw >> 16)) + vb2.y;
    }
    vtile[d0 * 68 + il] = f2b(v0);
    vtile[(d0 + 1) * 68 + il] = f2b(v1);
  }
  __syncthreads();
  int row = tid >> 2, c0 = (tid & 3) * 16;
  s16x8 o0, o1;
#pragma unroll
  for (int jj = 0; jj < 8; ++jj) {
    o0[jj] = (short)vtile[row * 68 + c0 + jj];
    o1[jj] = (short)vtile[row * 68 + c0 + 8 + jj];
  }
  size_t doff = ((size_t)((b * NHQ + h) * 64 + row)) * KPAD + (size_t)tile * 64 + c0;
  *(s16x8*)(vt + doff) = o0;
  *(s16x8*)(vt + doff + 8) = o1;
}

// ---------------- flash attention ----------------
// R13: z=3 part split (tiles 9/9/8) -> 1248 blocks, avg ~4 resident blocks/CU
// (was 832 -> 3.25). Blocks stay fat (>=8 tiles). Loop body = proven R4 structure.
__global__ __launch_bounds__(256, 4) void k_attn(const unsigned short* __restrict__ qb,
                                                 const unsigned short* __restrict__ kb,
                                                 const unsigned short* __restrict__ vtb,
                                                 const float* __restrict__ sml,
                                                 unsigned short* __restrict__ pO,
                                                 float* __restrict__ pl) {
  int qt = blockIdx.x; int bh = blockIdx.y; int part = blockIdx.z;
  int b = bh >> 4, h = bh & 15;
  int t0 = part * 9;
  int t1 = (part == 2) ? 26 : t0 + 9;
  int q0 = qt * 128;
  int tid = threadIdx.x, w = tid >> 6, lane = tid & 63, quad = lane >> 4, l15 = lane & 15;
  float M = __expf(fminf(sml[h], 4.6051702f)) * 1.4426950408889634f;  // log2-domain shift
  __shared__ __align__(16) unsigned short Kt[64 * 72];     //  9216 B
  __shared__ __align__(16) unsigned short Vt[64 * 72];     //  9216 B
  __shared__ __align__(16) unsigned short Pq[4][32 * 72];  // 18432 B (total 36864 -> 4 blk/CU)
  unsigned short* Pw = Pq[w];
  const unsigned short* qbase = qb + (size_t)(b * NHQ + h) * KPAD * 64;
  const unsigned short* kbase = kb + (size_t)(b * NHQ + h) * KPAD * 64;
  const unsigned short* vbase = vtb + (size_t)(b * NHQ + h) * 64 * KPAD;

  // staging geometry: 512 s16x8 chunks per K (and V) tile, 2 per thread
  int r0 = tid >> 3, c0 = tid & 7;            // chunk 0: rows 0..31
  int r1 = 32 + r0, c1 = c0;                  // chunk 1: rows 32..63

  // Q as B-operand: n=l15 -> q row; k = kb2*32 + quad*8
  s16x8 qf[2][2];
#pragma unroll
  for (int qtile = 0; qtile < 2; ++qtile)
#pragma unroll
    for (int kb2 = 0; kb2 < 2; ++kb2) {
      int row = q0 + w * 32 + qtile * 16 + l15;
      qf[qtile][kb2] = *(const s16x8*)(qbase + (size_t)row * 64 + kb2 * 32 + quad * 8);
    }

  float lsum[2] = {0.f, 0.f};
  fx4 oacc[2][4];
#pragma unroll
  for (int qtile = 0; qtile < 2; ++qtile)
#pragma unroll
    for (int dt = 0; dt < 4; ++dt) oacc[qtile][dt] = (fx4){0.f, 0.f, 0.f, 0.f};

  // prologue: issue tile t0's loads (T14 async-STAGE split)
  s16x8 kn0, kn1, vn0, vn1;
  {
    int j0 = t0 * 64;
    kn0 = *(const s16x8*)(kbase + (size_t)(j0 + r0) * 64 + c0 * 8);
    kn1 = *(const s16x8*)(kbase + (size_t)(j0 + r1) * 64 + c1 * 8);
    vn0 = *(const s16x8*)(vbase + (size_t)r0 * KPAD + j0 + c0 * 8);
    vn1 = *(const s16x8*)(vbase + (size_t)r1 * KPAD + j0 + c1 * 8);
  }

  for (int t = t0; t < t1; ++t) {
    int j0 = t * 64;
    bool tail = (j0 + 64 > KSEL);
    __builtin_amdgcn_s_barrier();    // all waves done reading prev Kt/Vt
    *(s16x8*)(Kt + r0 * 72 + c0 * 8) = kn0;
    *(s16x8*)(Kt + r1 * 72 + c1 * 8) = kn1;
    *(s16x8*)(Vt + r0 * 72 + c0 * 8) = vn0;
    *(s16x8*)(Vt + r1 * 72 + c1 * 8) = vn1;
    // issue next tile's loads; they stay in flight under this tile's compute
    if (t + 1 < t1) {
      int jn = (t + 1) * 64;
      kn0 = *(const s16x8*)(kbase + (size_t)(jn + r0) * 64 + c0 * 8);
      kn1 = *(const s16x8*)(kbase + (size_t)(jn + r1) * 64 + c1 * 8);
      vn0 = *(const s16x8*)(vbase + (size_t)r0 * KPAD + jn + c0 * 8);
      vn1 = *(const s16x8*)(vbase + (size_t)r1 * KPAD + jn + c1 * 8);
    }
    asm volatile("s_waitcnt lgkmcnt(0)" ::: "memory");   // ds_writes visible
    __builtin_amdgcn_s_barrier();

    // S^T -> exp2 -> wave-private P -> PV
    fx4 sacc[2][4];
#pragma unroll
    for (int qtile = 0; qtile < 2; ++qtile)
#pragma unroll
      for (int jj = 0; jj < 4; ++jj) sacc[qtile][jj] = (fx4){0.f, 0.f, 0.f, 0.f};
    __builtin_amdgcn_s_setprio(1);
#pragma unroll
    for (int jj = 0; jj < 4; ++jj) {
      int jl = jj * 16 + l15;
      s16x8 kf0 = *(const s16x8*)(Kt + jl * 72 + quad * 8);
      s16x8 kf1 = *(const s16x8*)(Kt + jl * 72 + 32 + quad * 8);
      sacc[0][jj] = MFMA16(kf0, qf[0][0], sacc[0][jj]);
      sacc[1][jj] = MFMA16(kf0, qf[1][0], sacc[1][jj]);
      sacc[0][jj] = MFMA16(kf1, qf[0][1], sacc[0][jj]);
      sacc[1][jj] = MFMA16(kf1, qf[1][1], sacc[1][jj]);
    }
    __builtin_amdgcn_s_setprio(0);
#pragma unroll
    for (int qtile = 0; qtile < 2; ++qtile)
#pragma unroll
      for (int jj = 0; jj < 4; ++jj) {
        int jbase = j0 + jj * 16 + quad * 4;
        fx4 sv = sacc[qtile][jj];
        float p0 = fexp2(sv[0] - M);
        float p1 = fexp2(sv[1] - M);
        float p2 = fexp2(sv[2] - M);
        float p3 = fexp2(sv[3] - M);
        if (tail) {
          if (jbase + 0 >= KSEL) p0 = 0.f;
          if (jbase + 1 >= KSEL) p1 = 0.f;
          if (jbase + 2 >= KSEL) p2 = 0.f;
          if (jbase + 3 >= KSEL) p3 = 0.f;
        }
        lsum[qtile] += (p0 + p1) + (p2 + p3);
        *(uint2*)(Pw + (qtile * 16 + l15) * 72 + jj * 16 + quad * 4) =
            make_uint2(cvtpk_bf16(p0, p1), cvtpk_bf16(p2, p3));
      }
    // PV: A=P (wave-private LDS), B=V (LDS)
    __builtin_amdgcn_s_setprio(1);
#pragma unroll
    for (int js = 0; js < 2; ++js) {
      s16x8 pf0 = *(const s16x8*)(Pw + l15 * 72 + js * 32 + quad * 8);
      s16x8 pf1 = *(const s16x8*)(Pw + (16 + l15) * 72 + js * 32 + quad * 8);
#pragma unroll
      for (int dt = 0; dt < 4; ++dt) {
        s16x8 vf = *(const s16x8*)(Vt + (dt * 16 + l15) * 72 + js * 32 + quad * 8);
        oacc[0][dt] = MFMA16(pf0, vf, oacc[0][dt]);
        oacc[1][dt] = MFMA16(pf1, vf, oacc[1][dt]);
      }
    }
    __builtin_amdgcn_s_setprio(0);
  }

  // combine quad-partitioned j-sums (lanes l15, +16, +32, +48 hold disjoint j sets)
#pragma unroll
  for (int qtile = 0; qtile < 2; ++qtile) {
    float s = lsum[qtile];
    s += __shfl_xor(s, 16);
    s += __shfl_xor(s, 32);
    lsum[qtile] = s;
  }

  size_t pbase = (((size_t)part * 2 + b) * NHQ + h) * KPAD;
#pragma unroll
  for (int qtile = 0; qtile < 2; ++qtile) {
    int gqb = q0 + w * 32 + qtile * 16;
    if (quad == 0) pl[pbase + gqb + l15] = lsum[qtile];
  }

  // transpose O through the (now free) wave-private P buffer -> coalesced stores
#pragma unroll
  for (int qtile = 0; qtile < 2; ++qtile)
#pragma unroll
    for (int dt = 0; dt < 4; ++dt)
#pragma unroll
      for (int r = 0; r < 4; ++r)
        Pw[(qtile * 16 + quad * 4 + r) * 72 + dt * 16 + l15] = f2b(oacc[qtile][dt][r]);
#pragma unroll
  for (int pass = 0; pass < 4; ++pass) {
    int row = pass * 8 + (lane >> 3), chunk = lane & 7;
    s16x8 vv = *(const s16x8*)(Pw + row * 72 + chunk * 8);
    *(s16x8*)(pO + (pbase + q0 + w * 32 + row) * 64 + chunk * 8) = vv;
  }
}

// ---------------- combine the three j-parts (vectorized x8): o = sum(O_p)/sum(l_p) ---------
__global__ __launch_bounds__(256) void k_comb(const unsigned short* __restrict__ pO,
                                              const float* __restrict__ pl,
                                              unsigned short* __restrict__ ob) {
  size_t g8 = (size_t)blockIdx.x * 256 + threadIdx.x;  // 425984 = 3407872/8
  size_t base = g8 * 8;
  int d0 = (int)(base & 63);
  size_t row = base >> 6;           // (b*16+h)*1664 + gq
  int gq = (int)(row % KPAD);
  int bhh = (int)(row / KPAD);
  int b = bhh >> 4, h = bhh & 15;
  uint4 p0 = *(const uint4*)(pO + base);
  uint4 p1 = *(const uint4*)(pO + base + 3407872);
  uint4 p2 = *(const uint4*)(pO + base + 2 * 3407872);
  float ls = pl[row] + pl[row + 53248] + pl[row + 2 * 53248];
  float rc = 1.0f / ls;
  unsigned int pw0[4] = {p0.x, p0.y, p0.z, p0.w};
  unsigned int pw1[4] = {p1.x, p1.y, p1.z, p1.w};
  unsigned int pw2[4] = {p2.x, p2.y, p2.z, p2.w};
  unsigned int ow[4];
#pragma unroll
  for (int j = 0; j < 4; ++j) {
    float lo = (b2f((unsigned short)pw0[j]) + b2f((unsigned short)pw1[j]) +
                b2f((unsigned short)pw2[j])) * rc;
    float hi = (b2f((unsigned short)(pw0[j] >> 16)) + b2f((unsigned short)(pw1[j] >> 16)) +
                b2f((unsigned short)(pw2[j] >> 16))) * rc;
    ow[j] = cvtpk_bf16(lo, hi);
  }
  *(uint4*)(ob + ((size_t)(b * KPAD + gq)) * CQ + h * 64 + d0) =
      make_uint4(ow[0], ow[1], ow[2], ow[3]);
}

extern "C" void kernel_launch(void* const* d_in, const int* in_sizes, int n_in,
                              void* d_out, int out_size, void* d_ws, size_t ws_size,
                              hipStream_t stream) {
  const float* x      = (const float*)d_in[0];
  const float* cached = (const float*)d_in[1];
  const float* wqkv   = (const float*)d_in[2];
  const float* qbias  = (const float*)d_in[3];
  const float* vbias  = (const float*)d_in[4];
  const float* wproj  = (const float*)d_in[5];
  const float* bproj  = (const float*)d_in[6];
  const float* sml    = (const float*)d_in[7];
  const float* rope   = (const float*)d_in[8];
  float* out = (float*)d_out;
  char* ws = (char*)d_ws;

  double* meanpart        = (double*)(ws);                    // 524288
  double* mean            = (double*)(ws + 524288);           // 16384
  double* mse             = (double*)(ws + 540672);           // 65536
  int* idx_sel            = (int*)(ws + 606208);              // 13312 -> 619520
  // overlap zone [619520, 44135424): x_bf + wqkv_bf + qkv (dead after k_normrope)
  unsigned short* x_bf    = (unsigned short*)(ws + 619520);   // 16777216
  unsigned short* wqkv_bf = (unsigned short*)(ws + 17396736); // 6291456
  unsigned short* qkv     = (unsigned short*)(ws + 23688192); // 20447232 -> 44135424
  // attn partials (3 parts) reuse the dead x_bf/wqkv_bf/qkv region
  unsigned short* pO      = (unsigned short*)(ws + 619520);   // 20447232
  float* pl               = (float*)(ws + 21066752);          // 638976 -> 21705728
  unsigned short* wproj_bf= (unsigned short*)(ws + 44135424); // 2097152
  unsigned short* qo      = (unsigned short*)(ws + 46232576); // 6815744
  unsigned short* ko      = (unsigned short*)(ws + 53048320); // 6815744
  unsigned short* vt      = (unsigned short*)(ws + 59864064); // 6815744
  unsigned short* ob      = (unsigned short*)(ws + 66679808); // 6815744 -> 73495552

  hipLaunchKernelGGL(k_mean_part, dim3(256), dim3(256), 0, stream, x, meanpart);
  hipLaunchKernelGGL(k_mean_reduce, dim3(8), dim3(256), 0, stream, meanpart, mean);
  hipLaunchKernelGGL(k_mse_base, dim3(8192), dim3(256), 0, stream, x, cached, mean, mse,
                     out, x_bf);
  hipLaunchKernelGGL(k_topk, dim3(2 + 1024), dim3(1024), 0, stream, mse, idx_sel,
                     wqkv, wproj, wqkv_bf, wproj_bf);
  hipLaunchKernelGGL(k_gemmA, dim3(52 * 24), dim3(256), 0, stream,
                     x_bf, wqkv_bf, idx_sel, qkv);
  hipLaunchKernelGGL(k_normrope, dim3(26 * 16 * BQ), dim3(256), 0, stream,
                     qkv, idx_sel, qbias, vbias, sml, rope, qo, ko, vt);
  hipLaunchKernelGGL(k_attn, dim3(13, BQ * NHQ, 3), dim3(256), 0, stream,
                     qo, ko, vt, sml, pO, pl);
  hipLaunchKernelGGL(k_comb, dim3(1664), dim3(256), 0, stream, pO, pl, ob);
  hipLaunchKernelGGL(k_gemmB, dim3(832), dim3(256), 0, stream,
                     ob, wproj_bf, idx_sel, out, x, bproj);
}

// Round 10
// 277.057 us; speedup vs baseline: 1.0480x; 1.0007x over previous
//
#include <hip/hip_runtime.h>
#include <hip/hip_bf16.h>
#include <math.h>

// Problem constants (setup_inputs)
#define BQ   2
#define LQ   4096
#define CQ   1024
#define NHQ  16
#define DHQ  64
#define KSEL 1638
#define KPAD 1664
#define MTOT (BQ*KSEL)   // 3276
#define MPAD 3328        // 26*128

typedef short s16x8 __attribute__((ext_vector_type(8)));
typedef float fx4   __attribute__((ext_vector_type(4)));

#define MFMA16(a,b,c) __builtin_amdgcn_mfma_f32_16x16x32_bf16(a,b,c,0,0,0)

__device__ __forceinline__ float b2f(unsigned short u) {
  union { float f; unsigned int i; } cv; cv.i = ((unsigned int)u) << 16; return cv.f;
}
__device__ __forceinline__ unsigned short f2b(float f) {
  union { float f; unsigned int i; } cv; cv.f = f;
  unsigned int x = cv.i;
  return (unsigned short)((x + 0x7fffu + ((x >> 16) & 1u)) >> 16);
}
__device__ __forceinline__ unsigned int fbits(float f) {
  union { float f; unsigned int i; } cv; cv.f = f; return cv.i;
}
// packed f32x2 -> bf16x2 (RNE), single VALU op
__device__ __forceinline__ unsigned int cvtpk_bf16(float a, float b) {
  unsigned int r;
  asm("v_cvt_pk_bf16_f32 %0, %1, %2" : "=v"(r) : "v"(a), "v"(b));
  return r;
}
__device__ __forceinline__ void async16(const void* g, void* l) {
  __builtin_amdgcn_global_load_lds((const __attribute__((address_space(1))) void*)g,
                                   (__attribute__((address_space(3))) void*)l, 16, 0, 0);
}
// raw 2^x (q is pre-scaled by log2(e) in k_normrope, M is in log2 units)
__device__ __forceinline__ float fexp2(float x) {
#if __has_builtin(__builtin_amdgcn_exp2f)
  return __builtin_amdgcn_exp2f(x);
#else
  return __expf(x * 0.69314718055994531f);
#endif
}

// ---------------- mean (fp64, 2-stage) ----------------
__global__ __launch_bounds__(256) void k_mean_part(const float* __restrict__ x,
                                                   double* __restrict__ part) {
  int bid = blockIdx.x;                    // 256 blocks: [b(2)][ch(32)][cb(4)]
  int cb = bid & 3, ch = (bid >> 2) & 31, b = bid >> 7;
  int c = cb * 256 + threadIdx.x;
  const float* p = x + ((size_t)b * LQ + (size_t)ch * 128) * CQ + c;
  double s = 0.0;
  for (int r = 0; r < 128; ++r) s += (double)p[(size_t)r * CQ];
  part[((size_t)b * 32 + ch) * CQ + c] = s;
}

__global__ __launch_bounds__(256) void k_mean_reduce(const double* __restrict__ part,
                                                     double* __restrict__ mean) {
  int g = blockIdx.x * 256 + threadIdx.x;  // 2048 = B*C
  int b = g >> 10, c = g & 1023;
  double s = 0.0;
  for (int ch = 0; ch < 32; ++ch) s += part[((size_t)b * 32 + ch) * CQ + c];
  mean[g] = s * (1.0 / 4096.0);
}

// ---------------- mse (fp64) + base output (x + upsample(cached)) + x->bf16 ----------------
__global__ __launch_bounds__(256) void k_mse_base(const float* __restrict__ x,
                                                  const float* __restrict__ cached,
                                                  const double* __restrict__ mean,
                                                  double* __restrict__ mse,
                                                  float* __restrict__ out,
                                                  unsigned short* __restrict__ xb) {
  int bl = blockIdx.x; int b = bl >> 12, l = bl & 4095;
  int hh = l >> 6, ww = l & 63;
  size_t xoff = ((size_t)b * LQ + l) * CQ;
  size_t uoff = (((size_t)b * 32 + (hh >> 1)) * 32 + (ww >> 1)) * CQ;
  const double* mrow = mean + (size_t)b * CQ;
  int c0 = threadIdx.x * 4;
  float4 xv = *(const float4*)(x + xoff + c0);
  float4 uv = *(const float4*)(cached + uoff + c0);
  float4 ov;
  ov.x = xv.x + uv.x; ov.y = xv.y + uv.y; ov.z = xv.z + uv.z; ov.w = xv.w + uv.w;
  *(float4*)(out + xoff + c0) = ov;
  ushort4 xo;
  xo.x = f2b(xv.x); xo.y = f2b(xv.y); xo.z = f2b(xv.z); xo.w = f2b(xv.w);
  ((ushort4*)xb)[(xoff + c0) >> 2] = xo;
  double d0 = (double)xv.x - mrow[c0];
  double d1 = (double)xv.y - mrow[c0 + 1];
  double d2 = (double)xv.z - mrow[c0 + 2];
  double d3 = (double)xv.w - mrow[c0 + 3];
  double ss = d0 * d0 + d1 * d1 + d2 * d2 + d3 * d3;
  for (int o = 1; o < 64; o <<= 1) ss += __shfl_xor(ss, o);
  __shared__ double ws4[4];
  if ((threadIdx.x & 63) == 0) ws4[threadIdx.x >> 6] = ss;
  __syncthreads();
  if (threadIdx.x == 0) mse[(size_t)b * LQ + l] = ws4[0] + ws4[1] + ws4[2] + ws4[3];
}

// ---------------- top-k (blocks 0,1) + fused weight fp32->bf16 conversion (blocks >=2) ----
__global__ __launch_bounds__(1024) void k_topk(const double* __restrict__ mse,
                                               int* __restrict__ idx_sel,
                                               const float* __restrict__ wqkv,
                                               const float* __restrict__ wproj,
                                               unsigned short* __restrict__ wqb,
                                               unsigned short* __restrict__ wpb) {
  if (blockIdx.x >= 2) {   // conversion path: 1024 blocks x 1024 thr x 1 float4
    int i = (blockIdx.x - 2) * 1024 + threadIdx.x;
    const float* s; unsigned short* d; int off;
    if (i < 786432) { s = wqkv;  d = wqb; off = i; }
    else            { s = wproj; d = wpb; off = i - 786432; }
    float4 v = ((const float4*)s)[off];
    ushort4 o;
    o.x = f2b(v.x); o.y = f2b(v.y); o.z = f2b(v.z); o.w = f2b(v.w);
    ((ushort4*)d)[off] = o;
    return;
  }
  __shared__ unsigned long long u[4096];       // 32 KB
  __shared__ unsigned int whist[16 * 257];     // 16.4 KB, stride 257 => cross-wave bank skew
  __shared__ unsigned int wtot[4];
  __shared__ unsigned long long sh_prefix;
  __shared__ int sh_rem, sh_rem2, sh_bsel, sh_cnt, sh_eqcnt;
  __shared__ int eqbuf[256];
  int b = blockIdx.x, t = threadIdx.x;
  int wv = t >> 6, laneid = t & 63;
  for (int p = 0; p < 4; ++p) {
    int i = p * 1024 + t;
    u[i] = (unsigned long long)__double_as_longlong(mse[(size_t)b * LQ + i]);
  }
  if (t == 0) { sh_prefix = 0ULL; sh_rem = KSEL; sh_cnt = 0; sh_eqcnt = 0; }
  __syncthreads();
  for (int shift = 56; shift >= 0; shift -= 8) {
    for (int z = t; z < 16 * 257; z += 1024) whist[z] = 0u;
    __syncthreads();
    unsigned long long pref = sh_prefix;
#pragma unroll
    for (int p = 0; p < 4; ++p) {
      int i = p * 1024 + t;
      unsigned long long v = u[i];
      bool cand = (shift == 56) || ((v >> ((shift + 8) & 63)) == pref);
      if (cand) atomicAdd(&whist[wv * 257 + ((unsigned int)(v >> shift) & 255u)], 1u);
    }
    __syncthreads();
    unsigned int myc = 0, mysc = 0;
    if (t < 256) {            // combine the 16 wave hists for my bin (bin = 255 - t)
      unsigned int s = 0;
      int bin = 255 - t;
#pragma unroll
      for (int wvi = 0; wvi < 16; ++wvi) s += whist[wvi * 257 + bin];
      myc = s;
      mysc = myc;
#pragma unroll
      for (int o = 1; o < 64; o <<= 1) {
        unsigned int v2 = __shfl_up(mysc, o);
        if (laneid >= o) mysc += v2;
      }
      if (laneid == 63) wtot[wv] = mysc;
    }
    __syncthreads();
    if (t < 256) {
      unsigned int basep = 0;
      for (int wvi = 0; wvi < wv; ++wvi) basep += wtot[wvi];
      unsigned int incl = basep + mysc;       // count of keys in bins >= my bin
      unsigned int excl = incl - myc;         // count of keys in bins >  my bin
      unsigned int rem = (unsigned int)sh_rem;
      if (excl < rem && rem <= incl) {        // exactly one thread crosses
        sh_bsel = 255 - t;
        sh_rem2 = (int)(rem - excl);
      }
    }
    __syncthreads();
    if (t == 0) {
      sh_prefix = (sh_prefix << 8) | (unsigned long long)sh_bsel;
      sh_rem = sh_rem2;
    }
    __syncthreads();
  }
  unsigned long long T = sh_prefix;
  int rem_eq = sh_rem;
#pragma unroll
  for (int p = 0; p < 4; ++p) {
    int i = p * 1024 + t;
    unsigned long long v = u[i];
    bool win = (v > T);
    unsigned long long mask = __ballot(win);
    int total = __popcll(mask);
    int base = 0;
    if (laneid == 0 && total > 0) base = atomicAdd(&sh_cnt, total);
    base = __shfl(base, 0);
    if (win) {
      int lpos = __popcll(mask & ((1ULL << laneid) - 1ULL));
      idx_sel[b * KPAD + base + lpos] = i;
    }
    if (v == T) {
      int e = atomicAdd(&sh_eqcnt, 1);
      if (e < 256) eqbuf[e] = i;
    }
  }
  __syncthreads();
  if (t == 0) {
    int n = sh_eqcnt; if (n > 256) n = 256;
    for (int a = 1; a < n; ++a) {           // ascending index sort (ties: smallest index wins)
      int key = eqbuf[a]; int c = a - 1;
      while (c >= 0 && eqbuf[c] > key) { eqbuf[c + 1] = eqbuf[c]; --c; }
      eqbuf[c + 1] = key;
    }
    int base = sh_cnt;
    for (int a = 0; a < rem_eq && a < n; ++a) idx_sel[b * KPAD + base + a] = eqbuf[a];
    for (int a = KSEL; a < KPAD; ++a) idx_sel[b * KPAD + a] = 0;
  }
}

// ---------------- qkv GEMM (64x128, BK=32), 1248 blocks, depth-2 prefetch ----------------
// R16: restore R10's depth-2 pipeline on the 64x128 shape (R12 dropped it).
// 3 rotating 12KB buffers (36KB LDS -> 4 blk/CU, >= grid residency), issue stage
// it+2, wait vmcnt(6): the awaited stage has 2 full iterations (~600cy) in flight
// vs depth-1's ~300cy against ~900cy HBM latency. + XCD swizzle (1248 = 8*156).
__global__ __launch_bounds__(256) void k_gemmA(const unsigned short* __restrict__ Asrc,
                                               const unsigned short* __restrict__ Bmat,
                                               const int* __restrict__ idx_sel,
                                               unsigned short* __restrict__ Cbf) {
  int bid = blockIdx.x;
  int swz = (bid & 7) * 156 + (bid >> 3);   // XCD-contiguous chunks
  int bm = swz % 52, bn = swz / 52;
  int tid = threadIdx.x;
  int w = tid >> 6, lane = tid & 63, quad = lane >> 4, l15 = lane & 15;
  int wm = w & 1, wn = w >> 1;
  __shared__ __align__(16) unsigned char sm[3][12288];   // A [64][32]bf16, B [128][32]bf16

  const unsigned short* gA;
  {
    int row = tid >> 2, kc = tid & 3;
    int m = bm * 64 + row; if (m >= MTOT) m = MTOT - 1;
    int bb = m / KSEL; int ii = m - bb * KSEL;
    int lsel = idx_sel[bb * KPAD + ii];
    gA = Asrc + ((size_t)bb * LQ + lsel) * CQ + kc * 8;
  }
  const unsigned short* gB[2];
#pragma unroll
  for (int p = 0; p < 2; ++p) {
    int e = p * 256 + tid; int row = e >> 2, kc = e & 3;
    gB[p] = Bmat + (size_t)(bn * 128 + row) * CQ + kc * 8;
  }

  fx4 acc[2][4];
#pragma unroll
  for (int a = 0; a < 2; ++a)
#pragma unroll
    for (int c = 0; c < 4; ++c) acc[a][c] = (fx4){0.f, 0.f, 0.f, 0.f};

#define STAGE_A(boff, it) do { int ke = (it) * 32;                                  \
    async16(gA + ke, sm[0] + (boff) + tid * 16);                                    \
    async16(gB[0] + ke, sm[0] + (boff) + 4096 + tid * 16);                          \
    async16(gB[1] + ke, sm[0] + (boff) + 8192 + tid * 16); } while (0)

  STAGE_A(0, 0);
  STAGE_A(12288, 1);
  for (int it = 0; it < 32; ++it) {
    int cur = it % 3;
    if (it + 2 < 32) STAGE_A(((it + 2) % 3) * 12288, it + 2);
    if (it <= 29)      asm volatile("s_waitcnt vmcnt(6)");
    else if (it == 30) asm volatile("s_waitcnt vmcnt(3)");
    else               asm volatile("s_waitcnt vmcnt(0)");
    __builtin_amdgcn_s_barrier();
    const unsigned char* smb = sm[0] + cur * 12288;
    s16x8 af[2], bf[4];
#pragma unroll
    for (int mt = 0; mt < 2; ++mt)
      af[mt] = *(const s16x8*)(smb + ((wm * 32 + mt * 16 + l15) * 32 + quad * 8) * 2);
#pragma unroll
    for (int nt = 0; nt < 4; ++nt)
      bf[nt] = *(const s16x8*)(smb + 4096 + ((wn * 64 + nt * 16 + l15) * 32 + quad * 8) * 2);
    __builtin_amdgcn_s_setprio(1);
#pragma unroll
    for (int mt = 0; mt < 2; ++mt)
#pragma unroll
      for (int nt = 0; nt < 4; ++nt)
        acc[mt][nt] = MFMA16(af[mt], bf[nt], acc[mt][nt]);
    __builtin_amdgcn_s_setprio(0);
    __builtin_amdgcn_s_barrier();    // all waves done reading cur before it's re-staged
  }
#undef STAGE_A

#pragma unroll
  for (int mt = 0; mt < 2; ++mt)
#pragma unroll
    for (int nt = 0; nt < 4; ++nt) {
      int n = bn * 128 + wn * 64 + nt * 16 + l15;
      int mbase = bm * 64 + wm * 32 + mt * 16 + quad * 4;
      fx4 vv = acc[mt][nt];
#pragma unroll
      for (int r = 0; r < 4; ++r) {
        int m = mbase + r;
        if (m < MTOT) Cbf[(size_t)m * 3072 + n] = f2b(vv[r]);
      }
    }
}

// ---------------- proj GEMM (64x64, BK=64) : 832 blocks, dbuf prefetch ----------------
__global__ __launch_bounds__(256) void k_gemmB(const unsigned short* __restrict__ Asrc,
                                               const unsigned short* __restrict__ Bmat,
                                               const int* __restrict__ idx_sel,
                                               float* __restrict__ Cf,
                                               const float* __restrict__ xin,
                                               const float* __restrict__ bproj) {
  int bid = blockIdx.x;
  int swz = (bid & 7) * 104 + (bid >> 3);   // XCD-contiguous chunks (832 = 8*104)
  int bm = swz % 52, bn = swz / 52;
  int tid = threadIdx.x;
  int w = tid >> 6, lane = tid & 63, quad = lane >> 4, l15 = lane & 15;
  int wm = w & 1, wn = w >> 1;
  __shared__ __align__(16) unsigned char sm[2][16384];   // A [64][64]bf16, B [64][64]bf16

  const unsigned short* g4[4];
#pragma unroll
  for (int p = 0; p < 4; ++p) {
    int e = (p & 1) * 256 + tid; int row = e >> 3, kc = e & 7;
    if (p < 2) {
      int m = bm * 64 + row; if (m >= MTOT) m = MTOT - 1;
      int bb = m / KSEL; int ii = m - bb * KSEL;
      g4[p] = Asrc + ((size_t)bb * KPAD + ii) * CQ + kc * 8;
    } else {
      g4[p] = Bmat + (size_t)(bn * 64 + row) * CQ + kc * 8;
    }
  }

  fx4 acc[2][2];
#pragma unroll
  for (int a = 0; a < 2; ++a)
#pragma unroll
    for (int c = 0; c < 2; ++c) acc[a][c] = (fx4){0.f, 0.f, 0.f, 0.f};

#define STAGE_B(buf, it) do { int ke = (it) * 64;                                   \
    _Pragma("unroll")                                                               \
    for (int p = 0; p < 4; ++p)                                                     \
      async16(g4[p] + ke, sm[buf] + p * 4096 + w * 1024);                           \
    } while (0)

  STAGE_B(0, 0);
  for (int it = 0; it < 16; ++it) {
    int cur = it & 1;
    if (it < 15) STAGE_B(cur ^ 1, it + 1);
    if (it < 15) asm volatile("s_waitcnt vmcnt(4)");
    else         asm volatile("s_waitcnt vmcnt(0)");
    __builtin_amdgcn_s_barrier();
    const unsigned char* smb = sm[cur];
#pragma unroll
    for (int kk = 0; kk < 2; ++kk) {
      s16x8 af[2], bf2[2];
#pragma unroll
      for (int mt = 0; mt < 2; ++mt)
        af[mt] = *(const s16x8*)(smb + ((wm * 32 + mt * 16 + l15) * 64 + kk * 32 + quad * 8) * 2);
#pragma unroll
      for (int nt = 0; nt < 2; ++nt)
        bf2[nt] = *(const s16x8*)(smb + 8192 + ((wn * 32 + nt * 16 + l15) * 64 + kk * 32 + quad * 8) * 2);
#pragma unroll
      for (int mt = 0; mt < 2; ++mt)
#pragma unroll
        for (int nt = 0; nt < 2; ++nt)
          acc[mt][nt] = MFMA16(af[mt], bf2[nt], acc[mt][nt]);
    }
    __builtin_amdgcn_s_barrier();    // all waves done reading cur before it's re-staged
  }
#undef STAGE_B

#pragma unroll
  for (int mt = 0; mt < 2; ++mt)
#pragma unroll
    for (int nt = 0; nt < 2; ++nt) {
      int n = bn * 64 + wn * 32 + nt * 16 + l15;
      int mbase = bm * 64 + wm * 32 + mt * 16 + quad * 4;
      fx4 vv = acc[mt][nt];
      float bp = bproj[n];
#pragma unroll
      for (int r = 0; r < 4; ++r) {
        int m = mbase + r;
        if (m < MTOT) {
          int bb = m / KSEL; int ii = m - bb * KSEL;
          int lsel = idx_sel[bb * KPAD + ii];
          size_t off = ((size_t)bb * LQ + lsel) * CQ + n;
          Cf[off] = xin[off] + vv[r] + bp;
        }
      }
    }
}

// ---------------- l2norm + scale + rope -> q,k ; v -> Vt (transposed) ----------------
__global__ __launch_bounds__(256) void k_normrope(const unsigned short* __restrict__ qkv,
                                                  const int* __restrict__ idx_sel,
                                                  const float* __restrict__ qbias,
                                                  const float* __restrict__ vbias,
                                                  const float* __restrict__ sml,
                                                  const float* __restrict__ rope,
                                                  unsigned short* __restrict__ qo,
                                                  unsigned short* __restrict__ ko,
                                                  unsigned short* __restrict__ vt) {
  int bid = blockIdx.x;                       // 26*16*2
  int tile = bid % 26; int h = (bid / 26) & 15; int b = bid / (26 * 16);
  int tid = threadIdx.x; int w = tid >> 6; int lane = tid & 63;
  int tk = lane >> 5, dl = lane & 31;         // token-half, d-pair index
  int d0 = dl * 2;
  __shared__ unsigned short vtile[64 * 68];
  float scale = expf(fminf(sml[h], 4.6051702f)) * 1.4426950408889634f;
  float2 qb2 = *(const float2*)(qbias + h * 64 + d0);
  float2 vb2 = *(const float2*)(vbias + h * 64 + d0);
  for (int pass = 0; pass < 8; ++pass) {
    int il = pass * 8 + w * 2 + tk;
    int i = tile * 64 + il;
    float v0 = 0.f, v1 = 0.f;
    if (i < KSEL) {
      int lsel = idx_sel[b * KPAD + i];
      size_t base = ((size_t)(b * KSEL + i)) * 3072 + h * 64 + d0;
      float r0 = rope[(size_t)lsel * 32 + dl];
      float r1 = rope[(size_t)LQ * 32 + (size_t)lsel * 32 + dl];
      // q
      unsigned int qw = *(const unsigned int*)(qkv + base);
      float q0 = b2f((unsigned short)qw) + qb2.x;
      float q1 = b2f((unsigned short)(qw >> 16)) + qb2.y;
      float ss = q0 * q0 + q1 * q1;
#pragma unroll
      for (int o = 1; o < 32; o <<= 1) ss += __shfl_xor(ss, o);
      float rn = scale / fmaxf(sqrtf(ss), 1e-12f);
      float qn0 = q0 * rn, qn1 = q1 * rn;
      *(unsigned int*)(qo + ((size_t)(b * NHQ + h) * KPAD + i) * 64 + d0) =
          cvtpk_bf16(r0 * qn0 - r1 * qn1, r1 * qn0 + r0 * qn1);
      // k
      unsigned int kw = *(const unsigned int*)(qkv + base + 1024);
      float k0 = b2f((unsigned short)kw);
      float k1 = b2f((unsigned short)(kw >> 16));
      float ks = k0 * k0 + k1 * k1;
#pragma unroll
      for (int o = 1; o < 32; o <<= 1) ks += __shfl_xor(ks, o);
      float rkn = 1.0f / fmaxf(sqrtf(ks), 1e-12f);
      float kn0 = k0 * rkn, kn1 = k1 * rkn;
      *(unsigned int*)(ko + ((size_t)(b * NHQ + h) * KPAD + i) * 64 + d0) =
          cvtpk_bf16(r0 * kn0 - r1 * kn1, r1 * kn0 + r0 * kn1);
      // v
      unsigned int vw = *(const unsigned int*)(qkv + base + 2048);
      v0 = b2f((unsigned short)vw) + vb2.x;
      v1 = b2f((unsigned short)(vw >> 16)) + vb2.y;
    }
    vtile[d0 * 68 + il] = f2b(v0);
    vtile[(d0 + 1) * 68 + il] = f2b(v1);
  }
  __syncthreads();
  int row = tid >> 2, c0 = (tid & 3) * 16;
  s16x8 o0, o1;
#pragma unroll
  for (int jj = 0; jj < 8; ++jj) {
    o0[jj] = (short)vtile[row * 68 + c0 + jj];
    o1[jj] = (short)vtile[row * 68 + c0 + 8 + jj];
  }
  size_t doff = ((size_t)((b * NHQ + h) * 64 + row)) * KPAD + (size_t)tile * 64 + c0;
  *(s16x8*)(vt + doff) = o0;
  *(s16x8*)(vt + doff + 8) = o1;
}

// ---------------- flash attention ----------------
// z=3 part split (tiles 9/9/8) -> 1248 blocks, ~4 resident blocks/CU. Loop body =
// proven R4 structure (VGPR 64, T14 async-STAGE, cvt_pk pack, setprio).
__global__ __launch_bounds__(256, 4) void k_attn(const unsigned short* __restrict__ qb,
                                                 const unsigned short* __restrict__ kb,
                                                 const unsigned short* __restrict__ vtb,
                                                 const float* __restrict__ sml,
                                                 unsigned short* __restrict__ pO,
                                                 float* __restrict__ pl) {
  int qt = blockIdx.x; int bh = blockIdx.y; int part = blockIdx.z;
  int b = bh >> 4, h = bh & 15;
  int t0 = part * 9;
  int t1 = (part == 2) ? 26 : t0 + 9;
  int q0 = qt * 128;
  int tid = threadIdx.x, w = tid >> 6, lane = tid & 63, quad = lane >> 4, l15 = lane & 15;
  float M = __expf(fminf(sml[h], 4.6051702f)) * 1.4426950408889634f;  // log2-domain shift
  __shared__ __align__(16) unsigned short Kt[64 * 72];     //  9216 B
  __shared__ __align__(16) unsigned short Vt[64 * 72];     //  9216 B
  __shared__ __align__(16) unsigned short Pq[4][32 * 72];  // 18432 B (total 36864 -> 4 blk/CU)
  unsigned short* Pw = Pq[w];
  const unsigned short* qbase = qb + (size_t)(b * NHQ + h) * KPAD * 64;
  const unsigned short* kbase = kb + (size_t)(b * NHQ + h) * KPAD * 64;
  const unsigned short* vbase = vtb + (size_t)(b * NHQ + h) * 64 * KPAD;

  // staging geometry: 512 s16x8 chunks per K (and V) tile, 2 per thread
  int r0 = tid >> 3, c0 = tid & 7;            // chunk 0: rows 0..31
  int r1 = 32 + r0, c1 = c0;                  // chunk 1: rows 32..63

  // Q as B-operand: n=l15 -> q row; k = kb2*32 + quad*8
  s16x8 qf[2][2];
#pragma unroll
  for (int qtile = 0; qtile < 2; ++qtile)
#pragma unroll
    for (int kb2 = 0; kb2 < 2; ++kb2) {
      int row = q0 + w * 32 + qtile * 16 + l15;
      qf[qtile][kb2] = *(const s16x8*)(qbase + (size_t)row * 64 + kb2 * 32 + quad * 8);
    }

  float lsum[2] = {0.f, 0.f};
  fx4 oacc[2][4];
#pragma unroll
  for (int qtile = 0; qtile < 2; ++qtile)
#pragma unroll
    for (int dt = 0; dt < 4; ++dt) oacc[qtile][dt] = (fx4){0.f, 0.f, 0.f, 0.f};

  // prologue: issue tile t0's loads (T14 async-STAGE split)
  s16x8 kn0, kn1, vn0, vn1;
  {
    int j0 = t0 * 64;
    kn0 = *(const s16x8*)(kbase + (size_t)(j0 + r0) * 64 + c0 * 8);
    kn1 = *(const s16x8*)(kbase + (size_t)(j0 + r1) * 64 + c1 * 8);
    vn0 = *(const s16x8*)(vbase + (size_t)r0 * KPAD + j0 + c0 * 8);
    vn1 = *(const s16x8*)(vbase + (size_t)r1 * KPAD + j0 + c1 * 8);
  }

  for (int t = t0; t < t1; ++t) {
    int j0 = t * 64;
    bool tail = (j0 + 64 > KSEL);
    __builtin_amdgcn_s_barrier();    // all waves done reading prev Kt/Vt
    *(s16x8*)(Kt + r0 * 72 + c0 * 8) = kn0;
    *(s16x8*)(Kt + r1 * 72 + c1 * 8) = kn1;
    *(s16x8*)(Vt + r0 * 72 + c0 * 8) = vn0;
    *(s16x8*)(Vt + r1 * 72 + c1 * 8) = vn1;
    // issue next tile's loads; they stay in flight under this tile's compute
    if (t + 1 < t1) {
      int jn = (t + 1) * 64;
      kn0 = *(const s16x8*)(kbase + (size_t)(jn + r0) * 64 + c0 * 8);
      kn1 = *(const s16x8*)(kbase + (size_t)(jn + r1) * 64 + c1 * 8);
      vn0 = *(const s16x8*)(vbase + (size_t)r0 * KPAD + jn + c0 * 8);
      vn1 = *(const s16x8*)(vbase + (size_t)r1 * KPAD + jn + c1 * 8);
    }
    asm volatile("s_waitcnt lgkmcnt(0)" ::: "memory");   // ds_writes visible
    __builtin_amdgcn_s_barrier();

    // S^T -> exp2 -> wave-private P -> PV
    fx4 sacc[2][4];
#pragma unroll
    for (int qtile = 0; qtile < 2; ++qtile)
#pragma unroll
      for (int jj = 0; jj < 4; ++jj) sacc[qtile][jj] = (fx4){0.f, 0.f, 0.f, 0.f};
    __builtin_amdgcn_s_setprio(1);
#pragma unroll
    for (int jj = 0; jj < 4; ++jj) {
      int jl = jj * 16 + l15;
      s16x8 kf0 = *(const s16x8*)(Kt + jl * 72 + quad * 8);
      s16x8 kf1 = *(const s16x8*)(Kt + jl * 72 + 32 + quad * 8);
      sacc[0][jj] = MFMA16(kf0, qf[0][0], sacc[0][jj]);
      sacc[1][jj] = MFMA16(kf0, qf[1][0], sacc[1][jj]);
      sacc[0][jj] = MFMA16(kf1, qf[0][1], sacc[0][jj]);
      sacc[1][jj] = MFMA16(kf1, qf[1][1], sacc[1][jj]);
    }
    __builtin_amdgcn_s_setprio(0);
#pragma unroll
    for (int qtile = 0; qtile < 2; ++qtile)
#pragma unroll
      for (int jj = 0; jj < 4; ++jj) {
        int jbase = j0 + jj * 16 + quad * 4;
        fx4 sv = sacc[qtile][jj];
        float p0 = fexp2(sv[0] - M);
        float p1 = fexp2(sv[1] - M);
        float p2 = fexp2(sv[2] - M);
        float p3 = fexp2(sv[3] - M);
        if (tail) {
          if (jbase + 0 >= KSEL) p0 = 0.f;
          if (jbase + 1 >= KSEL) p1 = 0.f;
          if (jbase + 2 >= KSEL) p2 = 0.f;
          if (jbase + 3 >= KSEL) p3 = 0.f;
        }
        lsum[qtile] += (p0 + p1) + (p2 + p3);
        *(uint2*)(Pw + (qtile * 16 + l15) * 72 + jj * 16 + quad * 4) =
            make_uint2(cvtpk_bf16(p0, p1), cvtpk_bf16(p2, p3));
      }
    // PV: A=P (wave-private LDS), B=V (LDS)
    __builtin_amdgcn_s_setprio(1);
#pragma unroll
    for (int js = 0; js < 2; ++js) {
      s16x8 pf0 = *(const s16x8*)(Pw + l15 * 72 + js * 32 + quad * 8);
      s16x8 pf1 = *(const s16x8*)(Pw + (16 + l15) * 72 + js * 32 + quad * 8);
#pragma unroll
      for (int dt = 0; dt < 4; ++dt) {
        s16x8 vf = *(const s16x8*)(Vt + (dt * 16 + l15) * 72 + js * 32 + quad * 8);
        oacc[0][dt] = MFMA16(pf0, vf, oacc[0][dt]);
        oacc[1][dt] = MFMA16(pf1, vf, oacc[1][dt]);
      }
    }
    __builtin_amdgcn_s_setprio(0);
  }

  // combine quad-partitioned j-sums (lanes l15, +16, +32, +48 hold disjoint j sets)
#pragma unroll
  for (int qtile = 0; qtile < 2; ++qtile) {
    float s = lsum[qtile];
    s += __shfl_xor(s, 16);
    s += __shfl_xor(s, 32);
    lsum[qtile] = s;
  }

  size_t pbase = (((size_t)part * 2 + b) * NHQ + h) * KPAD;
#pragma unroll
  for (int qtile = 0; qtile < 2; ++qtile) {
    int gqb = q0 + w * 32 + qtile * 16;
    if (quad == 0) pl[pbase + gqb + l15] = lsum[qtile];
  }

  // transpose O through the (now free) wave-private P buffer -> coalesced stores
#pragma unroll
  for (int qtile = 0; qtile < 2; ++qtile)
#pragma unroll
    for (int dt = 0; dt < 4; ++dt)
#pragma unroll
      for (int r = 0; r < 4; ++r)
        Pw[(qtile * 16 + quad * 4 + r) * 72 + dt * 16 + l15] = f2b(oacc[qtile][dt][r]);
#pragma unroll
  for (int pass = 0; pass < 4; ++pass) {
    int row = pass * 8 + (lane >> 3), chunk = lane & 7;
    s16x8 vv = *(const s16x8*)(Pw + row * 72 + chunk * 8);
    *(s16x8*)(pO + (pbase + q0 + w * 32 + row) * 64 + chunk * 8) = vv;
  }
}

// ---------------- combine the three j-parts (vectorized x8): o = sum(O_p)/sum(l_p) ---------
__global__ __launch_bounds__(256) void k_comb(const unsigned short* __restrict__ pO,
                                              const float* __restrict__ pl,
                                              unsigned short* __restrict__ ob) {
  size_t g8 = (size_t)blockIdx.x * 256 + threadIdx.x;  // 425984 = 3407872/8
  size_t base = g8 * 8;
  int d0 = (int)(base & 63);
  size_t row = base >> 6;           // (b*16+h)*1664 + gq
  int gq = (int)(row % KPAD);
  int bhh = (int)(row / KPAD);
  int b = bhh >> 4, h = bhh & 15;
  uint4 p0 = *(const uint4*)(pO + base);
  uint4 p1 = *(const uint4*)(pO + base + 3407872);
  uint4 p2 = *(const uint4*)(pO + base + 2 * 3407872);
  float ls = pl[row] + pl[row + 53248] + pl[row + 2 * 53248];
  float rc = 1.0f / ls;
  unsigned int pw0[4] = {p0.x, p0.y, p0.z, p0.w};
  unsigned int pw1[4] = {p1.x, p1.y, p1.z, p1.w};
  unsigned int pw2[4] = {p2.x, p2.y, p2.z, p2.w};
  unsigned int ow[4];
#pragma unroll
  for (int j = 0; j < 4; ++j) {
    float lo = (b2f((unsigned short)pw0[j]) + b2f((unsigned short)pw1[j]) +
                b2f((unsigned short)pw2[j])) * rc;
    float hi = (b2f((unsigned short)(pw0[j] >> 16)) + b2f((unsigned short)(pw1[j] >> 16)) +
                b2f((unsigned short)(pw2[j] >> 16))) * rc;
    ow[j] = cvtpk_bf16(lo, hi);
  }
  *(uint4*)(ob + ((size_t)(b * KPAD + gq)) * CQ + h * 64 + d0) =
      make_uint4(ow[0], ow[1], ow[2], ow[3]);
}

extern "C" void kernel_launch(void* const* d_in, const int* in_sizes, int n_in,
                              void* d_out, int out_size, void* d_ws, size_t ws_size,
                              hipStream_t stream) {
  const float* x      = (const float*)d_in[0];
  const float* cached = (const float*)d_in[1];
  const float* wqkv   = (const float*)d_in[2];
  const float* qbias  = (const float*)d_in[3];
  const float* vbias  = (const float*)d_in[4];
  const float* wproj  = (const float*)d_in[5];
  const float* bproj  = (const float*)d_in[6];
  const float* sml    = (const float*)d_in[7];
  const float* rope   = (const float*)d_in[8];
  float* out = (float*)d_out;
  char* ws = (char*)d_ws;

  double* meanpart        = (double*)(ws);                    // 524288
  double* mean            = (double*)(ws + 524288);           // 16384
  double* mse             = (double*)(ws + 540672);           // 65536
  int* idx_sel            = (int*)(ws + 606208);              // 13312 -> 619520
  // overlap zone [619520, 44135424): x_bf + wqkv_bf + qkv (dead after k_normrope)
  unsigned short* x_bf    = (unsigned short*)(ws + 619520);   // 16777216
  unsigned short* wqkv_bf = (unsigned short*)(ws + 17396736); // 6291456
  unsigned short* qkv     = (unsigned short*)(ws + 23688192); // 20447232 -> 44135424
  // attn partials (3 parts) reuse the dead x_bf/wqkv_bf/qkv region
  unsigned short* pO      = (unsigned short*)(ws + 619520);   // 20447232
  float* pl               = (float*)(ws + 21066752);          // 638976 -> 21705728
  unsigned short* wproj_bf= (unsigned short*)(ws + 44135424); // 2097152
  unsigned short* qo      = (unsigned short*)(ws + 46232576); // 6815744
  unsigned short* ko      = (unsigned short*)(ws + 53048320); // 6815744
  unsigned short* vt      = (unsigned short*)(ws + 59864064); // 6815744
  unsigned short* ob      = (unsigned short*)(ws + 66679808); // 6815744 -> 73495552

  hipLaunchKernelGGL(k_mean_part, dim3(256), dim3(256), 0, stream, x, meanpart);
  hipLaunchKernelGGL(k_mean_reduce, dim3(8), dim3(256), 0, stream, meanpart, mean);
  hipLaunchKernelGGL(k_mse_base, dim3(8192), dim3(256), 0, stream, x, cached, mean, mse,
                     out, x_bf);
  hipLaunchKernelGGL(k_topk, dim3(2 + 1024), dim3(1024), 0, stream, mse, idx_sel,
                     wqkv, wproj, wqkv_bf, wproj_bf);
  hipLaunchKernelGGL(k_gemmA, dim3(52 * 24), dim3(256), 0, stream,
                     x_bf, wqkv_bf, idx_sel, qkv);
  hipLaunchKernelGGL(k_normrope, dim3(26 * 16 * BQ), dim3(256), 0, stream,
                     qkv, idx_sel, qbias, vbias, sml, rope, qo, ko, vt);
  hipLaunchKernelGGL(k_attn, dim3(13, BQ * NHQ, 3), dim3(256), 0, stream,
                     qo, ko, vt, sml, pO, pl);
  hipLaunchKernelGGL(k_comb, dim3(1664), dim3(256), 0, stream, pO, pl, ob);
  hipLaunchKernelGGL(k_gemmB, dim3(832), dim3(256), 0, stream,
                     ob, wproj_bf, idx_sel, out, x, bproj);
}

// Round 11
// 272.023 us; speedup vs baseline: 1.0674x; 1.0185x over previous
//
#include <hip/hip_runtime.h>
#include <hip/hip_bf16.h>
#include <math.h>

// Problem constants (setup_inputs)
#define BQ   2
#define LQ   4096
#define CQ   1024
#define NHQ  16
#define DHQ  64
#define KSEL 1638
#define KPAD 1664
#define MTOT (BQ*KSEL)   // 3276
#define MPAD 3328        // 26*128

typedef short s16x8 __attribute__((ext_vector_type(8)));
typedef float fx4   __attribute__((ext_vector_type(4)));

#define MFMA16(a,b,c) __builtin_amdgcn_mfma_f32_16x16x32_bf16(a,b,c,0,0,0)

__device__ __forceinline__ float b2f(unsigned short u) {
  union { float f; unsigned int i; } cv; cv.i = ((unsigned int)u) << 16; return cv.f;
}
__device__ __forceinline__ unsigned short f2b(float f) {
  union { float f; unsigned int i; } cv; cv.f = f;
  unsigned int x = cv.i;
  return (unsigned short)((x + 0x7fffu + ((x >> 16) & 1u)) >> 16);
}
__device__ __forceinline__ unsigned int fbits(float f) {
  union { float f; unsigned int i; } cv; cv.f = f; return cv.i;
}
// packed f32x2 -> bf16x2 (RNE), single VALU op
__device__ __forceinline__ unsigned int cvtpk_bf16(float a, float b) {
  unsigned int r;
  asm("v_cvt_pk_bf16_f32 %0, %1, %2" : "=v"(r) : "v"(a), "v"(b));
  return r;
}
__device__ __forceinline__ void async16(const void* g, void* l) {
  __builtin_amdgcn_global_load_lds((const __attribute__((address_space(1))) void*)g,
                                   (__attribute__((address_space(3))) void*)l, 16, 0, 0);
}
// raw 2^x (q is pre-scaled by log2(e) in k_normrope, M is in log2 units)
__device__ __forceinline__ float fexp2(float x) {
#if __has_builtin(__builtin_amdgcn_exp2f)
  return __builtin_amdgcn_exp2f(x);
#else
  return __expf(x * 0.69314718055994531f);
#endif
}

// ---------------- mean (fp64, 2-stage) ----------------
__global__ __launch_bounds__(256) void k_mean_part(const float* __restrict__ x,
                                                   double* __restrict__ part) {
  int bid = blockIdx.x;                    // 256 blocks: [b(2)][ch(32)][cb(4)]
  int cb = bid & 3, ch = (bid >> 2) & 31, b = bid >> 7;
  int c = cb * 256 + threadIdx.x;
  const float* p = x + ((size_t)b * LQ + (size_t)ch * 128) * CQ + c;
  double s = 0.0;
  for (int r = 0; r < 128; ++r) s += (double)p[(size_t)r * CQ];
  part[((size_t)b * 32 + ch) * CQ + c] = s;
}

__global__ __launch_bounds__(256) void k_mean_reduce(const double* __restrict__ part,
                                                     double* __restrict__ mean) {
  int g = blockIdx.x * 256 + threadIdx.x;  // 2048 = B*C
  int b = g >> 10, c = g & 1023;
  double s = 0.0;
  for (int ch = 0; ch < 32; ++ch) s += part[((size_t)b * 32 + ch) * CQ + c];
  mean[g] = s * (1.0 / 4096.0);
}

// ---------------- mse (fp64) + base output (x + upsample(cached)) + x->bf16 ----------------
__global__ __launch_bounds__(256) void k_mse_base(const float* __restrict__ x,
                                                  const float* __restrict__ cached,
                                                  const double* __restrict__ mean,
                                                  double* __restrict__ mse,
                                                  float* __restrict__ out,
                                                  unsigned short* __restrict__ xb) {
  int bl = blockIdx.x; int b = bl >> 12, l = bl & 4095;
  int hh = l >> 6, ww = l & 63;
  size_t xoff = ((size_t)b * LQ + l) * CQ;
  size_t uoff = (((size_t)b * 32 + (hh >> 1)) * 32 + (ww >> 1)) * CQ;
  const double* mrow = mean + (size_t)b * CQ;
  int c0 = threadIdx.x * 4;
  float4 xv = *(const float4*)(x + xoff + c0);
  float4 uv = *(const float4*)(cached + uoff + c0);
  float4 ov;
  ov.x = xv.x + uv.x; ov.y = xv.y + uv.y; ov.z = xv.z + uv.z; ov.w = xv.w + uv.w;
  *(float4*)(out + xoff + c0) = ov;
  ushort4 xo;
  xo.x = f2b(xv.x); xo.y = f2b(xv.y); xo.z = f2b(xv.z); xo.w = f2b(xv.w);
  ((ushort4*)xb)[(xoff + c0) >> 2] = xo;
  double d0 = (double)xv.x - mrow[c0];
  double d1 = (double)xv.y - mrow[c0 + 1];
  double d2 = (double)xv.z - mrow[c0 + 2];
  double d3 = (double)xv.w - mrow[c0 + 3];
  double ss = d0 * d0 + d1 * d1 + d2 * d2 + d3 * d3;
  for (int o = 1; o < 64; o <<= 1) ss += __shfl_xor(ss, o);
  __shared__ double ws4[4];
  if ((threadIdx.x & 63) == 0) ws4[threadIdx.x >> 6] = ss;
  __syncthreads();
  if (threadIdx.x == 0) mse[(size_t)b * LQ + l] = ws4[0] + ws4[1] + ws4[2] + ws4[3];
}

// ---------------- top-k (blocks 0,1) + fused weight fp32->bf16 conversion (blocks >=2) ----
// R17: 4-pass radix over the HIGH 32 BITS only (mse >= 0 -> high-32 orders
// identically to the full double up to top-20-mantissa ties). The tie group
// (high32 == threshold) is resolved exactly: sort by full value desc, idx asc.
// Halves the serial-chain select cost (8 passes -> 4).
__global__ __launch_bounds__(1024) void k_topk(const double* __restrict__ mse,
                                               int* __restrict__ idx_sel,
                                               const float* __restrict__ wqkv,
                                               const float* __restrict__ wproj,
                                               unsigned short* __restrict__ wqb,
                                               unsigned short* __restrict__ wpb) {
  if (blockIdx.x >= 2) {   // conversion path: 1024 blocks x 1024 thr x 1 float4
    int i = (blockIdx.x - 2) * 1024 + threadIdx.x;
    const float* s; unsigned short* d; int off;
    if (i < 786432) { s = wqkv;  d = wqb; off = i; }
    else            { s = wproj; d = wpb; off = i - 786432; }
    float4 v = ((const float4*)s)[off];
    ushort4 o;
    o.x = f2b(v.x); o.y = f2b(v.y); o.z = f2b(v.z); o.w = f2b(v.w);
    ((ushort4*)d)[off] = o;
    return;
  }
  __shared__ unsigned long long u[4096];       // 32 KB
  __shared__ unsigned int whist[16 * 257];     // 16.4 KB, stride 257 => cross-wave bank skew
  __shared__ unsigned int wtot[4];
  __shared__ unsigned long long sh_prefix;
  __shared__ int sh_rem, sh_rem2, sh_bsel, sh_cnt, sh_eqcnt;
  __shared__ int eqbuf[256];
  int b = blockIdx.x, t = threadIdx.x;
  int wv = t >> 6, laneid = t & 63;
  for (int p = 0; p < 4; ++p) {
    int i = p * 1024 + t;
    u[i] = (unsigned long long)__double_as_longlong(mse[(size_t)b * LQ + i]);
  }
  if (t == 0) { sh_prefix = 0ULL; sh_rem = KSEL; sh_cnt = 0; sh_eqcnt = 0; }
  __syncthreads();
  for (int shift = 56; shift >= 32; shift -= 8) {   // high 32 bits only
    for (int z = t; z < 16 * 257; z += 1024) whist[z] = 0u;
    __syncthreads();
    unsigned long long pref = sh_prefix;
#pragma unroll
    for (int p = 0; p < 4; ++p) {
      int i = p * 1024 + t;
      unsigned long long v = u[i];
      bool cand = (shift == 56) || ((v >> ((shift + 8) & 63)) == pref);
      if (cand) atomicAdd(&whist[wv * 257 + ((unsigned int)(v >> shift) & 255u)], 1u);
    }
    __syncthreads();
    unsigned int myc = 0, mysc = 0;
    if (t < 256) {            // combine the 16 wave hists for my bin (bin = 255 - t)
      unsigned int s = 0;
      int bin = 255 - t;
#pragma unroll
      for (int wvi = 0; wvi < 16; ++wvi) s += whist[wvi * 257 + bin];
      myc = s;
      mysc = myc;
#pragma unroll
      for (int o = 1; o < 64; o <<= 1) {
        unsigned int v2 = __shfl_up(mysc, o);
        if (laneid >= o) mysc += v2;
      }
      if (laneid == 63) wtot[wv] = mysc;
    }
    __syncthreads();
    if (t < 256) {
      unsigned int basep = 0;
      for (int wvi = 0; wvi < wv; ++wvi) basep += wtot[wvi];
      unsigned int incl = basep + mysc;       // count of keys in bins >= my bin
      unsigned int excl = incl - myc;         // count of keys in bins >  my bin
      unsigned int rem = (unsigned int)sh_rem;
      if (excl < rem && rem <= incl) {        // exactly one thread crosses
        sh_bsel = 255 - t;
        sh_rem2 = (int)(rem - excl);
      }
    }
    __syncthreads();
    if (t == 0) {
      sh_prefix = (sh_prefix << 8) | (unsigned long long)sh_bsel;
      sh_rem = sh_rem2;
    }
    __syncthreads();
  }
  unsigned long long T = sh_prefix;           // threshold on the high 32 bits
  int rem_eq = sh_rem;
#pragma unroll
  for (int p = 0; p < 4; ++p) {
    int i = p * 1024 + t;
    unsigned long long v = u[i];
    bool win = ((v >> 32) > T);
    unsigned long long mask = __ballot(win);
    int total = __popcll(mask);
    int base = 0;
    if (laneid == 0 && total > 0) base = atomicAdd(&sh_cnt, total);
    base = __shfl(base, 0);
    if (win) {
      int lpos = __popcll(mask & ((1ULL << laneid) - 1ULL));
      idx_sel[b * KPAD + base + lpos] = i;
    }
    if ((v >> 32) == T) {
      int e = atomicAdd(&sh_eqcnt, 1);
      if (e < 256) eqbuf[e] = i;
    }
  }
  __syncthreads();
  if (t == 0) {
    int n = sh_eqcnt; if (n > 256) n = 256;
    // sort eq group by (full value desc, index asc) -- exact double ordering
    for (int a = 1; a < n; ++a) {
      int key = eqbuf[a]; unsigned long long kv = u[key]; int c = a - 1;
      while (c >= 0 && (u[eqbuf[c]] < kv || (u[eqbuf[c]] == kv && eqbuf[c] > key))) {
        eqbuf[c + 1] = eqbuf[c]; --c;
      }
      eqbuf[c + 1] = key;
    }
    int base = sh_cnt;
    for (int a = 0; a < rem_eq && a < n; ++a) idx_sel[b * KPAD + base + a] = eqbuf[a];
    for (int a = KSEL; a < KPAD; ++a) idx_sel[b * KPAD + a] = 0;
  }
}

// ---------------- qkv GEMM (64x128, BK=32), 1248 blocks, depth-1 dbuf ----------------
// R17: reverted to the R9-proven depth-1 form (45.6us, occ 33%). Depth-2's 36KB
// LDS cut blocks/CU 6->4 and regressed (R10 post-mortem: TLP > prefetch depth here).
__global__ __launch_bounds__(256) void k_gemmA(const unsigned short* __restrict__ Asrc,
                                               const unsigned short* __restrict__ Bmat,
                                               const int* __restrict__ idx_sel,
                                               unsigned short* __restrict__ Cbf) {
  int bid = blockIdx.x;
  int swz = (bid & 7) * 156 + (bid >> 3);   // XCD-contiguous chunks (1248 = 8*156)
  int bm = swz % 52, bn = swz / 52;
  int tid = threadIdx.x;
  int w = tid >> 6, lane = tid & 63, quad = lane >> 4, l15 = lane & 15;
  int wm = w & 1, wn = w >> 1;
  __shared__ __align__(16) unsigned char sm[2][12288];   // A [64][32]bf16, B [128][32]bf16

  const unsigned short* gA;
  {
    int row = tid >> 2, kc = tid & 3;
    int m = bm * 64 + row; if (m >= MTOT) m = MTOT - 1;
    int bb = m / KSEL; int ii = m - bb * KSEL;
    int lsel = idx_sel[bb * KPAD + ii];
    gA = Asrc + ((size_t)bb * LQ + lsel) * CQ + kc * 8;
  }
  const unsigned short* gB[2];
#pragma unroll
  for (int p = 0; p < 2; ++p) {
    int e = p * 256 + tid; int row = e >> 2, kc = e & 3;
    gB[p] = Bmat + (size_t)(bn * 128 + row) * CQ + kc * 8;
  }

  fx4 acc[2][4];
#pragma unroll
  for (int a = 0; a < 2; ++a)
#pragma unroll
    for (int c = 0; c < 4; ++c) acc[a][c] = (fx4){0.f, 0.f, 0.f, 0.f};

#define STAGE_A(buf, it) do { int ke = (it) * 32;                                   \
    async16(gA + ke, sm[buf] + tid * 16);                                           \
    async16(gB[0] + ke, sm[buf] + 4096 + tid * 16);                                 \
    async16(gB[1] + ke, sm[buf] + 8192 + tid * 16); } while (0)

  STAGE_A(0, 0);
  for (int it = 0; it < 32; ++it) {
    int cur = it & 1;
    if (it < 31) STAGE_A(cur ^ 1, it + 1);
    if (it < 31) asm volatile("s_waitcnt vmcnt(3)");
    else         asm volatile("s_waitcnt vmcnt(0)");
    __builtin_amdgcn_s_barrier();
    const unsigned char* smb = sm[cur];
    s16x8 af[2], bf[4];
#pragma unroll
    for (int mt = 0; mt < 2; ++mt)
      af[mt] = *(const s16x8*)(smb + ((wm * 32 + mt * 16 + l15) * 32 + quad * 8) * 2);
#pragma unroll
    for (int nt = 0; nt < 4; ++nt)
      bf[nt] = *(const s16x8*)(smb + 4096 + ((wn * 64 + nt * 16 + l15) * 32 + quad * 8) * 2);
    __builtin_amdgcn_s_setprio(1);
#pragma unroll
    for (int mt = 0; mt < 2; ++mt)
#pragma unroll
      for (int nt = 0; nt < 4; ++nt)
        acc[mt][nt] = MFMA16(af[mt], bf[nt], acc[mt][nt]);
    __builtin_amdgcn_s_setprio(0);
    __builtin_amdgcn_s_barrier();    // all waves done reading cur before it's re-staged
  }
#undef STAGE_A

#pragma unroll
  for (int mt = 0; mt < 2; ++mt)
#pragma unroll
    for (int nt = 0; nt < 4; ++nt) {
      int n = bn * 128 + wn * 64 + nt * 16 + l15;
      int mbase = bm * 64 + wm * 32 + mt * 16 + quad * 4;
      fx4 vv = acc[mt][nt];
#pragma unroll
      for (int r = 0; r < 4; ++r) {
        int m = mbase + r;
        if (m < MTOT) Cbf[(size_t)m * 3072 + n] = f2b(vv[r]);
      }
    }
}

// ---------------- proj GEMM (64x64, BK=64) : 832 blocks, dbuf prefetch ----------------
__global__ __launch_bounds__(256) void k_gemmB(const unsigned short* __restrict__ Asrc,
                                               const unsigned short* __restrict__ Bmat,
                                               const int* __restrict__ idx_sel,
                                               float* __restrict__ Cf,
                                               const float* __restrict__ xin,
                                               const float* __restrict__ bproj) {
  int bid = blockIdx.x;
  int swz = (bid & 7) * 104 + (bid >> 3);   // XCD-contiguous chunks (832 = 8*104)
  int bm = swz % 52, bn = swz / 52;
  int tid = threadIdx.x;
  int w = tid >> 6, lane = tid & 63, quad = lane >> 4, l15 = lane & 15;
  int wm = w & 1, wn = w >> 1;
  __shared__ __align__(16) unsigned char sm[2][16384];   // A [64][64]bf16, B [64][64]bf16

  const unsigned short* g4[4];
#pragma unroll
  for (int p = 0; p < 4; ++p) {
    int e = (p & 1) * 256 + tid; int row = e >> 3, kc = e & 7;
    if (p < 2) {
      int m = bm * 64 + row; if (m >= MTOT) m = MTOT - 1;
      int bb = m / KSEL; int ii = m - bb * KSEL;
      g4[p] = Asrc + ((size_t)bb * KPAD + ii) * CQ + kc * 8;
    } else {
      g4[p] = Bmat + (size_t)(bn * 64 + row) * CQ + kc * 8;
    }
  }

  fx4 acc[2][2];
#pragma unroll
  for (int a = 0; a < 2; ++a)
#pragma unroll
    for (int c = 0; c < 2; ++c) acc[a][c] = (fx4){0.f, 0.f, 0.f, 0.f};

#define STAGE_B(buf, it) do { int ke = (it) * 64;                                   \
    _Pragma("unroll")                                                               \
    for (int p = 0; p < 4; ++p)                                                     \
      async16(g4[p] + ke, sm[buf] + p * 4096 + w * 1024);                           \
    } while (0)

  STAGE_B(0, 0);
  for (int it = 0; it < 16; ++it) {
    int cur = it & 1;
    if (it < 15) STAGE_B(cur ^ 1, it + 1);
    if (it < 15) asm volatile("s_waitcnt vmcnt(4)");
    else         asm volatile("s_waitcnt vmcnt(0)");
    __builtin_amdgcn_s_barrier();
    const unsigned char* smb = sm[cur];
#pragma unroll
    for (int kk = 0; kk < 2; ++kk) {
      s16x8 af[2], bf2[2];
#pragma unroll
      for (int mt = 0; mt < 2; ++mt)
        af[mt] = *(const s16x8*)(smb + ((wm * 32 + mt * 16 + l15) * 64 + kk * 32 + quad * 8) * 2);
#pragma unroll
      for (int nt = 0; nt < 2; ++nt)
        bf2[nt] = *(const s16x8*)(smb + 8192 + ((wn * 32 + nt * 16 + l15) * 64 + kk * 32 + quad * 8) * 2);
#pragma unroll
      for (int mt = 0; mt < 2; ++mt)
#pragma unroll
        for (int nt = 0; nt < 2; ++nt)
          acc[mt][nt] = MFMA16(af[mt], bf2[nt], acc[mt][nt]);
    }
    __builtin_amdgcn_s_barrier();    // all waves done reading cur before it's re-staged
  }
#undef STAGE_B

#pragma unroll
  for (int mt = 0; mt < 2; ++mt)
#pragma unroll
    for (int nt = 0; nt < 2; ++nt) {
      int n = bn * 64 + wn * 32 + nt * 16 + l15;
      int mbase = bm * 64 + wm * 32 + mt * 16 + quad * 4;
      fx4 vv = acc[mt][nt];
      float bp = bproj[n];
#pragma unroll
      for (int r = 0; r < 4; ++r) {
        int m = mbase + r;
        if (m < MTOT) {
          int bb = m / KSEL; int ii = m - bb * KSEL;
          int lsel = idx_sel[bb * KPAD + ii];
          size_t off = ((size_t)bb * LQ + lsel) * CQ + n;
          Cf[off] = xin[off] + vv[r] + bp;
        }
      }
    }
}

// ---------------- l2norm + scale + rope -> q,k ; v -> Vt (transposed) ----------------
__global__ __launch_bounds__(256) void k_normrope(const unsigned short* __restrict__ qkv,
                                                  const int* __restrict__ idx_sel,
                                                  const float* __restrict__ qbias,
                                                  const float* __restrict__ vbias,
                                                  const float* __restrict__ sml,
                                                  const float* __restrict__ rope,
                                                  unsigned short* __restrict__ qo,
                                                  unsigned short* __restrict__ ko,
                                                  unsigned short* __restrict__ vt) {
  int bid = blockIdx.x;                       // 26*16*2
  int tile = bid % 26; int h = (bid / 26) & 15; int b = bid / (26 * 16);
  int tid = threadIdx.x; int w = tid >> 6; int lane = tid & 63;
  int tk = lane >> 5, dl = lane & 31;         // token-half, d-pair index
  int d0 = dl * 2;
  __shared__ unsigned short vtile[64 * 68];
  float scale = expf(fminf(sml[h], 4.6051702f)) * 1.4426950408889634f;
  float2 qb2 = *(const float2*)(qbias + h * 64 + d0);
  float2 vb2 = *(const float2*)(vbias + h * 64 + d0);
  for (int pass = 0; pass < 8; ++pass) {
    int il = pass * 8 + w * 2 + tk;
    int i = tile * 64 + il;
    float v0 = 0.f, v1 = 0.f;
    if (i < KSEL) {
      int lsel = idx_sel[b * KPAD + i];
      size_t base = ((size_t)(b * KSEL + i)) * 3072 + h * 64 + d0;
      float r0 = rope[(size_t)lsel * 32 + dl];
      float r1 = rope[(size_t)LQ * 32 + (size_t)lsel * 32 + dl];
      // q
      unsigned int qw = *(const unsigned int*)(qkv + base);
      float q0 = b2f((unsigned short)qw) + qb2.x;
      float q1 = b2f((unsigned short)(qw >> 16)) + qb2.y;
      float ss = q0 * q0 + q1 * q1;
#pragma unroll
      for (int o = 1; o < 32; o <<= 1) ss += __shfl_xor(ss, o);
      float rn = scale / fmaxf(sqrtf(ss), 1e-12f);
      float qn0 = q0 * rn, qn1 = q1 * rn;
      *(unsigned int*)(qo + ((size_t)(b * NHQ + h) * KPAD + i) * 64 + d0) =
          cvtpk_bf16(r0 * qn0 - r1 * qn1, r1 * qn0 + r0 * qn1);
      // k
      unsigned int kw = *(const unsigned int*)(qkv + base + 1024);
      float k0 = b2f((unsigned short)kw);
      float k1 = b2f((unsigned short)(kw >> 16));
      float ks = k0 * k0 + k1 * k1;
#pragma unroll
      for (int o = 1; o < 32; o <<= 1) ks += __shfl_xor(ks, o);
      float rkn = 1.0f / fmaxf(sqrtf(ks), 1e-12f);
      float kn0 = k0 * rkn, kn1 = k1 * rkn;
      *(unsigned int*)(ko + ((size_t)(b * NHQ + h) * KPAD + i) * 64 + d0) =
          cvtpk_bf16(r0 * kn0 - r1 * kn1, r1 * kn0 + r0 * kn1);
      // v
      unsigned int vw = *(const unsigned int*)(qkv + base + 2048);
      v0 = b2f((unsigned short)vw) + vb2.x;
      v1 = b2f((unsigned short)(vw >> 16)) + vb2.y;
    }
    vtile[d0 * 68 + il] = f2b(v0);
    vtile[(d0 + 1) * 68 + il] = f2b(v1);
  }
  __syncthreads();
  int row = tid >> 2, c0 = (tid & 3) * 16;
  s16x8 o0, o1;
#pragma unroll
  for (int jj = 0; jj < 8; ++jj) {
    o0[jj] = (short)vtile[row * 68 + c0 + jj];
    o1[jj] = (short)vtile[row * 68 + c0 + 8 + jj];
  }
  size_t doff = ((size_t)((b * NHQ + h) * 64 + row)) * KPAD + (size_t)tile * 64 + c0;
  *(s16x8*)(vt + doff) = o0;
  *(s16x8*)(vt + doff + 8) = o1;
}

// ---------------- flash attention ----------------
// z=3 part split (tiles 9/9/8) -> 1248 blocks, ~4 resident blocks/CU. Loop body =
// proven R4 structure (VGPR 64, T14 async-STAGE, cvt_pk pack, setprio).
__global__ __launch_bounds__(256, 4) void k_attn(const unsigned short* __restrict__ qb,
                                                 const unsigned short* __restrict__ kb,
                                                 const unsigned short* __restrict__ vtb,
                                                 const float* __restrict__ sml,
                                                 unsigned short* __restrict__ pO,
                                                 float* __restrict__ pl) {
  int qt = blockIdx.x; int bh = blockIdx.y; int part = blockIdx.z;
  int b = bh >> 4, h = bh & 15;
  int t0 = part * 9;
  int t1 = (part == 2) ? 26 : t0 + 9;
  int q0 = qt * 128;
  int tid = threadIdx.x, w = tid >> 6, lane = tid & 63, quad = lane >> 4, l15 = lane & 15;
  float M = __expf(fminf(sml[h], 4.6051702f)) * 1.4426950408889634f;  // log2-domain shift
  __shared__ __align__(16) unsigned short Kt[64 * 72];     //  9216 B
  __shared__ __align__(16) unsigned short Vt[64 * 72];     //  9216 B
  __shared__ __align__(16) unsigned short Pq[4][32 * 72];  // 18432 B (total 36864 -> 4 blk/CU)
  unsigned short* Pw = Pq[w];
  const unsigned short* qbase = qb + (size_t)(b * NHQ + h) * KPAD * 64;
  const unsigned short* kbase = kb + (size_t)(b * NHQ + h) * KPAD * 64;
  const unsigned short* vbase = vtb + (size_t)(b * NHQ + h) * 64 * KPAD;

  // staging geometry: 512 s16x8 chunks per K (and V) tile, 2 per thread
  int r0 = tid >> 3, c0 = tid & 7;            // chunk 0: rows 0..31
  int r1 = 32 + r0, c1 = c0;                  // chunk 1: rows 32..63

  // Q as B-operand: n=l15 -> q row; k = kb2*32 + quad*8
  s16x8 qf[2][2];
#pragma unroll
  for (int qtile = 0; qtile < 2; ++qtile)
#pragma unroll
    for (int kb2 = 0; kb2 < 2; ++kb2) {
      int row = q0 + w * 32 + qtile * 16 + l15;
      qf[qtile][kb2] = *(const s16x8*)(qbase + (size_t)row * 64 + kb2 * 32 + quad * 8);
    }

  float lsum[2] = {0.f, 0.f};
  fx4 oacc[2][4];
#pragma unroll
  for (int qtile = 0; qtile < 2; ++qtile)
#pragma unroll
    for (int dt = 0; dt < 4; ++dt) oacc[qtile][dt] = (fx4){0.f, 0.f, 0.f, 0.f};

  // prologue: issue tile t0's loads (T14 async-STAGE split)
  s16x8 kn0, kn1, vn0, vn1;
  {
    int j0 = t0 * 64;
    kn0 = *(const s16x8*)(kbase + (size_t)(j0 + r0) * 64 + c0 * 8);
    kn1 = *(const s16x8*)(kbase + (size_t)(j0 + r1) * 64 + c1 * 8);
    vn0 = *(const s16x8*)(vbase + (size_t)r0 * KPAD + j0 + c0 * 8);
    vn1 = *(const s16x8*)(vbase + (size_t)r1 * KPAD + j0 + c1 * 8);
  }

  for (int t = t0; t < t1; ++t) {
    int j0 = t * 64;
    bool tail = (j0 + 64 > KSEL);
    __builtin_amdgcn_s_barrier();    // all waves done reading prev Kt/Vt
    *(s16x8*)(Kt + r0 * 72 + c0 * 8) = kn0;
    *(s16x8*)(Kt + r1 * 72 + c1 * 8) = kn1;
    *(s16x8*)(Vt + r0 * 72 + c0 * 8) = vn0;
    *(s16x8*)(Vt + r1 * 72 + c1 * 8) = vn1;
    // issue next tile's loads; they stay in flight under this tile's compute
    if (t + 1 < t1) {
      int jn = (t + 1) * 64;
      kn0 = *(const s16x8*)(kbase + (size_t)(jn + r0) * 64 + c0 * 8);
      kn1 = *(const s16x8*)(kbase + (size_t)(jn + r1) * 64 + c1 * 8);
      vn0 = *(const s16x8*)(vbase + (size_t)r0 * KPAD + jn + c0 * 8);
      vn1 = *(const s16x8*)(vbase + (size_t)r1 * KPAD + jn + c1 * 8);
    }
    asm volatile("s_waitcnt lgkmcnt(0)" ::: "memory");   // ds_writes visible
    __builtin_amdgcn_s_barrier();

    // S^T -> exp2 -> wave-private P -> PV
    fx4 sacc[2][4];
#pragma unroll
    for (int qtile = 0; qtile < 2; ++qtile)
#pragma unroll
      for (int jj = 0; jj < 4; ++jj) sacc[qtile][jj] = (fx4){0.f, 0.f, 0.f, 0.f};
    __builtin_amdgcn_s_setprio(1);
#pragma unroll
    for (int jj = 0; jj < 4; ++jj) {
      int jl = jj * 16 + l15;
      s16x8 kf0 = *(const s16x8*)(Kt + jl * 72 + quad * 8);
      s16x8 kf1 = *(const s16x8*)(Kt + jl * 72 + 32 + quad * 8);
      sacc[0][jj] = MFMA16(kf0, qf[0][0], sacc[0][jj]);
      sacc[1][jj] = MFMA16(kf0, qf[1][0], sacc[1][jj]);
      sacc[0][jj] = MFMA16(kf1, qf[0][1], sacc[0][jj]);
      sacc[1][jj] = MFMA16(kf1, qf[1][1], sacc[1][jj]);
    }
    __builtin_amdgcn_s_setprio(0);
#pragma unroll
    for (int qtile = 0; qtile < 2; ++qtile)
#pragma unroll
      for (int jj = 0; jj < 4; ++jj) {
        int jbase = j0 + jj * 16 + quad * 4;
        fx4 sv = sacc[qtile][jj];
        float p0 = fexp2(sv[0] - M);
        float p1 = fexp2(sv[1] - M);
        float p2 = fexp2(sv[2] - M);
        float p3 = fexp2(sv[3] - M);
        if (tail) {
          if (jbase + 0 >= KSEL) p0 = 0.f;
          if (jbase + 1 >= KSEL) p1 = 0.f;
          if (jbase + 2 >= KSEL) p2 = 0.f;
          if (jbase + 3 >= KSEL) p3 = 0.f;
        }
        lsum[qtile] += (p0 + p1) + (p2 + p3);
        *(uint2*)(Pw + (qtile * 16 + l15) * 72 + jj * 16 + quad * 4) =
            make_uint2(cvtpk_bf16(p0, p1), cvtpk_bf16(p2, p3));
      }
    // PV: A=P (wave-private LDS), B=V (LDS)
    __builtin_amdgcn_s_setprio(1);
#pragma unroll
    for (int js = 0; js < 2; ++js) {
      s16x8 pf0 = *(const s16x8*)(Pw + l15 * 72 + js * 32 + quad * 8);
      s16x8 pf1 = *(const s16x8*)(Pw + (16 + l15) * 72 + js * 32 + quad * 8);
#pragma unroll
      for (int dt = 0; dt < 4; ++dt) {
        s16x8 vf = *(const s16x8*)(Vt + (dt * 16 + l15) * 72 + js * 32 + quad * 8);
        oacc[0][dt] = MFMA16(pf0, vf, oacc[0][dt]);
        oacc[1][dt] = MFMA16(pf1, vf, oacc[1][dt]);
      }
    }
    __builtin_amdgcn_s_setprio(0);
  }

  // combine quad-partitioned j-sums (lanes l15, +16, +32, +48 hold disjoint j sets)
#pragma unroll
  for (int qtile = 0; qtile < 2; ++qtile) {
    float s = lsum[qtile];
    s += __shfl_xor(s, 16);
    s += __shfl_xor(s, 32);
    lsum[qtile] = s;
  }

  size_t pbase = (((size_t)part * 2 + b) * NHQ + h) * KPAD;
#pragma unroll
  for (int qtile = 0; qtile < 2; ++qtile) {
    int gqb = q0 + w * 32 + qtile * 16;
    if (quad == 0) pl[pbase + gqb + l15] = lsum[qtile];
  }

  // transpose O through the (now free) wave-private P buffer -> coalesced stores
#pragma unroll
  for (int qtile = 0; qtile < 2; ++qtile)
#pragma unroll
    for (int dt = 0; dt < 4; ++dt)
#pragma unroll
      for (int r = 0; r < 4; ++r)
        Pw[(qtile * 16 + quad * 4 + r) * 72 + dt * 16 + l15] = f2b(oacc[qtile][dt][r]);
#pragma unroll
  for (int pass = 0; pass < 4; ++pass) {
    int row = pass * 8 + (lane >> 3), chunk = lane & 7;
    s16x8 vv = *(const s16x8*)(Pw + row * 72 + chunk * 8);
    *(s16x8*)(pO + (pbase + q0 + w * 32 + row) * 64 + chunk * 8) = vv;
  }
}

// ---------------- combine the three j-parts (vectorized x8): o = sum(O_p)/sum(l_p) ---------
__global__ __launch_bounds__(256) void k_comb(const unsigned short* __restrict__ pO,
                                              const float* __restrict__ pl,
                                              unsigned short* __restrict__ ob) {
  size_t g8 = (size_t)blockIdx.x * 256 + threadIdx.x;  // 425984 = 3407872/8
  size_t base = g8 * 8;
  int d0 = (int)(base & 63);
  size_t row = base >> 6;           // (b*16+h)*1664 + gq
  int gq = (int)(row % KPAD);
  int bhh = (int)(row / KPAD);
  int b = bhh >> 4, h = bhh & 15;
  uint4 p0 = *(const uint4*)(pO + base);
  uint4 p1 = *(const uint4*)(pO + base + 3407872);
  uint4 p2 = *(const uint4*)(pO + base + 2 * 3407872);
  float ls = pl[row] + pl[row + 53248] + pl[row + 2 * 53248];
  float rc = 1.0f / ls;
  unsigned int pw0[4] = {p0.x, p0.y, p0.z, p0.w};
  unsigned int pw1[4] = {p1.x, p1.y, p1.z, p1.w};
  unsigned int pw2[4] = {p2.x, p2.y, p2.z, p2.w};
  unsigned int ow[4];
#pragma unroll
  for (int j = 0; j < 4; ++j) {
    float lo = (b2f((unsigned short)pw0[j]) + b2f((unsigned short)pw1[j]) +
                b2f((unsigned short)pw2[j])) * rc;
    float hi = (b2f((unsigned short)(pw0[j] >> 16)) + b2f((unsigned short)(pw1[j] >> 16)) +
                b2f((unsigned short)(pw2[j] >> 16))) * rc;
    ow[j] = cvtpk_bf16(lo, hi);
  }
  *(uint4*)(ob + ((size_t)(b * KPAD + gq)) * CQ + h * 64 + d0) =
      make_uint4(ow[0], ow[1], ow[2], ow[3]);
}

extern "C" void kernel_launch(void* const* d_in, const int* in_sizes, int n_in,
                              void* d_out, int out_size, void* d_ws, size_t ws_size,
                              hipStream_t stream) {
  const float* x      = (const float*)d_in[0];
  const float* cached = (const float*)d_in[1];
  const float* wqkv   = (const float*)d_in[2];
  const float* qbias  = (const float*)d_in[3];
  const float* vbias  = (const float*)d_in[4];
  const float* wproj  = (const float*)d_in[5];
  const float* bproj  = (const float*)d_in[6];
  const float* sml    = (const float*)d_in[7];
  const float* rope   = (const float*)d_in[8];
  float* out = (float*)d_out;
  char* ws = (char*)d_ws;

  double* meanpart        = (double*)(ws);                    // 524288
  double* mean            = (double*)(ws + 524288);           // 16384
  double* mse             = (double*)(ws + 540672);           // 65536
  int* idx_sel            = (int*)(ws + 606208);              // 13312 -> 619520
  // overlap zone [619520, 44135424): x_bf + wqkv_bf + qkv (dead after k_normrope)
  unsigned short* x_bf    = (unsigned short*)(ws + 619520);   // 16777216
  unsigned short* wqkv_bf = (unsigned short*)(ws + 17396736); // 6291456
  unsigned short* qkv     = (unsigned short*)(ws + 23688192); // 20447232 -> 44135424
  // attn partials (3 parts) reuse the dead x_bf/wqkv_bf/qkv region
  unsigned short* pO      = (unsigned short*)(ws + 619520);   // 20447232
  float* pl               = (float*)(ws + 21066752);          // 638976 -> 21705728
  unsigned short* wproj_bf= (unsigned short*)(ws + 44135424); // 2097152
  unsigned short* qo      = (unsigned short*)(ws + 46232576); // 6815744
  unsigned short* ko      = (unsigned short*)(ws + 53048320); // 6815744
  unsigned short* vt      = (unsigned short*)(ws + 59864064); // 6815744
  unsigned short* ob      = (unsigned short*)(ws + 66679808); // 6815744 -> 73495552

  hipLaunchKernelGGL(k_mean_part, dim3(256), dim3(256), 0, stream, x, meanpart);
  hipLaunchKernelGGL(k_mean_reduce, dim3(8), dim3(256), 0, stream, meanpart, mean);
  hipLaunchKernelGGL(k_mse_base, dim3(8192), dim3(256), 0, stream, x, cached, mean, mse,
                     out, x_bf);
  hipLaunchKernelGGL(k_topk, dim3(2 + 1024), dim3(1024), 0, stream, mse, idx_sel,
                     wqkv, wproj, wqkv_bf, wproj_bf);
  hipLaunchKernelGGL(k_gemmA, dim3(52 * 24), dim3(256), 0, stream,
                     x_bf, wqkv_bf, idx_sel, qkv);
  hipLaunchKernelGGL(k_normrope, dim3(26 * 16 * BQ), dim3(256), 0, stream,
                     qkv, idx_sel, qbias, vbias, sml, rope, qo, ko, vt);
  hipLaunchKernelGGL(k_attn, dim3(13, BQ * NHQ, 3), dim3(256), 0, stream,
                     qo, ko, vt, sml, pO, pl);
  hipLaunchKernelGGL(k_comb, dim3(1664), dim3(256), 0, stream, pO, pl, ob);
  hipLaunchKernelGGL(k_gemmB, dim3(832), dim3(256), 0, stream,
                     ob, wproj_bf, idx_sel, out, x, bproj);
}

// Round 12
// 265.977 us; speedup vs baseline: 1.0917x; 1.0227x over previous
//
#include <hip/hip_runtime.h>
#include <hip/hip_bf16.h>
#include <math.h>

// Problem constants (setup_inputs)
#define BQ   2
#define LQ   4096
#define CQ   1024
#define NHQ  16
#define DHQ  64
#define KSEL 1638
#define KPAD 1664
#define MTOT (BQ*KSEL)   // 3276
#define MPAD 3328        // 26*128

typedef short s16x8 __attribute__((ext_vector_type(8)));
typedef float fx4   __attribute__((ext_vector_type(4)));

#define MFMA16(a,b,c) __builtin_amdgcn_mfma_f32_16x16x32_bf16(a,b,c,0,0,0)

__device__ __forceinline__ float b2f(unsigned short u) {
  union { float f; unsigned int i; } cv; cv.i = ((unsigned int)u) << 16; return cv.f;
}
__device__ __forceinline__ unsigned short f2b(float f) {
  union { float f; unsigned int i; } cv; cv.f = f;
  unsigned int x = cv.i;
  return (unsigned short)((x + 0x7fffu + ((x >> 16) & 1u)) >> 16);
}
__device__ __forceinline__ unsigned int fbits(float f) {
  union { float f; unsigned int i; } cv; cv.f = f; return cv.i;
}
// packed f32x2 -> bf16x2 (RNE), single VALU op
__device__ __forceinline__ unsigned int cvtpk_bf16(float a, float b) {
  unsigned int r;
  asm("v_cvt_pk_bf16_f32 %0, %1, %2" : "=v"(r) : "v"(a), "v"(b));
  return r;
}
__device__ __forceinline__ void async16(const void* g, void* l) {
  __builtin_amdgcn_global_load_lds((const __attribute__((address_space(1))) void*)g,
                                   (__attribute__((address_space(3))) void*)l, 16, 0, 0);
}
// raw 2^x (q is pre-scaled by log2(e) in k_normrope, M is in log2 units)
__device__ __forceinline__ float fexp2(float x) {
#if __has_builtin(__builtin_amdgcn_exp2f)
  return __builtin_amdgcn_exp2f(x);
#else
  return __expf(x * 0.69314718055994531f);
#endif
}

// ---------------- mean (fp64, 2-stage) ----------------
__global__ __launch_bounds__(256) void k_mean_part(const float* __restrict__ x,
                                                   double* __restrict__ part) {
  int bid = blockIdx.x;                    // 256 blocks: [b(2)][ch(32)][cb(4)]
  int cb = bid & 3, ch = (bid >> 2) & 31, b = bid >> 7;
  int c = cb * 256 + threadIdx.x;
  const float* p = x + ((size_t)b * LQ + (size_t)ch * 128) * CQ + c;
  double s = 0.0;
  for (int r = 0; r < 128; ++r) s += (double)p[(size_t)r * CQ];
  part[((size_t)b * 32 + ch) * CQ + c] = s;
}

__global__ __launch_bounds__(256) void k_mean_reduce(const double* __restrict__ part,
                                                     double* __restrict__ mean) {
  int g = blockIdx.x * 256 + threadIdx.x;  // 2048 = B*C
  int b = g >> 10, c = g & 1023;
  double s = 0.0;
  for (int ch = 0; ch < 32; ++ch) s += part[((size_t)b * 32 + ch) * CQ + c];
  mean[g] = s * (1.0 / 4096.0);
}

// ---------------- mse (fp64) + base output (x + upsample(cached)) + x->bf16 ----------------
__global__ __launch_bounds__(256) void k_mse_base(const float* __restrict__ x,
                                                  const float* __restrict__ cached,
                                                  const double* __restrict__ mean,
                                                  double* __restrict__ mse,
                                                  float* __restrict__ out,
                                                  unsigned short* __restrict__ xb) {
  int bl = blockIdx.x; int b = bl >> 12, l = bl & 4095;
  int hh = l >> 6, ww = l & 63;
  size_t xoff = ((size_t)b * LQ + l) * CQ;
  size_t uoff = (((size_t)b * 32 + (hh >> 1)) * 32 + (ww >> 1)) * CQ;
  const double* mrow = mean + (size_t)b * CQ;
  int c0 = threadIdx.x * 4;
  float4 xv = *(const float4*)(x + xoff + c0);
  float4 uv = *(const float4*)(cached + uoff + c0);
  float4 ov;
  ov.x = xv.x + uv.x; ov.y = xv.y + uv.y; ov.z = xv.z + uv.z; ov.w = xv.w + uv.w;
  *(float4*)(out + xoff + c0) = ov;
  ushort4 xo;
  xo.x = f2b(xv.x); xo.y = f2b(xv.y); xo.z = f2b(xv.z); xo.w = f2b(xv.w);
  ((ushort4*)xb)[(xoff + c0) >> 2] = xo;
  double d0 = (double)xv.x - mrow[c0];
  double d1 = (double)xv.y - mrow[c0 + 1];
  double d2 = (double)xv.z - mrow[c0 + 2];
  double d3 = (double)xv.w - mrow[c0 + 3];
  double ss = d0 * d0 + d1 * d1 + d2 * d2 + d3 * d3;
  for (int o = 1; o < 64; o <<= 1) ss += __shfl_xor(ss, o);
  __shared__ double ws4[4];
  if ((threadIdx.x & 63) == 0) ws4[threadIdx.x >> 6] = ss;
  __syncthreads();
  if (threadIdx.x == 0) mse[(size_t)b * LQ + l] = ws4[0] + ws4[1] + ws4[2] + ws4[3];
}

// ---------------- top-k (blocks 0,1) + fused weight fp32->bf16 conversion (blocks >=2) ----
// 4-pass radix over the HIGH 32 BITS (mse >= 0); tie group resolved exactly.
__global__ __launch_bounds__(1024) void k_topk(const double* __restrict__ mse,
                                               int* __restrict__ idx_sel,
                                               const float* __restrict__ wqkv,
                                               const float* __restrict__ wproj,
                                               unsigned short* __restrict__ wqb,
                                               unsigned short* __restrict__ wpb) {
  if (blockIdx.x >= 2) {   // conversion path: 1024 blocks x 1024 thr x 1 float4
    int i = (blockIdx.x - 2) * 1024 + threadIdx.x;
    const float* s; unsigned short* d; int off;
    if (i < 786432) { s = wqkv;  d = wqb; off = i; }
    else            { s = wproj; d = wpb; off = i - 786432; }
    float4 v = ((const float4*)s)[off];
    ushort4 o;
    o.x = f2b(v.x); o.y = f2b(v.y); o.z = f2b(v.z); o.w = f2b(v.w);
    ((ushort4*)d)[off] = o;
    return;
  }
  __shared__ unsigned long long u[4096];       // 32 KB
  __shared__ unsigned int whist[16 * 257];     // 16.4 KB, stride 257 => cross-wave bank skew
  __shared__ unsigned int wtot[4];
  __shared__ unsigned long long sh_prefix;
  __shared__ int sh_rem, sh_rem2, sh_bsel, sh_cnt, sh_eqcnt;
  __shared__ int eqbuf[256];
  int b = blockIdx.x, t = threadIdx.x;
  int wv = t >> 6, laneid = t & 63;
  for (int p = 0; p < 4; ++p) {
    int i = p * 1024 + t;
    u[i] = (unsigned long long)__double_as_longlong(mse[(size_t)b * LQ + i]);
  }
  if (t == 0) { sh_prefix = 0ULL; sh_rem = KSEL; sh_cnt = 0; sh_eqcnt = 0; }
  __syncthreads();
  for (int shift = 56; shift >= 32; shift -= 8) {   // high 32 bits only
    for (int z = t; z < 16 * 257; z += 1024) whist[z] = 0u;
    __syncthreads();
    unsigned long long pref = sh_prefix;
#pragma unroll
    for (int p = 0; p < 4; ++p) {
      int i = p * 1024 + t;
      unsigned long long v = u[i];
      bool cand = (shift == 56) || ((v >> ((shift + 8) & 63)) == pref);
      if (cand) atomicAdd(&whist[wv * 257 + ((unsigned int)(v >> shift) & 255u)], 1u);
    }
    __syncthreads();
    unsigned int myc = 0, mysc = 0;
    if (t < 256) {            // combine the 16 wave hists for my bin (bin = 255 - t)
      unsigned int s = 0;
      int bin = 255 - t;
#pragma unroll
      for (int wvi = 0; wvi < 16; ++wvi) s += whist[wvi * 257 + bin];
      myc = s;
      mysc = myc;
#pragma unroll
      for (int o = 1; o < 64; o <<= 1) {
        unsigned int v2 = __shfl_up(mysc, o);
        if (laneid >= o) mysc += v2;
      }
      if (laneid == 63) wtot[wv] = mysc;
    }
    __syncthreads();
    if (t < 256) {
      unsigned int basep = 0;
      for (int wvi = 0; wvi < wv; ++wvi) basep += wtot[wvi];
      unsigned int incl = basep + mysc;       // count of keys in bins >= my bin
      unsigned int excl = incl - myc;         // count of keys in bins >  my bin
      unsigned int rem = (unsigned int)sh_rem;
      if (excl < rem && rem <= incl) {        // exactly one thread crosses
        sh_bsel = 255 - t;
        sh_rem2 = (int)(rem - excl);
      }
    }
    __syncthreads();
    if (t == 0) {
      sh_prefix = (sh_prefix << 8) | (unsigned long long)sh_bsel;
      sh_rem = sh_rem2;
    }
    __syncthreads();
  }
  unsigned long long T = sh_prefix;           // threshold on the high 32 bits
  int rem_eq = sh_rem;
#pragma unroll
  for (int p = 0; p < 4; ++p) {
    int i = p * 1024 + t;
    unsigned long long v = u[i];
    bool win = ((v >> 32) > T);
    unsigned long long mask = __ballot(win);
    int total = __popcll(mask);
    int base = 0;
    if (laneid == 0 && total > 0) base = atomicAdd(&sh_cnt, total);
    base = __shfl(base, 0);
    if (win) {
      int lpos = __popcll(mask & ((1ULL << laneid) - 1ULL));
      idx_sel[b * KPAD + base + lpos] = i;
    }
    if ((v >> 32) == T) {
      int e = atomicAdd(&sh_eqcnt, 1);
      if (e < 256) eqbuf[e] = i;
    }
  }
  __syncthreads();
  if (t == 0) {
    int n = sh_eqcnt; if (n > 256) n = 256;
    // sort eq group by (full value desc, index asc) -- exact double ordering
    for (int a = 1; a < n; ++a) {
      int key = eqbuf[a]; unsigned long long kv = u[key]; int c = a - 1;
      while (c >= 0 && (u[eqbuf[c]] < kv || (u[eqbuf[c]] == kv && eqbuf[c] > key))) {
        eqbuf[c + 1] = eqbuf[c]; --c;
      }
      eqbuf[c + 1] = key;
    }
    int base = sh_cnt;
    for (int a = 0; a < rem_eq && a < n; ++a) idx_sel[b * KPAD + base + a] = eqbuf[a];
    for (int a = KSEL; a < KPAD; ++a) idx_sel[b * KPAD + a] = 0;
  }
}

// ---------------- qkv GEMM (64x128, BK=32), 1248 blocks, single-barrier dbuf ------------
// R18: 2-barrier/K-step -> 1 barrier. Schedule: vmcnt(0); barrier; stage(it+1);
// ds_read+MFMA. At the barrier every wave's stage-it loads have landed (own
// vmcnt(0) first) and all reads of buffer (it-1)&1 are done -> staging into it
// is safe. Halves the 64 barrier convoys; LDS/occupancy unchanged (24KB, 6/CU cap).
__global__ __launch_bounds__(256) void k_gemmA(const unsigned short* __restrict__ Asrc,
                                               const unsigned short* __restrict__ Bmat,
                                               const int* __restrict__ idx_sel,
                                               unsigned short* __restrict__ Cbf) {
  int bid = blockIdx.x;
  int swz = (bid & 7) * 156 + (bid >> 3);   // XCD-contiguous chunks (1248 = 8*156)
  int bm = swz % 52, bn = swz / 52;
  int tid = threadIdx.x;
  int w = tid >> 6, lane = tid & 63, quad = lane >> 4, l15 = lane & 15;
  int wm = w & 1, wn = w >> 1;
  __shared__ __align__(16) unsigned char sm[2][12288];   // A [64][32]bf16, B [128][32]bf16

  const unsigned short* gA;
  {
    int row = tid >> 2, kc = tid & 3;
    int m = bm * 64 + row; if (m >= MTOT) m = MTOT - 1;
    int bb = m / KSEL; int ii = m - bb * KSEL;
    int lsel = idx_sel[bb * KPAD + ii];
    gA = Asrc + ((size_t)bb * LQ + lsel) * CQ + kc * 8;
  }
  const unsigned short* gB[2];
#pragma unroll
  for (int p = 0; p < 2; ++p) {
    int e = p * 256 + tid; int row = e >> 2, kc = e & 3;
    gB[p] = Bmat + (size_t)(bn * 128 + row) * CQ + kc * 8;
  }

  fx4 acc[2][4];
#pragma unroll
  for (int a = 0; a < 2; ++a)
#pragma unroll
    for (int c = 0; c < 4; ++c) acc[a][c] = (fx4){0.f, 0.f, 0.f, 0.f};

#define STAGE_A(buf, it) do { int ke = (it) * 32;                                   \
    async16(gA + ke, sm[buf] + tid * 16);                                           \
    async16(gB[0] + ke, sm[buf] + 4096 + tid * 16);                                 \
    async16(gB[1] + ke, sm[buf] + 8192 + tid * 16); } while (0)

  STAGE_A(0, 0);
  for (int it = 0; it < 32; ++it) {
    int cur = it & 1;
    asm volatile("s_waitcnt vmcnt(0)");   // own stage-it loads landed
    __builtin_amdgcn_s_barrier();         // all waves: stage-it landed + it-1 reads done
    if (it < 31) STAGE_A(cur ^ 1, it + 1);
    const unsigned char* smb = sm[cur];
    s16x8 af[2], bf[4];
#pragma unroll
    for (int mt = 0; mt < 2; ++mt)
      af[mt] = *(const s16x8*)(smb + ((wm * 32 + mt * 16 + l15) * 32 + quad * 8) * 2);
#pragma unroll
    for (int nt = 0; nt < 4; ++nt)
      bf[nt] = *(const s16x8*)(smb + 4096 + ((wn * 64 + nt * 16 + l15) * 32 + quad * 8) * 2);
    __builtin_amdgcn_s_setprio(1);
#pragma unroll
    for (int mt = 0; mt < 2; ++mt)
#pragma unroll
      for (int nt = 0; nt < 4; ++nt)
        acc[mt][nt] = MFMA16(af[mt], bf[nt], acc[mt][nt]);
    __builtin_amdgcn_s_setprio(0);
  }
#undef STAGE_A

#pragma unroll
  for (int mt = 0; mt < 2; ++mt)
#pragma unroll
    for (int nt = 0; nt < 4; ++nt) {
      int n = bn * 128 + wn * 64 + nt * 16 + l15;
      int mbase = bm * 64 + wm * 32 + mt * 16 + quad * 4;
      fx4 vv = acc[mt][nt];
#pragma unroll
      for (int r = 0; r < 4; ++r) {
        int m = mbase + r;
        if (m < MTOT) Cbf[(size_t)m * 3072 + n] = f2b(vv[r]);
      }
    }
}

// ---------------- proj GEMM (64x64, BK=64) : 832 blocks, dbuf prefetch ----------------
__global__ __launch_bounds__(256) void k_gemmB(const unsigned short* __restrict__ Asrc,
                                               const unsigned short* __restrict__ Bmat,
                                               const int* __restrict__ idx_sel,
                                               float* __restrict__ Cf,
                                               const float* __restrict__ xin,
                                               const float* __restrict__ bproj) {
  int bid = blockIdx.x;
  int swz = (bid & 7) * 104 + (bid >> 3);   // XCD-contiguous chunks (832 = 8*104)
  int bm = swz % 52, bn = swz / 52;
  int tid = threadIdx.x;
  int w = tid >> 6, lane = tid & 63, quad = lane >> 4, l15 = lane & 15;
  int wm = w & 1, wn = w >> 1;
  __shared__ __align__(16) unsigned char sm[2][16384];   // A [64][64]bf16, B [64][64]bf16

  const unsigned short* g4[4];
#pragma unroll
  for (int p = 0; p < 4; ++p) {
    int e = (p & 1) * 256 + tid; int row = e >> 3, kc = e & 7;
    if (p < 2) {
      int m = bm * 64 + row; if (m >= MTOT) m = MTOT - 1;
      int bb = m / KSEL; int ii = m - bb * KSEL;
      g4[p] = Asrc + ((size_t)bb * KPAD + ii) * CQ + kc * 8;
    } else {
      g4[p] = Bmat + (size_t)(bn * 64 + row) * CQ + kc * 8;
    }
  }

  fx4 acc[2][2];
#pragma unroll
  for (int a = 0; a < 2; ++a)
#pragma unroll
    for (int c = 0; c < 2; ++c) acc[a][c] = (fx4){0.f, 0.f, 0.f, 0.f};

#define STAGE_B(buf, it) do { int ke = (it) * 64;                                   \
    _Pragma("unroll")                                                               \
    for (int p = 0; p < 4; ++p)                                                     \
      async16(g4[p] + ke, sm[buf] + p * 4096 + w * 1024);                           \
    } while (0)

  STAGE_B(0, 0);
  for (int it = 0; it < 16; ++it) {
    int cur = it & 1;
    if (it < 15) STAGE_B(cur ^ 1, it + 1);
    if (it < 15) asm volatile("s_waitcnt vmcnt(4)");
    else         asm volatile("s_waitcnt vmcnt(0)");
    __builtin_amdgcn_s_barrier();
    const unsigned char* smb = sm[cur];
#pragma unroll
    for (int kk = 0; kk < 2; ++kk) {
      s16x8 af[2], bf2[2];
#pragma unroll
      for (int mt = 0; mt < 2; ++mt)
        af[mt] = *(const s16x8*)(smb + ((wm * 32 + mt * 16 + l15) * 64 + kk * 32 + quad * 8) * 2);
#pragma unroll
      for (int nt = 0; nt < 2; ++nt)
        bf2[nt] = *(const s16x8*)(smb + 8192 + ((wn * 32 + nt * 16 + l15) * 64 + kk * 32 + quad * 8) * 2);
#pragma unroll
      for (int mt = 0; mt < 2; ++mt)
#pragma unroll
        for (int nt = 0; nt < 2; ++nt)
          acc[mt][nt] = MFMA16(af[mt], bf2[nt], acc[mt][nt]);
    }
    __builtin_amdgcn_s_barrier();    // all waves done reading cur before it's re-staged
  }
#undef STAGE_B

#pragma unroll
  for (int mt = 0; mt < 2; ++mt)
#pragma unroll
    for (int nt = 0; nt < 2; ++nt) {
      int n = bn * 64 + wn * 32 + nt * 16 + l15;
      int mbase = bm * 64 + wm * 32 + mt * 16 + quad * 4;
      fx4 vv = acc[mt][nt];
      float bp = bproj[n];
#pragma unroll
      for (int r = 0; r < 4; ++r) {
        int m = mbase + r;
        if (m < MTOT) {
          int bb = m / KSEL; int ii = m - bb * KSEL;
          int lsel = idx_sel[bb * KPAD + ii];
          size_t off = ((size_t)bb * LQ + lsel) * CQ + n;
          Cf[off] = xin[off] + vv[r] + bp;
        }
      }
    }
}

// ---------------- l2norm + scale + rope -> q,k ; v -> Vt (transposed) ----------------
__global__ __launch_bounds__(256) void k_normrope(const unsigned short* __restrict__ qkv,
                                                  const int* __restrict__ idx_sel,
                                                  const float* __restrict__ qbias,
                                                  const float* __restrict__ vbias,
                                                  const float* __restrict__ sml,
                                                  const float* __restrict__ rope,
                                                  unsigned short* __restrict__ qo,
                                                  unsigned short* __restrict__ ko,
                                                  unsigned short* __restrict__ vt) {
  int bid = blockIdx.x;                       // 26*16*2
  int tile = bid % 26; int h = (bid / 26) & 15; int b = bid / (26 * 16);
  int tid = threadIdx.x; int w = tid >> 6; int lane = tid & 63;
  int tk = lane >> 5, dl = lane & 31;         // token-half, d-pair index
  int d0 = dl * 2;
  __shared__ unsigned short vtile[64 * 68];
  float scale = expf(fminf(sml[h], 4.6051702f)) * 1.4426950408889634f;
  float2 qb2 = *(const float2*)(qbias + h * 64 + d0);
  float2 vb2 = *(const float2*)(vbias + h * 64 + d0);
  for (int pass = 0; pass < 8; ++pass) {
    int il = pass * 8 + w * 2 + tk;
    int i = tile * 64 + il;
    float v0 = 0.f, v1 = 0.f;
    if (i < KSEL) {
      int lsel = idx_sel[b * KPAD + i];
      size_t base = ((size_t)(b * KSEL + i)) * 3072 + h * 64 + d0;
      float r0 = rope[(size_t)lsel * 32 + dl];
      float r1 = rope[(size_t)LQ * 32 + (size_t)lsel * 32 + dl];
      // q
      unsigned int qw = *(const unsigned int*)(qkv + base);
      float q0 = b2f((unsigned short)qw) + qb2.x;
      float q1 = b2f((unsigned short)(qw >> 16)) + qb2.y;
      float ss = q0 * q0 + q1 * q1;
#pragma unroll
      for (int o = 1; o < 32; o <<= 1) ss += __shfl_xor(ss, o);
      float rn = scale / fmaxf(sqrtf(ss), 1e-12f);
      float qn0 = q0 * rn, qn1 = q1 * rn;
      *(unsigned int*)(qo + ((size_t)(b * NHQ + h) * KPAD + i) * 64 + d0) =
          cvtpk_bf16(r0 * qn0 - r1 * qn1, r1 * qn0 + r0 * qn1);
      // k
      unsigned int kw = *(const unsigned int*)(qkv + base + 1024);
      float k0 = b2f((unsigned short)kw);
      float k1 = b2f((unsigned short)(kw >> 16));
      float ks = k0 * k0 + k1 * k1;
#pragma unroll
      for (int o = 1; o < 32; o <<= 1) ks += __shfl_xor(ks, o);
      float rkn = 1.0f / fmaxf(sqrtf(ks), 1e-12f);
      float kn0 = k0 * rkn, kn1 = k1 * rkn;
      *(unsigned int*)(ko + ((size_t)(b * NHQ + h) * KPAD + i) * 64 + d0) =
          cvtpk_bf16(r0 * kn0 - r1 * kn1, r1 * kn0 + r0 * kn1);
      // v
      unsigned int vw = *(const unsigned int*)(qkv + base + 2048);
      v0 = b2f((unsigned short)vw) + vb2.x;
      v1 = b2f((unsigned short)(vw >> 16)) + vb2.y;
    }
    vtile[d0 * 68 + il] = f2b(v0);
    vtile[(d0 + 1) * 68 + il] = f2b(v1);
  }
  __syncthreads();
  int row = tid >> 2, c0 = (tid & 3) * 16;
  s16x8 o0, o1;
#pragma unroll
  for (int jj = 0; jj < 8; ++jj) {
    o0[jj] = (short)vtile[row * 68 + c0 + jj];
    o1[jj] = (short)vtile[row * 68 + c0 + 8 + jj];
  }
  size_t doff = ((size_t)((b * NHQ + h) * 64 + row)) * KPAD + (size_t)tile * 64 + c0;
  *(s16x8*)(vt + doff) = o0;
  *(s16x8*)(vt + doff + 8) = o1;
}

// ---------------- flash attention ----------------
// R18 (T1): 1D grid + XCD-chunk swizzle. 1248 = 8*156; 156 = 12*13 -> each XCD
// chunk holds 12 COMPLETE bh-groups (13 qt blocks each), so the 13 blocks sharing
// one (b,h,part) K/V panel run on ONE XCD's L2 (working set ~2.8MB < 4MB).
// Loop body = proven R4 structure (z=3 tiles 9/9/8, VGPR 64).
__global__ __launch_bounds__(256, 4) void k_attn(const unsigned short* __restrict__ qb,
                                                 const unsigned short* __restrict__ kb,
                                                 const unsigned short* __restrict__ vtb,
                                                 const float* __restrict__ sml,
                                                 unsigned short* __restrict__ pO,
                                                 float* __restrict__ pl) {
  int bid = blockIdx.x;                     // 1248 = 13*32*3
  int swz = (bid & 7) * 156 + (bid >> 3);   // XCD-contiguous chunks
  int part = swz / 416;                     // 416 = 13*32
  int rem = swz - part * 416;
  int bh = rem / 13;
  int qt = rem - bh * 13;
  int b = bh >> 4, h = bh & 15;
  int t0 = part * 9;
  int t1 = (part == 2) ? 26 : t0 + 9;
  int q0 = qt * 128;
  int tid = threadIdx.x, w = tid >> 6, lane = tid & 63, quad = lane >> 4, l15 = lane & 15;
  float M = __expf(fminf(sml[h], 4.6051702f)) * 1.4426950408889634f;  // log2-domain shift
  __shared__ __align__(16) unsigned short Kt[64 * 72];     //  9216 B
  __shared__ __align__(16) unsigned short Vt[64 * 72];     //  9216 B
  __shared__ __align__(16) unsigned short Pq[4][32 * 72];  // 18432 B (total 36864 -> 4 blk/CU)
  unsigned short* Pw = Pq[w];
  const unsigned short* qbase = qb + (size_t)(b * NHQ + h) * KPAD * 64;
  const unsigned short* kbase = kb + (size_t)(b * NHQ + h) * KPAD * 64;
  const unsigned short* vbase = vtb + (size_t)(b * NHQ + h) * 64 * KPAD;

  // staging geometry: 512 s16x8 chunks per K (and V) tile, 2 per thread
  int r0 = tid >> 3, c0 = tid & 7;            // chunk 0: rows 0..31
  int r1 = 32 + r0, c1 = c0;                  // chunk 1: rows 32..63

  // Q as B-operand: n=l15 -> q row; k = kb2*32 + quad*8
  s16x8 qf[2][2];
#pragma unroll
  for (int qtile = 0; qtile < 2; ++qtile)
#pragma unroll
    for (int kb2 = 0; kb2 < 2; ++kb2) {
      int row = q0 + w * 32 + qtile * 16 + l15;
      qf[qtile][kb2] = *(const s16x8*)(qbase + (size_t)row * 64 + kb2 * 32 + quad * 8);
    }

  float lsum[2] = {0.f, 0.f};
  fx4 oacc[2][4];
#pragma unroll
  for (int qtile = 0; qtile < 2; ++qtile)
#pragma unroll
    for (int dt = 0; dt < 4; ++dt) oacc[qtile][dt] = (fx4){0.f, 0.f, 0.f, 0.f};

  // prologue: issue tile t0's loads (T14 async-STAGE split)
  s16x8 kn0, kn1, vn0, vn1;
  {
    int j0 = t0 * 64;
    kn0 = *(const s16x8*)(kbase + (size_t)(j0 + r0) * 64 + c0 * 8);
    kn1 = *(const s16x8*)(kbase + (size_t)(j0 + r1) * 64 + c1 * 8);
    vn0 = *(const s16x8*)(vbase + (size_t)r0 * KPAD + j0 + c0 * 8);
    vn1 = *(const s16x8*)(vbase + (size_t)r1 * KPAD + j0 + c1 * 8);
  }

  for (int t = t0; t < t1; ++t) {
    int j0 = t * 64;
    bool tail = (j0 + 64 > KSEL);
    __builtin_amdgcn_s_barrier();    // all waves done reading prev Kt/Vt
    *(s16x8*)(Kt + r0 * 72 + c0 * 8) = kn0;
    *(s16x8*)(Kt + r1 * 72 + c1 * 8) = kn1;
    *(s16x8*)(Vt + r0 * 72 + c0 * 8) = vn0;
    *(s16x8*)(Vt + r1 * 72 + c1 * 8) = vn1;
    // issue next tile's loads; they stay in flight under this tile's compute
    if (t + 1 < t1) {
      int jn = (t + 1) * 64;
      kn0 = *(const s16x8*)(kbase + (size_t)(jn + r0) * 64 + c0 * 8);
      kn1 = *(const s16x8*)(kbase + (size_t)(jn + r1) * 64 + c1 * 8);
      vn0 = *(const s16x8*)(vbase + (size_t)r0 * KPAD + jn + c0 * 8);
      vn1 = *(const s16x8*)(vbase + (size_t)r1 * KPAD + jn + c1 * 8);
    }
    asm volatile("s_waitcnt lgkmcnt(0)" ::: "memory");   // ds_writes visible
    __builtin_amdgcn_s_barrier();

    // S^T -> exp2 -> wave-private P -> PV
    fx4 sacc[2][4];
#pragma unroll
    for (int qtile = 0; qtile < 2; ++qtile)
#pragma unroll
      for (int jj = 0; jj < 4; ++jj) sacc[qtile][jj] = (fx4){0.f, 0.f, 0.f, 0.f};
    __builtin_amdgcn_s_setprio(1);
#pragma unroll
    for (int jj = 0; jj < 4; ++jj) {
      int jl = jj * 16 + l15;
      s16x8 kf0 = *(const s16x8*)(Kt + jl * 72 + quad * 8);
      s16x8 kf1 = *(const s16x8*)(Kt + jl * 72 + 32 + quad * 8);
      sacc[0][jj] = MFMA16(kf0, qf[0][0], sacc[0][jj]);
      sacc[1][jj] = MFMA16(kf0, qf[1][0], sacc[1][jj]);
      sacc[0][jj] = MFMA16(kf1, qf[0][1], sacc[0][jj]);
      sacc[1][jj] = MFMA16(kf1, qf[1][1], sacc[1][jj]);
    }
    __builtin_amdgcn_s_setprio(0);
#pragma unroll
    for (int qtile = 0; qtile < 2; ++qtile)
#pragma unroll
      for (int jj = 0; jj < 4; ++jj) {
        int jbase = j0 + jj * 16 + quad * 4;
        fx4 sv = sacc[qtile][jj];
        float p0 = fexp2(sv[0] - M);
        float p1 = fexp2(sv[1] - M);
        float p2 = fexp2(sv[2] - M);
        float p3 = fexp2(sv[3] - M);
        if (tail) {
          if (jbase + 0 >= KSEL) p0 = 0.f;
          if (jbase + 1 >= KSEL) p1 = 0.f;
          if (jbase + 2 >= KSEL) p2 = 0.f;
          if (jbase + 3 >= KSEL) p3 = 0.f;
        }
        lsum[qtile] += (p0 + p1) + (p2 + p3);
        *(uint2*)(Pw + (qtile * 16 + l15) * 72 + jj * 16 + quad * 4) =
            make_uint2(cvtpk_bf16(p0, p1), cvtpk_bf16(p2, p3));
      }
    // PV: A=P (wave-private LDS), B=V (LDS)
    __builtin_amdgcn_s_setprio(1);
#pragma unroll
    for (int js = 0; js < 2; ++js) {
      s16x8 pf0 = *(const s16x8*)(Pw + l15 * 72 + js * 32 + quad * 8);
      s16x8 pf1 = *(const s16x8*)(Pw + (16 + l15) * 72 + js * 32 + quad * 8);
#pragma unroll
      for (int dt = 0; dt < 4; ++dt) {
        s16x8 vf = *(const s16x8*)(Vt + (dt * 16 + l15) * 72 + js * 32 + quad * 8);
        oacc[0][dt] = MFMA16(pf0, vf, oacc[0][dt]);
        oacc[1][dt] = MFMA16(pf1, vf, oacc[1][dt]);
      }
    }
    __builtin_amdgcn_s_setprio(0);
  }

  // combine quad-partitioned j-sums (lanes l15, +16, +32, +48 hold disjoint j sets)
#pragma unroll
  for (int qtile = 0; qtile < 2; ++qtile) {
    float s = lsum[qtile];
    s += __shfl_xor(s, 16);
    s += __shfl_xor(s, 32);
    lsum[qtile] = s;
  }

  size_t pbase = (((size_t)part * 2 + b) * NHQ + h) * KPAD;
#pragma unroll
  for (int qtile = 0; qtile < 2; ++qtile) {
    int gqb = q0 + w * 32 + qtile * 16;
    if (quad == 0) pl[pbase + gqb + l15] = lsum[qtile];
  }

  // transpose O through the (now free) wave-private P buffer -> coalesced stores
#pragma unroll
  for (int qtile = 0; qtile < 2; ++qtile)
#pragma unroll
    for (int dt = 0; dt < 4; ++dt)
#pragma unroll
      for (int r = 0; r < 4; ++r)
        Pw[(qtile * 16 + quad * 4 + r) * 72 + dt * 16 + l15] = f2b(oacc[qtile][dt][r]);
#pragma unroll
  for (int pass = 0; pass < 4; ++pass) {
    int row = pass * 8 + (lane >> 3), chunk = lane & 7;
    s16x8 vv = *(const s16x8*)(Pw + row * 72 + chunk * 8);
    *(s16x8*)(pO + (pbase + q0 + w * 32 + row) * 64 + chunk * 8) = vv;
  }
}

// ---------------- combine the three j-parts (vectorized x8): o = sum(O_p)/sum(l_p) ---------
__global__ __launch_bounds__(256) void k_comb(const unsigned short* __restrict__ pO,
                                              const float* __restrict__ pl,
                                              unsigned short* __restrict__ ob) {
  size_t g8 = (size_t)blockIdx.x * 256 + threadIdx.x;  // 425984 = 3407872/8
  size_t base = g8 * 8;
  int d0 = (int)(base & 63);
  size_t row = base >> 6;           // (b*16+h)*1664 + gq
  int gq = (int)(row % KPAD);
  int bhh = (int)(row / KPAD);
  int b = bhh >> 4, h = bhh & 15;
  uint4 p0 = *(const uint4*)(pO + base);
  uint4 p1 = *(const uint4*)(pO + base + 3407872);
  uint4 p2 = *(const uint4*)(pO + base + 2 * 3407872);
  float ls = pl[row] + pl[row + 53248] + pl[row + 2 * 53248];
  float rc = 1.0f / ls;
  unsigned int pw0[4] = {p0.x, p0.y, p0.z, p0.w};
  unsigned int pw1[4] = {p1.x, p1.y, p1.z, p1.w};
  unsigned int pw2[4] = {p2.x, p2.y, p2.z, p2.w};
  unsigned int ow[4];
#pragma unroll
  for (int j = 0; j < 4; ++j) {
    float lo = (b2f((unsigned short)pw0[j]) + b2f((unsigned short)pw1[j]) +
                b2f((unsigned short)pw2[j])) * rc;
    float hi = (b2f((unsigned short)(pw0[j] >> 16)) + b2f((unsigned short)(pw1[j] >> 16)) +
                b2f((unsigned short)(pw2[j] >> 16))) * rc;
    ow[j] = cvtpk_bf16(lo, hi);
  }
  *(uint4*)(ob + ((size_t)(b * KPAD + gq)) * CQ + h * 64 + d0) =
      make_uint4(ow[0], ow[1], ow[2], ow[3]);
}

extern "C" void kernel_launch(void* const* d_in, const int* in_sizes, int n_in,
                              void* d_out, int out_size, void* d_ws, size_t ws_size,
                              hipStream_t stream) {
  const float* x      = (const float*)d_in[0];
  const float* cached = (const float*)d_in[1];
  const float* wqkv   = (const float*)d_in[2];
  const float* qbias  = (const float*)d_in[3];
  const float* vbias  = (const float*)d_in[4];
  const float* wproj  = (const float*)d_in[5];
  const float* bproj  = (const float*)d_in[6];
  const float* sml    = (const float*)d_in[7];
  const float* rope   = (const float*)d_in[8];
  float* out = (float*)d_out;
  char* ws = (char*)d_ws;

  double* meanpart        = (double*)(ws);                    // 524288
  double* mean            = (double*)(ws + 524288);           // 16384
  double* mse             = (double*)(ws + 540672);           // 65536
  int* idx_sel            = (int*)(ws + 606208);              // 13312 -> 619520
  // overlap zone [619520, 44135424): x_bf + wqkv_bf + qkv (dead after k_normrope)
  unsigned short* x_bf    = (unsigned short*)(ws + 619520);   // 16777216
  unsigned short* wqkv_bf = (unsigned short*)(ws + 17396736); // 6291456
  unsigned short* qkv     = (unsigned short*)(ws + 23688192); // 20447232 -> 44135424
  // attn partials (3 parts) reuse the dead x_bf/wqkv_bf/qkv region
  unsigned short* pO      = (unsigned short*)(ws + 619520);   // 20447232
  float* pl               = (float*)(ws + 21066752);          // 638976 -> 21705728
  unsigned short* wproj_bf= (unsigned short*)(ws + 44135424); // 2097152
  unsigned short* qo      = (unsigned short*)(ws + 46232576); // 6815744
  unsigned short* ko      = (unsigned short*)(ws + 53048320); // 6815744
  unsigned short* vt      = (unsigned short*)(ws + 59864064); // 6815744
  unsigned short* ob      = (unsigned short*)(ws + 66679808); // 6815744 -> 73495552

  hipLaunchKernelGGL(k_mean_part, dim3(256), dim3(256), 0, stream, x, meanpart);
  hipLaunchKernelGGL(k_mean_reduce, dim3(8), dim3(256), 0, stream, meanpart, mean);
  hipLaunchKernelGGL(k_mse_base, dim3(8192), dim3(256), 0, stream, x, cached, mean, mse,
                     out, x_bf);
  hipLaunchKernelGGL(k_topk, dim3(2 + 1024), dim3(1024), 0, stream, mse, idx_sel,
                     wqkv, wproj, wqkv_bf, wproj_bf);
  hipLaunchKernelGGL(k_gemmA, dim3(52 * 24), dim3(256), 0, stream,
                     x_bf, wqkv_bf, idx_sel, qkv);
  hipLaunchKernelGGL(k_normrope, dim3(26 * 16 * BQ), dim3(256), 0, stream,
                     qkv, idx_sel, qbias, vbias, sml, rope, qo, ko, vt);
  hipLaunchKernelGGL(k_attn, dim3(1248), dim3(256), 0, stream,
                     qo, ko, vt, sml, pO, pl);
  hipLaunchKernelGGL(k_comb, dim3(1664), dim3(256), 0, stream, pO, pl, ob);
  hipLaunchKernelGGL(k_gemmB, dim3(832), dim3(256), 0, stream,
                     ob, wproj_bf, idx_sel, out, x, bproj);
}

// Round 13
// 265.077 us; speedup vs baseline: 1.0954x; 1.0034x over previous
//
#include <hip/hip_runtime.h>
#include <hip/hip_bf16.h>
#include <math.h>

// Problem constants (setup_inputs)
#define BQ   2
#define LQ   4096
#define CQ   1024
#define NHQ  16
#define DHQ  64
#define KSEL 1638
#define KPAD 1664
#define MTOT (BQ*KSEL)   // 3276
#define MPAD 3328        // 26*128

typedef short s16x8 __attribute__((ext_vector_type(8)));
typedef float fx4   __attribute__((ext_vector_type(4)));

#define MFMA16(a,b,c) __builtin_amdgcn_mfma_f32_16x16x32_bf16(a,b,c,0,0,0)

__device__ __forceinline__ float b2f(unsigned short u) {
  union { float f; unsigned int i; } cv; cv.i = ((unsigned int)u) << 16; return cv.f;
}
__device__ __forceinline__ unsigned short f2b(float f) {
  union { float f; unsigned int i; } cv; cv.f = f;
  unsigned int x = cv.i;
  return (unsigned short)((x + 0x7fffu + ((x >> 16) & 1u)) >> 16);
}
__device__ __forceinline__ unsigned int fbits(float f) {
  union { float f; unsigned int i; } cv; cv.f = f; return cv.i;
}
// packed f32x2 -> bf16x2 (RNE), single VALU op
__device__ __forceinline__ unsigned int cvtpk_bf16(float a, float b) {
  unsigned int r;
  asm("v_cvt_pk_bf16_f32 %0, %1, %2" : "=v"(r) : "v"(a), "v"(b));
  return r;
}
__device__ __forceinline__ void async16(const void* g, void* l) {
  __builtin_amdgcn_global_load_lds((const __attribute__((address_space(1))) void*)g,
                                   (__attribute__((address_space(3))) void*)l, 16, 0, 0);
}
// raw 2^x (q is pre-scaled by log2(e) in k_normrope, M is in log2 units)
__device__ __forceinline__ float fexp2(float x) {
#if __has_builtin(__builtin_amdgcn_exp2f)
  return __builtin_amdgcn_exp2f(x);
#else
  return __expf(x * 0.69314718055994531f);
#endif
}

// ---------------- mean (fp64, 2-stage) ----------------
__global__ __launch_bounds__(256) void k_mean_part(const float* __restrict__ x,
                                                   double* __restrict__ part) {
  int bid = blockIdx.x;                    // 256 blocks: [b(2)][ch(32)][cb(4)]
  int cb = bid & 3, ch = (bid >> 2) & 31, b = bid >> 7;
  int c = cb * 256 + threadIdx.x;
  const float* p = x + ((size_t)b * LQ + (size_t)ch * 128) * CQ + c;
  double s = 0.0;
  for (int r = 0; r < 128; ++r) s += (double)p[(size_t)r * CQ];
  part[((size_t)b * 32 + ch) * CQ + c] = s;
}

__global__ __launch_bounds__(256) void k_mean_reduce(const double* __restrict__ part,
                                                     double* __restrict__ mean) {
  int g = blockIdx.x * 256 + threadIdx.x;  // 2048 = B*C
  int b = g >> 10, c = g & 1023;
  double s = 0.0;
  for (int ch = 0; ch < 32; ++ch) s += part[((size_t)b * 32 + ch) * CQ + c];
  mean[g] = s * (1.0 / 4096.0);
}

// ---------------- mse (fp64) + base output (x + upsample(cached)) + x->bf16 ----------------
__global__ __launch_bounds__(256) void k_mse_base(const float* __restrict__ x,
                                                  const float* __restrict__ cached,
                                                  const double* __restrict__ mean,
                                                  double* __restrict__ mse,
                                                  float* __restrict__ out,
                                                  unsigned short* __restrict__ xb) {
  int bl = blockIdx.x; int b = bl >> 12, l = bl & 4095;
  int hh = l >> 6, ww = l & 63;
  size_t xoff = ((size_t)b * LQ + l) * CQ;
  size_t uoff = (((size_t)b * 32 + (hh >> 1)) * 32 + (ww >> 1)) * CQ;
  const double* mrow = mean + (size_t)b * CQ;
  int c0 = threadIdx.x * 4;
  float4 xv = *(const float4*)(x + xoff + c0);
  float4 uv = *(const float4*)(cached + uoff + c0);
  float4 ov;
  ov.x = xv.x + uv.x; ov.y = xv.y + uv.y; ov.z = xv.z + uv.z; ov.w = xv.w + uv.w;
  *(float4*)(out + xoff + c0) = ov;
  ushort4 xo;
  xo.x = f2b(xv.x); xo.y = f2b(xv.y); xo.z = f2b(xv.z); xo.w = f2b(xv.w);
  ((ushort4*)xb)[(xoff + c0) >> 2] = xo;
  double d0 = (double)xv.x - mrow[c0];
  double d1 = (double)xv.y - mrow[c0 + 1];
  double d2 = (double)xv.z - mrow[c0 + 2];
  double d3 = (double)xv.w - mrow[c0 + 3];
  double ss = d0 * d0 + d1 * d1 + d2 * d2 + d3 * d3;
  for (int o = 1; o < 64; o <<= 1) ss += __shfl_xor(ss, o);
  __shared__ double ws4[4];
  if ((threadIdx.x & 63) == 0) ws4[threadIdx.x >> 6] = ss;
  __syncthreads();
  if (threadIdx.x == 0) mse[(size_t)b * LQ + l] = ws4[0] + ws4[1] + ws4[2] + ws4[3];
}

// ---------------- top-k (blocks 0,1) + fused weight fp32->bf16 conversion (blocks >=2) ----
// 4-pass radix over the HIGH 32 BITS (mse >= 0); tie group resolved exactly.
__global__ __launch_bounds__(1024) void k_topk(const double* __restrict__ mse,
                                               int* __restrict__ idx_sel,
                                               const float* __restrict__ wqkv,
                                               const float* __restrict__ wproj,
                                               unsigned short* __restrict__ wqb,
                                               unsigned short* __restrict__ wpb) {
  if (blockIdx.x >= 2) {   // conversion path: 1024 blocks x 1024 thr x 1 float4
    int i = (blockIdx.x - 2) * 1024 + threadIdx.x;
    const float* s; unsigned short* d; int off;
    if (i < 786432) { s = wqkv;  d = wqb; off = i; }
    else            { s = wproj; d = wpb; off = i - 786432; }
    float4 v = ((const float4*)s)[off];
    ushort4 o;
    o.x = f2b(v.x); o.y = f2b(v.y); o.z = f2b(v.z); o.w = f2b(v.w);
    ((ushort4*)d)[off] = o;
    return;
  }
  __shared__ unsigned long long u[4096];       // 32 KB
  __shared__ unsigned int whist[16 * 257];     // 16.4 KB, stride 257 => cross-wave bank skew
  __shared__ unsigned int wtot[4];
  __shared__ unsigned long long sh_prefix;
  __shared__ int sh_rem, sh_rem2, sh_bsel, sh_cnt, sh_eqcnt;
  __shared__ int eqbuf[256];
  int b = blockIdx.x, t = threadIdx.x;
  int wv = t >> 6, laneid = t & 63;
  for (int p = 0; p < 4; ++p) {
    int i = p * 1024 + t;
    u[i] = (unsigned long long)__double_as_longlong(mse[(size_t)b * LQ + i]);
  }
  if (t == 0) { sh_prefix = 0ULL; sh_rem = KSEL; sh_cnt = 0; sh_eqcnt = 0; }
  __syncthreads();
  for (int shift = 56; shift >= 32; shift -= 8) {   // high 32 bits only
    for (int z = t; z < 16 * 257; z += 1024) whist[z] = 0u;
    __syncthreads();
    unsigned long long pref = sh_prefix;
#pragma unroll
    for (int p = 0; p < 4; ++p) {
      int i = p * 1024 + t;
      unsigned long long v = u[i];
      bool cand = (shift == 56) || ((v >> ((shift + 8) & 63)) == pref);
      if (cand) atomicAdd(&whist[wv * 257 + ((unsigned int)(v >> shift) & 255u)], 1u);
    }
    __syncthreads();
    unsigned int myc = 0, mysc = 0;
    if (t < 256) {            // combine the 16 wave hists for my bin (bin = 255 - t)
      unsigned int s = 0;
      int bin = 255 - t;
#pragma unroll
      for (int wvi = 0; wvi < 16; ++wvi) s += whist[wvi * 257 + bin];
      myc = s;
      mysc = myc;
#pragma unroll
      for (int o = 1; o < 64; o <<= 1) {
        unsigned int v2 = __shfl_up(mysc, o);
        if (laneid >= o) mysc += v2;
      }
      if (laneid == 63) wtot[wv] = mysc;
    }
    __syncthreads();
    if (t < 256) {
      unsigned int basep = 0;
      for (int wvi = 0; wvi < wv; ++wvi) basep += wtot[wvi];
      unsigned int incl = basep + mysc;       // count of keys in bins >= my bin
      unsigned int excl = incl - myc;         // count of keys in bins >  my bin
      unsigned int rem = (unsigned int)sh_rem;
      if (excl < rem && rem <= incl) {        // exactly one thread crosses
        sh_bsel = 255 - t;
        sh_rem2 = (int)(rem - excl);
      }
    }
    __syncthreads();
    if (t == 0) {
      sh_prefix = (sh_prefix << 8) | (unsigned long long)sh_bsel;
      sh_rem = sh_rem2;
    }
    __syncthreads();
  }
  unsigned long long T = sh_prefix;           // threshold on the high 32 bits
  int rem_eq = sh_rem;
#pragma unroll
  for (int p = 0; p < 4; ++p) {
    int i = p * 1024 + t;
    unsigned long long v = u[i];
    bool win = ((v >> 32) > T);
    unsigned long long mask = __ballot(win);
    int total = __popcll(mask);
    int base = 0;
    if (laneid == 0 && total > 0) base = atomicAdd(&sh_cnt, total);
    base = __shfl(base, 0);
    if (win) {
      int lpos = __popcll(mask & ((1ULL << laneid) - 1ULL));
      idx_sel[b * KPAD + base + lpos] = i;
    }
    if ((v >> 32) == T) {
      int e = atomicAdd(&sh_eqcnt, 1);
      if (e < 256) eqbuf[e] = i;
    }
  }
  __syncthreads();
  if (t == 0) {
    int n = sh_eqcnt; if (n > 256) n = 256;
    // sort eq group by (full value desc, index asc) -- exact double ordering
    for (int a = 1; a < n; ++a) {
      int key = eqbuf[a]; unsigned long long kv = u[key]; int c = a - 1;
      while (c >= 0 && (u[eqbuf[c]] < kv || (u[eqbuf[c]] == kv && eqbuf[c] > key))) {
        eqbuf[c + 1] = eqbuf[c]; --c;
      }
      eqbuf[c + 1] = key;
    }
    int base = sh_cnt;
    for (int a = 0; a < rem_eq && a < n; ++a) idx_sel[b * KPAD + base + a] = eqbuf[a];
    for (int a = KSEL; a < KPAD; ++a) idx_sel[b * KPAD + a] = 0;
  }
}

// ---------------- qkv GEMM (64x128, BK=32), 1248 blocks, split-depth pipeline ------------
// R19: operand-split prefetch depth. B panels are L2-resident (bn-major XCD chunks,
// ~200cy) -> depth-1 suffices; A rows come from HBM (~900cy) -> depth-2 via 3
// rotating 4KB A-buffers. B keeps 2x8KB. LDS 28672 -> 5 blk/CU cap >= 4.9 avg grid.
// vmcnt: queue at iter x = [A(x), B(x), A(x+1)] -> wait vmcnt(1); after barrier
// issue B(x+1) THEN A(x+2) (keeps queue sorted oldest-first).
__global__ __launch_bounds__(256) void k_gemmA(const unsigned short* __restrict__ Asrc,
                                               const unsigned short* __restrict__ Bmat,
                                               const int* __restrict__ idx_sel,
                                               unsigned short* __restrict__ Cbf) {
  int bid = blockIdx.x;
  int swz = (bid & 7) * 156 + (bid >> 3);   // XCD-contiguous chunks (1248 = 8*156)
  int bm = swz % 52, bn = swz / 52;
  int tid = threadIdx.x;
  int w = tid >> 6, lane = tid & 63, quad = lane >> 4, l15 = lane & 15;
  int wm = w & 1, wn = w >> 1;
  __shared__ __align__(16) unsigned char smA[3 * 4096];    // A [64][32]bf16 x3
  __shared__ __align__(16) unsigned char smB[2 * 8192];    // B [128][32]bf16 x2

  const unsigned short* gA;
  {
    int row = tid >> 2, kc = tid & 3;
    int m = bm * 64 + row; if (m >= MTOT) m = MTOT - 1;
    int bb = m / KSEL; int ii = m - bb * KSEL;
    int lsel = idx_sel[bb * KPAD + ii];
    gA = Asrc + ((size_t)bb * LQ + lsel) * CQ + kc * 8;
  }
  const unsigned short* gB[2];
#pragma unroll
  for (int p = 0; p < 2; ++p) {
    int e = p * 256 + tid; int row = e >> 2, kc = e & 3;
    gB[p] = Bmat + (size_t)(bn * 128 + row) * CQ + kc * 8;
  }

  fx4 acc[2][4];
#pragma unroll
  for (int a = 0; a < 2; ++a)
#pragma unroll
    for (int c = 0; c < 4; ++c) acc[a][c] = (fx4){0.f, 0.f, 0.f, 0.f};

#define STAGE_AA(abuf, it) \
    async16(gA + (it) * 32, smA + (abuf) * 4096 + tid * 16)
#define STAGE_AB(bbuf, it) do { int ke = (it) * 32;                                 \
    async16(gB[0] + ke, smB + (bbuf) * 8192 + tid * 16);                            \
    async16(gB[1] + ke, smB + (bbuf) * 8192 + 4096 + tid * 16); } while (0)

  // prologue queue: [A0, B0, A1]
  STAGE_AA(0, 0);
  STAGE_AB(0, 0);
  STAGE_AA(1, 1);
  for (int it = 0; it < 32; ++it) {
    int ab = it % 3, bb2 = it & 1;
    if (it < 31) asm volatile("s_waitcnt vmcnt(1)");   // A(it),B(it) landed; A(it+1) in flight
    else         asm volatile("s_waitcnt vmcnt(0)");
    __builtin_amdgcn_s_barrier();   // all waves: stage-it landed, it-1 readers done
    if (it < 31) STAGE_AB(bb2 ^ 1, it + 1);           // B first (older) ...
    if (it < 30) STAGE_AA((it + 2) % 3, it + 2);      // ... then deep A
    const unsigned char* sa = smA + ab * 4096;
    const unsigned char* sb = smB + bb2 * 8192;
    s16x8 af[2], bf[4];
#pragma unroll
    for (int mt = 0; mt < 2; ++mt)
      af[mt] = *(const s16x8*)(sa + ((wm * 32 + mt * 16 + l15) * 32 + quad * 8) * 2);
#pragma unroll
    for (int nt = 0; nt < 4; ++nt)
      bf[nt] = *(const s16x8*)(sb + ((wn * 64 + nt * 16 + l15) * 32 + quad * 8) * 2);
    __builtin_amdgcn_s_setprio(1);
#pragma unroll
    for (int mt = 0; mt < 2; ++mt)
#pragma unroll
      for (int nt = 0; nt < 4; ++nt)
        acc[mt][nt] = MFMA16(af[mt], bf[nt], acc[mt][nt]);
    __builtin_amdgcn_s_setprio(0);
  }
#undef STAGE_AA
#undef STAGE_AB

#pragma unroll
  for (int mt = 0; mt < 2; ++mt)
#pragma unroll
    for (int nt = 0; nt < 4; ++nt) {
      int n = bn * 128 + wn * 64 + nt * 16 + l15;
      int mbase = bm * 64 + wm * 32 + mt * 16 + quad * 4;
      fx4 vv = acc[mt][nt];
#pragma unroll
      for (int r = 0; r < 4; ++r) {
        int m = mbase + r;
        if (m < MTOT) Cbf[(size_t)m * 3072 + n] = f2b(vv[r]);
      }
    }
}

// ---------------- proj GEMM (64x64, BK=64) : 832 blocks, single-barrier dbuf ------------
// R19: same single-barrier transform as gemmA (vmcnt(0); barrier; stage(it+1); compute).
__global__ __launch_bounds__(256) void k_gemmB(const unsigned short* __restrict__ Asrc,
                                               const unsigned short* __restrict__ Bmat,
                                               const int* __restrict__ idx_sel,
                                               float* __restrict__ Cf,
                                               const float* __restrict__ xin,
                                               const float* __restrict__ bproj) {
  int bid = blockIdx.x;
  int swz = (bid & 7) * 104 + (bid >> 3);   // XCD-contiguous chunks (832 = 8*104)
  int bm = swz % 52, bn = swz / 52;
  int tid = threadIdx.x;
  int w = tid >> 6, lane = tid & 63, quad = lane >> 4, l15 = lane & 15;
  int wm = w & 1, wn = w >> 1;
  __shared__ __align__(16) unsigned char sm[2][16384];   // A [64][64]bf16, B [64][64]bf16

  const unsigned short* g4[4];
#pragma unroll
  for (int p = 0; p < 4; ++p) {
    int e = (p & 1) * 256 + tid; int row = e >> 3, kc = e & 7;
    if (p < 2) {
      int m = bm * 64 + row; if (m >= MTOT) m = MTOT - 1;
      int bb = m / KSEL; int ii = m - bb * KSEL;
      g4[p] = Asrc + ((size_t)bb * KPAD + ii) * CQ + kc * 8;
    } else {
      g4[p] = Bmat + (size_t)(bn * 64 + row) * CQ + kc * 8;
    }
  }

  fx4 acc[2][2];
#pragma unroll
  for (int a = 0; a < 2; ++a)
#pragma unroll
    for (int c = 0; c < 2; ++c) acc[a][c] = (fx4){0.f, 0.f, 0.f, 0.f};

#define STAGE_B(buf, it) do { int ke = (it) * 64;                                   \
    _Pragma("unroll")                                                               \
    for (int p = 0; p < 4; ++p)                                                     \
      async16(g4[p] + ke, sm[buf] + p * 4096 + w * 1024);                           \
    } while (0)

  STAGE_B(0, 0);
  for (int it = 0; it < 16; ++it) {
    int cur = it & 1;
    asm volatile("s_waitcnt vmcnt(0)");
    __builtin_amdgcn_s_barrier();
    if (it < 15) STAGE_B(cur ^ 1, it + 1);
    const unsigned char* smb = sm[cur];
#pragma unroll
    for (int kk = 0; kk < 2; ++kk) {
      s16x8 af[2], bf2[2];
#pragma unroll
      for (int mt = 0; mt < 2; ++mt)
        af[mt] = *(const s16x8*)(smb + ((wm * 32 + mt * 16 + l15) * 64 + kk * 32 + quad * 8) * 2);
#pragma unroll
      for (int nt = 0; nt < 2; ++nt)
        bf2[nt] = *(const s16x8*)(smb + 8192 + ((wn * 32 + nt * 16 + l15) * 64 + kk * 32 + quad * 8) * 2);
      __builtin_amdgcn_s_setprio(1);
#pragma unroll
      for (int mt = 0; mt < 2; ++mt)
#pragma unroll
        for (int nt = 0; nt < 2; ++nt)
          acc[mt][nt] = MFMA16(af[mt], bf2[nt], acc[mt][nt]);
      __builtin_amdgcn_s_setprio(0);
    }
  }
#undef STAGE_B

#pragma unroll
  for (int mt = 0; mt < 2; ++mt)
#pragma unroll
    for (int nt = 0; nt < 2; ++nt) {
      int n = bn * 64 + wn * 32 + nt * 16 + l15;
      int mbase = bm * 64 + wm * 32 + mt * 16 + quad * 4;
      fx4 vv = acc[mt][nt];
      float bp = bproj[n];
#pragma unroll
      for (int r = 0; r < 4; ++r) {
        int m = mbase + r;
        if (m < MTOT) {
          int bb = m / KSEL; int ii = m - bb * KSEL;
          int lsel = idx_sel[bb * KPAD + ii];
          size_t off = ((size_t)bb * LQ + lsel) * CQ + n;
          Cf[off] = xin[off] + vv[r] + bp;
        }
      }
    }
}

// ---------------- l2norm + scale + rope -> q,k ; v -> Vt (transposed) ----------------
__global__ __launch_bounds__(256) void k_normrope(const unsigned short* __restrict__ qkv,
                                                  const int* __restrict__ idx_sel,
                                                  const float* __restrict__ qbias,
                                                  const float* __restrict__ vbias,
                                                  const float* __restrict__ sml,
                                                  const float* __restrict__ rope,
                                                  unsigned short* __restrict__ qo,
                                                  unsigned short* __restrict__ ko,
                                                  unsigned short* __restrict__ vt) {
  int bid = blockIdx.x;                       // 26*16*2
  int tile = bid % 26; int h = (bid / 26) & 15; int b = bid / (26 * 16);
  int tid = threadIdx.x; int w = tid >> 6; int lane = tid & 63;
  int tk = lane >> 5, dl = lane & 31;         // token-half, d-pair index
  int d0 = dl * 2;
  __shared__ unsigned short vtile[64 * 68];
  float scale = expf(fminf(sml[h], 4.6051702f)) * 1.4426950408889634f;
  float2 qb2 = *(const float2*)(qbias + h * 64 + d0);
  float2 vb2 = *(const float2*)(vbias + h * 64 + d0);
  for (int pass = 0; pass < 8; ++pass) {
    int il = pass * 8 + w * 2 + tk;
    int i = tile * 64 + il;
    float v0 = 0.f, v1 = 0.f;
    if (i < KSEL) {
      int lsel = idx_sel[b * KPAD + i];
      size_t base = ((size_t)(b * KSEL + i)) * 3072 + h * 64 + d0;
      float r0 = rope[(size_t)lsel * 32 + dl];
      float r1 = rope[(size_t)LQ * 32 + (size_t)lsel * 32 + dl];
      // q
      unsigned int qw = *(const unsigned int*)(qkv + base);
      float q0 = b2f((unsigned short)qw) + qb2.x;
      float q1 = b2f((unsigned short)(qw >> 16)) + qb2.y;
      float ss = q0 * q0 + q1 * q1;
#pragma unroll
      for (int o = 1; o < 32; o <<= 1) ss += __shfl_xor(ss, o);
      float rn = scale / fmaxf(sqrtf(ss), 1e-12f);
      float qn0 = q0 * rn, qn1 = q1 * rn;
      *(unsigned int*)(qo + ((size_t)(b * NHQ + h) * KPAD + i) * 64 + d0) =
          cvtpk_bf16(r0 * qn0 - r1 * qn1, r1 * qn0 + r0 * qn1);
      // k
      unsigned int kw = *(const unsigned int*)(qkv + base + 1024);
      float k0 = b2f((unsigned short)kw);
      float k1 = b2f((unsigned short)(kw >> 16));
      float ks = k0 * k0 + k1 * k1;
#pragma unroll
      for (int o = 1; o < 32; o <<= 1) ks += __shfl_xor(ks, o);
      float rkn = 1.0f / fmaxf(sqrtf(ks), 1e-12f);
      float kn0 = k0 * rkn, kn1 = k1 * rkn;
      *(unsigned int*)(ko + ((size_t)(b * NHQ + h) * KPAD + i) * 64 + d0) =
          cvtpk_bf16(r0 * kn0 - r1 * kn1, r1 * kn0 + r0 * kn1);
      // v
      unsigned int vw = *(const unsigned int*)(qkv + base + 2048);
      v0 = b2f((unsigned short)vw) + vb2.x;
      v1 = b2f((unsigned short)(vw >> 16)) + vb2.y;
    }
    vtile[d0 * 68 + il] = f2b(v0);
    vtile[(d0 + 1) * 68 + il] = f2b(v1);
  }
  __syncthreads();
  int row = tid >> 2, c0 = (tid & 3) * 16;
  s16x8 o0, o1;
#pragma unroll
  for (int jj = 0; jj < 8; ++jj) {
    o0[jj] = (short)vtile[row * 68 + c0 + jj];
    o1[jj] = (short)vtile[row * 68 + c0 + 8 + jj];
  }
  size_t doff = ((size_t)((b * NHQ + h) * 64 + row)) * KPAD + (size_t)tile * 64 + c0;
  *(s16x8*)(vt + doff) = o0;
  *(s16x8*)(vt + doff + 8) = o1;
}

// ---------------- flash attention ----------------
// 1D grid + XCD-chunk swizzle (each XCD chunk = 12 complete bh-groups -> K/V
// panels L2-resident). z=3 tiles 9/9/8. Loop body = proven R4 structure.
__global__ __launch_bounds__(256, 4) void k_attn(const unsigned short* __restrict__ qb,
                                                 const unsigned short* __restrict__ kb,
                                                 const unsigned short* __restrict__ vtb,
                                                 const float* __restrict__ sml,
                                                 unsigned short* __restrict__ pO,
                                                 float* __restrict__ pl) {
  int bid = blockIdx.x;                     // 1248 = 13*32*3
  int swz = (bid & 7) * 156 + (bid >> 3);   // XCD-contiguous chunks
  int part = swz / 416;                     // 416 = 13*32
  int rem = swz - part * 416;
  int bh = rem / 13;
  int qt = rem - bh * 13;
  int b = bh >> 4, h = bh & 15;
  int t0 = part * 9;
  int t1 = (part == 2) ? 26 : t0 + 9;
  int q0 = qt * 128;
  int tid = threadIdx.x, w = tid >> 6, lane = tid & 63, quad = lane >> 4, l15 = lane & 15;
  float M = __expf(fminf(sml[h], 4.6051702f)) * 1.4426950408889634f;  // log2-domain shift
  __shared__ __align__(16) unsigned short Kt[64 * 72];     //  9216 B
  __shared__ __align__(16) unsigned short Vt[64 * 72];     //  9216 B
  __shared__ __align__(16) unsigned short Pq[4][32 * 72];  // 18432 B (total 36864 -> 4 blk/CU)
  unsigned short* Pw = Pq[w];
  const unsigned short* qbase = qb + (size_t)(b * NHQ + h) * KPAD * 64;
  const unsigned short* kbase = kb + (size_t)(b * NHQ + h) * KPAD * 64;
  const unsigned short* vbase = vtb + (size_t)(b * NHQ + h) * 64 * KPAD;

  // staging geometry: 512 s16x8 chunks per K (and V) tile, 2 per thread
  int r0 = tid >> 3, c0 = tid & 7;            // chunk 0: rows 0..31
  int r1 = 32 + r0, c1 = c0;                  // chunk 1: rows 32..63

  // Q as B-operand: n=l15 -> q row; k = kb2*32 + quad*8
  s16x8 qf[2][2];
#pragma unroll
  for (int qtile = 0; qtile < 2; ++qtile)
#pragma unroll
    for (int kb2 = 0; kb2 < 2; ++kb2) {
      int row = q0 + w * 32 + qtile * 16 + l15;
      qf[qtile][kb2] = *(const s16x8*)(qbase + (size_t)row * 64 + kb2 * 32 + quad * 8);
    }

  float lsum[2] = {0.f, 0.f};
  fx4 oacc[2][4];
#pragma unroll
  for (int qtile = 0; qtile < 2; ++qtile)
#pragma unroll
    for (int dt = 0; dt < 4; ++dt) oacc[qtile][dt] = (fx4){0.f, 0.f, 0.f, 0.f};

  // prologue: issue tile t0's loads (T14 async-STAGE split)
  s16x8 kn0, kn1, vn0, vn1;
  {
    int j0 = t0 * 64;
    kn0 = *(const s16x8*)(kbase + (size_t)(j0 + r0) * 64 + c0 * 8);
    kn1 = *(const s16x8*)(kbase + (size_t)(j0 + r1) * 64 + c1 * 8);
    vn0 = *(const s16x8*)(vbase + (size_t)r0 * KPAD + j0 + c0 * 8);
    vn1 = *(const s16x8*)(vbase + (size_t)r1 * KPAD + j0 + c1 * 8);
  }

  for (int t = t0; t < t1; ++t) {
    int j0 = t * 64;
    bool tail = (j0 + 64 > KSEL);
    __builtin_amdgcn_s_barrier();    // all waves done reading prev Kt/Vt
    *(s16x8*)(Kt + r0 * 72 + c0 * 8) = kn0;
    *(s16x8*)(Kt + r1 * 72 + c1 * 8) = kn1;
    *(s16x8*)(Vt + r0 * 72 + c0 * 8) = vn0;
    *(s16x8*)(Vt + r1 * 72 + c1 * 8) = vn1;
    // issue next tile's loads; they stay in flight under this tile's compute
    if (t + 1 < t1) {
      int jn = (t + 1) * 64;
      kn0 = *(const s16x8*)(kbase + (size_t)(jn + r0) * 64 + c0 * 8);
      kn1 = *(const s16x8*)(kbase + (size_t)(jn + r1) * 64 + c1 * 8);
      vn0 = *(const s16x8*)(vbase + (size_t)r0 * KPAD + jn + c0 * 8);
      vn1 = *(const s16x8*)(vbase + (size_t)r1 * KPAD + jn + c1 * 8);
    }
    asm volatile("s_waitcnt lgkmcnt(0)" ::: "memory");   // ds_writes visible
    __builtin_amdgcn_s_barrier();

    // S^T -> exp2 -> wave-private P -> PV
    fx4 sacc[2][4];
#pragma unroll
    for (int qtile = 0; qtile < 2; ++qtile)
#pragma unroll
      for (int jj = 0; jj < 4; ++jj) sacc[qtile][jj] = (fx4){0.f, 0.f, 0.f, 0.f};
    __builtin_amdgcn_s_setprio(1);
#pragma unroll
    for (int jj = 0; jj < 4; ++jj) {
      int jl = jj * 16 + l15;
      s16x8 kf0 = *(const s16x8*)(Kt + jl * 72 + quad * 8);
      s16x8 kf1 = *(const s16x8*)(Kt + jl * 72 + 32 + quad * 8);
      sacc[0][jj] = MFMA16(kf0, qf[0][0], sacc[0][jj]);
      sacc[1][jj] = MFMA16(kf0, qf[1][0], sacc[1][jj]);
      sacc[0][jj] = MFMA16(kf1, qf[0][1], sacc[0][jj]);
      sacc[1][jj] = MFMA16(kf1, qf[1][1], sacc[1][jj]);
    }
    __builtin_amdgcn_s_setprio(0);
#pragma unroll
    for (int qtile = 0; qtile < 2; ++qtile)
#pragma unroll
      for (int jj = 0; jj < 4; ++jj) {
        int jbase = j0 + jj * 16 + quad * 4;
        fx4 sv = sacc[qtile][jj];
        float p0 = fexp2(sv[0] - M);
        float p1 = fexp2(sv[1] - M);
        float p2 = fexp2(sv[2] - M);
        float p3 = fexp2(sv[3] - M);
        if (tail) {
          if (jbase + 0 >= KSEL) p0 = 0.f;
          if (jbase + 1 >= KSEL) p1 = 0.f;
          if (jbase + 2 >= KSEL) p2 = 0.f;
          if (jbase + 3 >= KSEL) p3 = 0.f;
        }
        lsum[qtile] += (p0 + p1) + (p2 + p3);
        *(uint2*)(Pw + (qtile * 16 + l15) * 72 + jj * 16 + quad * 4) =
            make_uint2(cvtpk_bf16(p0, p1), cvtpk_bf16(p2, p3));
      }
    // PV: A=P (wave-private LDS), B=V (LDS)
    __builtin_amdgcn_s_setprio(1);
#pragma unroll
    for (int js = 0; js < 2; ++js) {
      s16x8 pf0 = *(const s16x8*)(Pw + l15 * 72 + js * 32 + quad * 8);
      s16x8 pf1 = *(const s16x8*)(Pw + (16 + l15) * 72 + js * 32 + quad * 8);
#pragma unroll
      for (int dt = 0; dt < 4; ++dt) {
        s16x8 vf = *(const s16x8*)(Vt + (dt * 16 + l15) * 72 + js * 32 + quad * 8);
        oacc[0][dt] = MFMA16(pf0, vf, oacc[0][dt]);
        oacc[1][dt] = MFMA16(pf1, vf, oacc[1][dt]);
      }
    }
    __builtin_amdgcn_s_setprio(0);
  }

  // combine quad-partitioned j-sums (lanes l15, +16, +32, +48 hold disjoint j sets)
#pragma unroll
  for (int qtile = 0; qtile < 2; ++qtile) {
    float s = lsum[qtile];
    s += __shfl_xor(s, 16);
    s += __shfl_xor(s, 32);
    lsum[qtile] = s;
  }

  size_t pbase = (((size_t)part * 2 + b) * NHQ + h) * KPAD;
#pragma unroll
  for (int qtile = 0; qtile < 2; ++qtile) {
    int gqb = q0 + w * 32 + qtile * 16;
    if (quad == 0) pl[pbase + gqb + l15] = lsum[qtile];
  }

  // transpose O through the (now free) wave-private P buffer -> coalesced stores
#pragma unroll
  for (int qtile = 0; qtile < 2; ++qtile)
#pragma unroll
    for (int dt = 0; dt < 4; ++dt)
#pragma unroll
      for (int r = 0; r < 4; ++r)
        Pw[(qtile * 16 + quad * 4 + r) * 72 + dt * 16 + l15] = f2b(oacc[qtile][dt][r]);
#pragma unroll
  for (int pass = 0; pass < 4; ++pass) {
    int row = pass * 8 + (lane >> 3), chunk = lane & 7;
    s16x8 vv = *(const s16x8*)(Pw + row * 72 + chunk * 8);
    *(s16x8*)(pO + (pbase + q0 + w * 32 + row) * 64 + chunk * 8) = vv;
  }
}

// ---------------- combine the three j-parts (vectorized x8): o = sum(O_p)/sum(l_p) ---------
__global__ __launch_bounds__(256) void k_comb(const unsigned short* __restrict__ pO,
                                              const float* __restrict__ pl,
                                              unsigned short* __restrict__ ob) {
  size_t g8 = (size_t)blockIdx.x * 256 + threadIdx.x;  // 425984 = 3407872/8
  size_t base = g8 * 8;
  int d0 = (int)(base & 63);
  size_t row = base >> 6;           // (b*16+h)*1664 + gq
  int gq = (int)(row % KPAD);
  int bhh = (int)(row / KPAD);
  int b = bhh >> 4, h = bhh & 15;
  uint4 p0 = *(const uint4*)(pO + base);
  uint4 p1 = *(const uint4*)(pO + base + 3407872);
  uint4 p2 = *(const uint4*)(pO + base + 2 * 3407872);
  float ls = pl[row] + pl[row + 53248] + pl[row + 2 * 53248];
  float rc = 1.0f / ls;
  unsigned int pw0[4] = {p0.x, p0.y, p0.z, p0.w};
  unsigned int pw1[4] = {p1.x, p1.y, p1.z, p1.w};
  unsigned int pw2[4] = {p2.x, p2.y, p2.z, p2.w};
  unsigned int ow[4];
#pragma unroll
  for (int j = 0; j < 4; ++j) {
    float lo = (b2f((unsigned short)pw0[j]) + b2f((unsigned short)pw1[j]) +
                b2f((unsigned short)pw2[j])) * rc;
    float hi = (b2f((unsigned short)(pw0[j] >> 16)) + b2f((unsigned short)(pw1[j] >> 16)) +
                b2f((unsigned short)(pw2[j] >> 16))) * rc;
    ow[j] = cvtpk_bf16(lo, hi);
  }
  *(uint4*)(ob + ((size_t)(b * KPAD + gq)) * CQ + h * 64 + d0) =
      make_uint4(ow[0], ow[1], ow[2], ow[3]);
}

extern "C" void kernel_launch(void* const* d_in, const int* in_sizes, int n_in,
                              void* d_out, int out_size, void* d_ws, size_t ws_size,
                              hipStream_t stream) {
  const float* x      = (const float*)d_in[0];
  const float* cached = (const float*)d_in[1];
  const float* wqkv   = (const float*)d_in[2];
  const float* qbias  = (const float*)d_in[3];
  const float* vbias  = (const float*)d_in[4];
  const float* wproj  = (const float*)d_in[5];
  const float* bproj  = (const float*)d_in[6];
  const float* sml    = (const float*)d_in[7];
  const float* rope   = (const float*)d_in[8];
  float* out = (float*)d_out;
  char* ws = (char*)d_ws;

  double* meanpart        = (double*)(ws);                    // 524288
  double* mean            = (double*)(ws + 524288);           // 16384
  double* mse             = (double*)(ws + 540672);           // 65536
  int* idx_sel            = (int*)(ws + 606208);              // 13312 -> 619520
  // overlap zone [619520, 44135424): x_bf + wqkv_bf + qkv (dead after k_normrope)
  unsigned short* x_bf    = (unsigned short*)(ws + 619520);   // 16777216
  unsigned short* wqkv_bf = (unsigned short*)(ws + 17396736); // 6291456
  unsigned short* qkv     = (unsigned short*)(ws + 23688192); // 20447232 -> 44135424
  // attn partials (3 parts) reuse the dead x_bf/wqkv_bf/qkv region
  unsigned short* pO      = (unsigned short*)(ws + 619520);   // 20447232
  float* pl               = (float*)(ws + 21066752);          // 638976 -> 21705728
  unsigned short* wproj_bf= (unsigned short*)(ws + 44135424); // 2097152
  unsigned short* qo      = (unsigned short*)(ws + 46232576); // 6815744
  unsigned short* ko      = (unsigned short*)(ws + 53048320); // 6815744
  unsigned short* vt      = (unsigned short*)(ws + 59864064); // 6815744
  unsigned short* ob      = (unsigned short*)(ws + 66679808); // 6815744 -> 73495552

  hipLaunchKernelGGL(k_mean_part, dim3(256), dim3(256), 0, stream, x, meanpart);
  hipLaunchKernelGGL(k_mean_reduce, dim3(8), dim3(256), 0, stream, meanpart, mean);
  hipLaunchKernelGGL(k_mse_base, dim3(8192), dim3(256), 0, stream, x, cached, mean, mse,
                     out, x_bf);
  hipLaunchKernelGGL(k_topk, dim3(2 + 1024), dim3(1024), 0, stream, mse, idx_sel,
                     wqkv, wproj, wqkv_bf, wproj_bf);
  hipLaunchKernelGGL(k_gemmA, dim3(52 * 24), dim3(256), 0, stream,
                     x_bf, wqkv_bf, idx_sel, qkv);
  hipLaunchKernelGGL(k_normrope, dim3(26 * 16 * BQ), dim3(256), 0, stream,
                     qkv, idx_sel, qbias, vbias, sml, rope, qo, ko, vt);
  hipLaunchKernelGGL(k_attn, dim3(1248), dim3(256), 0, stream,
                     qo, ko, vt, sml, pO, pl);
  hipLaunchKernelGGL(k_comb, dim3(1664), dim3(256), 0, stream, pO, pl, ob);
  hipLaunchKernelGGL(k_gemmB, dim3(832), dim3(256), 0, stream,
                     ob, wproj_bf, idx_sel, out, x, bproj);
}

// Round 14
// 260.026 us; speedup vs baseline: 1.1167x; 1.0194x over previous
//
#include <hip/hip_runtime.h>
#include <hip/hip_bf16.h>
#include <math.h>

// Problem constants (setup_inputs)
#define BQ   2
#define LQ   4096
#define CQ   1024
#define NHQ  16
#define DHQ  64
#define KSEL 1638
#define KPAD 1664
#define MTOT (BQ*KSEL)   // 3276
#define MPAD 3328        // 26*128

typedef short s16x8 __attribute__((ext_vector_type(8)));
typedef float fx4   __attribute__((ext_vector_type(4)));

#define MFMA16(a,b,c) __builtin_amdgcn_mfma_f32_16x16x32_bf16(a,b,c,0,0,0)

__device__ __forceinline__ float b2f(unsigned short u) {
  union { float f; unsigned int i; } cv; cv.i = ((unsigned int)u) << 16; return cv.f;
}
__device__ __forceinline__ unsigned short f2b(float f) {
  union { float f; unsigned int i; } cv; cv.f = f;
  unsigned int x = cv.i;
  return (unsigned short)((x + 0x7fffu + ((x >> 16) & 1u)) >> 16);
}
__device__ __forceinline__ unsigned int fbits(float f) {
  union { float f; unsigned int i; } cv; cv.f = f; return cv.i;
}
// packed f32x2 -> bf16x2 (RNE), single VALU op
__device__ __forceinline__ unsigned int cvtpk_bf16(float a, float b) {
  unsigned int r;
  asm("v_cvt_pk_bf16_f32 %0, %1, %2" : "=v"(r) : "v"(a), "v"(b));
  return r;
}
__device__ __forceinline__ void async16(const void* g, void* l) {
  __builtin_amdgcn_global_load_lds((const __attribute__((address_space(1))) void*)g,
                                   (__attribute__((address_space(3))) void*)l, 16, 0, 0);
}
// raw 2^x (q is pre-scaled by log2(e) in k_normrope, M is in log2 units)
__device__ __forceinline__ float fexp2(float x) {
#if __has_builtin(__builtin_amdgcn_exp2f)
  return __builtin_amdgcn_exp2f(x);
#else
  return __expf(x * 0.69314718055994531f);
#endif
}

// ---------------- mean (fp64, 2-stage) ----------------
__global__ __launch_bounds__(256) void k_mean_part(const float* __restrict__ x,
                                                   double* __restrict__ part) {
  int bid = blockIdx.x;                    // 256 blocks: [b(2)][ch(32)][cb(4)]
  int cb = bid & 3, ch = (bid >> 2) & 31, b = bid >> 7;
  int c = cb * 256 + threadIdx.x;
  const float* p = x + ((size_t)b * LQ + (size_t)ch * 128) * CQ + c;
  double s = 0.0;
  for (int r = 0; r < 128; ++r) s += (double)p[(size_t)r * CQ];
  part[((size_t)b * 32 + ch) * CQ + c] = s;
}

__global__ __launch_bounds__(256) void k_mean_reduce(const double* __restrict__ part,
                                                     double* __restrict__ mean) {
  int g = blockIdx.x * 256 + threadIdx.x;  // 2048 = B*C
  int b = g >> 10, c = g & 1023;
  double s = 0.0;
  for (int ch = 0; ch < 32; ++ch) s += part[((size_t)b * 32 + ch) * CQ + c];
  mean[g] = s * (1.0 / 4096.0);
}

// ---------------- mse (fp64) + base output (x + upsample(cached)) + x->bf16 ----------------
__global__ __launch_bounds__(256) void k_mse_base(const float* __restrict__ x,
                                                  const float* __restrict__ cached,
                                                  const double* __restrict__ mean,
                                                  double* __restrict__ mse,
                                                  float* __restrict__ out,
                                                  unsigned short* __restrict__ xb) {
  int bl = blockIdx.x; int b = bl >> 12, l = bl & 4095;
  int hh = l >> 6, ww = l & 63;
  size_t xoff = ((size_t)b * LQ + l) * CQ;
  size_t uoff = (((size_t)b * 32 + (hh >> 1)) * 32 + (ww >> 1)) * CQ;
  const double* mrow = mean + (size_t)b * CQ;
  int c0 = threadIdx.x * 4;
  float4 xv = *(const float4*)(x + xoff + c0);
  float4 uv = *(const float4*)(cached + uoff + c0);
  float4 ov;
  ov.x = xv.x + uv.x; ov.y = xv.y + uv.y; ov.z = xv.z + uv.z; ov.w = xv.w + uv.w;
  *(float4*)(out + xoff + c0) = ov;
  ushort4 xo;
  xo.x = f2b(xv.x); xo.y = f2b(xv.y); xo.z = f2b(xv.z); xo.w = f2b(xv.w);
  ((ushort4*)xb)[(xoff + c0) >> 2] = xo;
  double d0 = (double)xv.x - mrow[c0];
  double d1 = (double)xv.y - mrow[c0 + 1];
  double d2 = (double)xv.z - mrow[c0 + 2];
  double d3 = (double)xv.w - mrow[c0 + 3];
  double ss = d0 * d0 + d1 * d1 + d2 * d2 + d3 * d3;
  for (int o = 1; o < 64; o <<= 1) ss += __shfl_xor(ss, o);
  __shared__ double ws4[4];
  if ((threadIdx.x & 63) == 0) ws4[threadIdx.x >> 6] = ss;
  __syncthreads();
  if (threadIdx.x == 0) mse[(size_t)b * LQ + l] = ws4[0] + ws4[1] + ws4[2] + ws4[3];
}

// ---------------- top-k (blocks 0,1) + fused weight fp32->bf16 conversion (blocks >=2) ----
// 4-pass radix over the HIGH 32 BITS (mse >= 0); tie group resolved exactly.
__global__ __launch_bounds__(1024) void k_topk(const double* __restrict__ mse,
                                               int* __restrict__ idx_sel,
                                               const float* __restrict__ wqkv,
                                               const float* __restrict__ wproj,
                                               unsigned short* __restrict__ wqb,
                                               unsigned short* __restrict__ wpb) {
  if (blockIdx.x >= 2) {   // conversion path: 1024 blocks x 1024 thr x 1 float4
    int i = (blockIdx.x - 2) * 1024 + threadIdx.x;
    const float* s; unsigned short* d; int off;
    if (i < 786432) { s = wqkv;  d = wqb; off = i; }
    else            { s = wproj; d = wpb; off = i - 786432; }
    float4 v = ((const float4*)s)[off];
    ushort4 o;
    o.x = f2b(v.x); o.y = f2b(v.y); o.z = f2b(v.z); o.w = f2b(v.w);
    ((ushort4*)d)[off] = o;
    return;
  }
  __shared__ unsigned long long u[4096];       // 32 KB
  __shared__ unsigned int whist[16 * 257];     // 16.4 KB, stride 257 => cross-wave bank skew
  __shared__ unsigned int wtot[4];
  __shared__ unsigned long long sh_prefix;
  __shared__ int sh_rem, sh_rem2, sh_bsel, sh_cnt, sh_eqcnt;
  __shared__ int eqbuf[256];
  int b = blockIdx.x, t = threadIdx.x;
  int wv = t >> 6, laneid = t & 63;
  for (int p = 0; p < 4; ++p) {
    int i = p * 1024 + t;
    u[i] = (unsigned long long)__double_as_longlong(mse[(size_t)b * LQ + i]);
  }
  if (t == 0) { sh_prefix = 0ULL; sh_rem = KSEL; sh_cnt = 0; sh_eqcnt = 0; }
  __syncthreads();
  for (int shift = 56; shift >= 32; shift -= 8) {   // high 32 bits only
    for (int z = t; z < 16 * 257; z += 1024) whist[z] = 0u;
    __syncthreads();
    unsigned long long pref = sh_prefix;
#pragma unroll
    for (int p = 0; p < 4; ++p) {
      int i = p * 1024 + t;
      unsigned long long v = u[i];
      bool cand = (shift == 56) || ((v >> ((shift + 8) & 63)) == pref);
      if (cand) atomicAdd(&whist[wv * 257 + ((unsigned int)(v >> shift) & 255u)], 1u);
    }
    __syncthreads();
    unsigned int myc = 0, mysc = 0;
    if (t < 256) {            // combine the 16 wave hists for my bin (bin = 255 - t)
      unsigned int s = 0;
      int bin = 255 - t;
#pragma unroll
      for (int wvi = 0; wvi < 16; ++wvi) s += whist[wvi * 257 + bin];
      myc = s;
      mysc = myc;
#pragma unroll
      for (int o = 1; o < 64; o <<= 1) {
        unsigned int v2 = __shfl_up(mysc, o);
        if (laneid >= o) mysc += v2;
      }
      if (laneid == 63) wtot[wv] = mysc;
    }
    __syncthreads();
    if (t < 256) {
      unsigned int basep = 0;
      for (int wvi = 0; wvi < wv; ++wvi) basep += wtot[wvi];
      unsigned int incl = basep + mysc;       // count of keys in bins >= my bin
      unsigned int excl = incl - myc;         // count of keys in bins >  my bin
      unsigned int rem = (unsigned int)sh_rem;
      if (excl < rem && rem <= incl) {        // exactly one thread crosses
        sh_bsel = 255 - t;
        sh_rem2 = (int)(rem - excl);
      }
    }
    __syncthreads();
    if (t == 0) {
      sh_prefix = (sh_prefix << 8) | (unsigned long long)sh_bsel;
      sh_rem = sh_rem2;
    }
    __syncthreads();
  }
  unsigned long long T = sh_prefix;           // threshold on the high 32 bits
  int rem_eq = sh_rem;
#pragma unroll
  for (int p = 0; p < 4; ++p) {
    int i = p * 1024 + t;
    unsigned long long v = u[i];
    bool win = ((v >> 32) > T);
    unsigned long long mask = __ballot(win);
    int total = __popcll(mask);
    int base = 0;
    if (laneid == 0 && total > 0) base = atomicAdd(&sh_cnt, total);
    base = __shfl(base, 0);
    if (win) {
      int lpos = __popcll(mask & ((1ULL << laneid) - 1ULL));
      idx_sel[b * KPAD + base + lpos] = i;
    }
    if ((v >> 32) == T) {
      int e = atomicAdd(&sh_eqcnt, 1);
      if (e < 256) eqbuf[e] = i;
    }
  }
  __syncthreads();
  if (t == 0) {
    int n = sh_eqcnt; if (n > 256) n = 256;
    // sort eq group by (full value desc, index asc) -- exact double ordering
    for (int a = 1; a < n; ++a) {
      int key = eqbuf[a]; unsigned long long kv = u[key]; int c = a - 1;
      while (c >= 0 && (u[eqbuf[c]] < kv || (u[eqbuf[c]] == kv && eqbuf[c] > key))) {
        eqbuf[c + 1] = eqbuf[c]; --c;
      }
      eqbuf[c + 1] = key;
    }
    int base = sh_cnt;
    for (int a = 0; a < rem_eq && a < n; ++a) idx_sel[b * KPAD + base + a] = eqbuf[a];
    for (int a = KSEL; a < KPAD; ++a) idx_sel[b * KPAD + a] = 0;
  }
}

// ---------------- qkv GEMM (128x128, BK=32), 512 thr, single-barrier dbuf ----------------
// R20: fatter tile to cut aggregate staged L2 traffic (R13 post-mortem: gemmA is
// bound by machine-wide staging bandwidth, 490MB at ~11TB/s = 44us; per-load
// latency fixes were null). 128x128/512thr: 256 B staged per MFMA (was 384) ->
// ~320MB total. Same wave count (624x8 = 1248x4), same R12-proven single-barrier
// schedule. LDS 32KB -> 4 blk/CU cap (wave-limited), grid 2.44 blk/CU = 19.5 w/CU.
__global__ __launch_bounds__(512) void k_gemmA(const unsigned short* __restrict__ Asrc,
                                               const unsigned short* __restrict__ Bmat,
                                               const int* __restrict__ idx_sel,
                                               unsigned short* __restrict__ Cbf) {
  int bid = blockIdx.x;
  int swz = (bid & 7) * 78 + (bid >> 3);    // XCD-contiguous chunks (624 = 8*78)
  int bm = swz % 26, bn = swz / 26;
  int tid = threadIdx.x;
  int w = tid >> 6, lane = tid & 63, quad = lane >> 4, l15 = lane & 15;
  int wm = w & 1, wn = w >> 1;              // 2(M) x 4(N) waves, wave tile 64x32
  __shared__ __align__(16) unsigned char sm[2][16384];   // A [128][32] @0, B [128][32] @8192

  const unsigned short* gA;
  {
    int row = tid >> 2, kc = tid & 3;       // 512 thr cover 128 rows x 4 chunks
    int m = bm * 128 + row; if (m >= MTOT) m = MTOT - 1;
    int bb = m / KSEL; int ii = m - bb * KSEL;
    int lsel = idx_sel[bb * KPAD + ii];
    gA = Asrc + ((size_t)bb * LQ + lsel) * CQ + kc * 8;
  }
  const unsigned short* gB;
  {
    int row = tid >> 2, kc = tid & 3;
    gB = Bmat + (size_t)(bn * 128 + row) * CQ + kc * 8;
  }

  fx4 acc[4][2];
#pragma unroll
  for (int a = 0; a < 4; ++a)
#pragma unroll
    for (int c = 0; c < 2; ++c) acc[a][c] = (fx4){0.f, 0.f, 0.f, 0.f};

#define STAGE_A(buf, it) do { int ke = (it) * 32;                                   \
    async16(gA + ke, sm[buf] + tid * 16);                                           \
    async16(gB + ke, sm[buf] + 8192 + tid * 16); } while (0)

  STAGE_A(0, 0);
  for (int it = 0; it < 32; ++it) {
    int cur = it & 1;
    asm volatile("s_waitcnt vmcnt(0)");   // own stage-it loads landed
    __builtin_amdgcn_s_barrier();         // all waves: stage-it landed + it-1 reads done
    if (it < 31) STAGE_A(cur ^ 1, it + 1);
    const unsigned char* smb = sm[cur];
    s16x8 af[4], bf[2];
#pragma unroll
    for (int mt = 0; mt < 4; ++mt)
      af[mt] = *(const s16x8*)(smb + ((wm * 64 + mt * 16 + l15) * 32 + quad * 8) * 2);
#pragma unroll
    for (int nt = 0; nt < 2; ++nt)
      bf[nt] = *(const s16x8*)(smb + 8192 + ((wn * 32 + nt * 16 + l15) * 32 + quad * 8) * 2);
    __builtin_amdgcn_s_setprio(1);
#pragma unroll
    for (int mt = 0; mt < 4; ++mt)
#pragma unroll
      for (int nt = 0; nt < 2; ++nt)
        acc[mt][nt] = MFMA16(af[mt], bf[nt], acc[mt][nt]);
    __builtin_amdgcn_s_setprio(0);
  }
#undef STAGE_A

#pragma unroll
  for (int mt = 0; mt < 4; ++mt)
#pragma unroll
    for (int nt = 0; nt < 2; ++nt) {
      int n = bn * 128 + wn * 32 + nt * 16 + l15;
      int mbase = bm * 128 + wm * 64 + mt * 16 + quad * 4;
      fx4 vv = acc[mt][nt];
#pragma unroll
      for (int r = 0; r < 4; ++r) {
        int m = mbase + r;
        if (m < MTOT) Cbf[(size_t)m * 3072 + n] = f2b(vv[r]);
      }
    }
}

// ---------------- proj GEMM (64x64, BK=64) : 832 blocks, single-barrier dbuf ------------
__global__ __launch_bounds__(256) void k_gemmB(const unsigned short* __restrict__ Asrc,
                                               const unsigned short* __restrict__ Bmat,
                                               const int* __restrict__ idx_sel,
                                               float* __restrict__ Cf,
                                               const float* __restrict__ xin,
                                               const float* __restrict__ bproj) {
  int bid = blockIdx.x;
  int swz = (bid & 7) * 104 + (bid >> 3);   // XCD-contiguous chunks (832 = 8*104)
  int bm = swz % 52, bn = swz / 52;
  int tid = threadIdx.x;
  int w = tid >> 6, lane = tid & 63, quad = lane >> 4, l15 = lane & 15;
  int wm = w & 1, wn = w >> 1;
  __shared__ __align__(16) unsigned char sm[2][16384];   // A [64][64]bf16, B [64][64]bf16

  const unsigned short* g4[4];
#pragma unroll
  for (int p = 0; p < 4; ++p) {
    int e = (p & 1) * 256 + tid; int row = e >> 3, kc = e & 7;
    if (p < 2) {
      int m = bm * 64 + row; if (m >= MTOT) m = MTOT - 1;
      int bb = m / KSEL; int ii = m - bb * KSEL;
      g4[p] = Asrc + ((size_t)bb * KPAD + ii) * CQ + kc * 8;
    } else {
      g4[p] = Bmat + (size_t)(bn * 64 + row) * CQ + kc * 8;
    }
  }

  fx4 acc[2][2];
#pragma unroll
  for (int a = 0; a < 2; ++a)
#pragma unroll
    for (int c = 0; c < 2; ++c) acc[a][c] = (fx4){0.f, 0.f, 0.f, 0.f};

#define STAGE_B(buf, it) do { int ke = (it) * 64;                                   \
    _Pragma("unroll")                                                               \
    for (int p = 0; p < 4; ++p)                                                     \
      async16(g4[p] + ke, sm[buf] + p * 4096 + w * 1024);                           \
    } while (0)

  STAGE_B(0, 0);
  for (int it = 0; it < 16; ++it) {
    int cur = it & 1;
    asm volatile("s_waitcnt vmcnt(0)");
    __builtin_amdgcn_s_barrier();
    if (it < 15) STAGE_B(cur ^ 1, it + 1);
    const unsigned char* smb = sm[cur];
#pragma unroll
    for (int kk = 0; kk < 2; ++kk) {
      s16x8 af[2], bf2[2];
#pragma unroll
      for (int mt = 0; mt < 2; ++mt)
        af[mt] = *(const s16x8*)(smb + ((wm * 32 + mt * 16 + l15) * 64 + kk * 32 + quad * 8) * 2);
#pragma unroll
      for (int nt = 0; nt < 2; ++nt)
        bf2[nt] = *(const s16x8*)(smb + 8192 + ((wn * 32 + nt * 16 + l15) * 64 + kk * 32 + quad * 8) * 2);
      __builtin_amdgcn_s_setprio(1);
#pragma unroll
      for (int mt = 0; mt < 2; ++mt)
#pragma unroll
        for (int nt = 0; nt < 2; ++nt)
          acc[mt][nt] = MFMA16(af[mt], bf2[nt], acc[mt][nt]);
      __builtin_amdgcn_s_setprio(0);
    }
  }
#undef STAGE_B

#pragma unroll
  for (int mt = 0; mt < 2; ++mt)
#pragma unroll
    for (int nt = 0; nt < 2; ++nt) {
      int n = bn * 64 + wn * 32 + nt * 16 + l15;
      int mbase = bm * 64 + wm * 32 + mt * 16 + quad * 4;
      fx4 vv = acc[mt][nt];
      float bp = bproj[n];
#pragma unroll
      for (int r = 0; r < 4; ++r) {
        int m = mbase + r;
        if (m < MTOT) {
          int bb = m / KSEL; int ii = m - bb * KSEL;
          int lsel = idx_sel[bb * KPAD + ii];
          size_t off = ((size_t)bb * LQ + lsel) * CQ + n;
          Cf[off] = xin[off] + vv[r] + bp;
        }
      }
    }
}

// ---------------- l2norm + scale + rope -> q,k ; v -> Vt (transposed) ----------------
__global__ __launch_bounds__(256) void k_normrope(const unsigned short* __restrict__ qkv,
                                                  const int* __restrict__ idx_sel,
                                                  const float* __restrict__ qbias,
                                                  const float* __restrict__ vbias,
                                                  const float* __restrict__ sml,
                                                  const float* __restrict__ rope,
                                                  unsigned short* __restrict__ qo,
                                                  unsigned short* __restrict__ ko,
                                                  unsigned short* __restrict__ vt) {
  int bid = blockIdx.x;                       // 26*16*2
  int tile = bid % 26; int h = (bid / 26) & 15; int b = bid / (26 * 16);
  int tid = threadIdx.x; int w = tid >> 6; int lane = tid & 63;
  int tk = lane >> 5, dl = lane & 31;         // token-half, d-pair index
  int d0 = dl * 2;
  __shared__ unsigned short vtile[64 * 68];
  float scale = expf(fminf(sml[h], 4.6051702f)) * 1.4426950408889634f;
  float2 qb2 = *(const float2*)(qbias + h * 64 + d0);
  float2 vb2 = *(const float2*)(vbias + h * 64 + d0);
  for (int pass = 0; pass < 8; ++pass) {
    int il = pass * 8 + w * 2 + tk;
    int i = tile * 64 + il;
    float v0 = 0.f, v1 = 0.f;
    if (i < KSEL) {
      int lsel = idx_sel[b * KPAD + i];
      size_t base = ((size_t)(b * KSEL + i)) * 3072 + h * 64 + d0;
      float r0 = rope[(size_t)lsel * 32 + dl];
      float r1 = rope[(size_t)LQ * 32 + (size_t)lsel * 32 + dl];
      // q
      unsigned int qw = *(const unsigned int*)(qkv + base);
      float q0 = b2f((unsigned short)qw) + qb2.x;
      float q1 = b2f((unsigned short)(qw >> 16)) + qb2.y;
      float ss = q0 * q0 + q1 * q1;
#pragma unroll
      for (int o = 1; o < 32; o <<= 1) ss += __shfl_xor(ss, o);
      float rn = scale / fmaxf(sqrtf(ss), 1e-12f);
      float qn0 = q0 * rn, qn1 = q1 * rn;
      *(unsigned int*)(qo + ((size_t)(b * NHQ + h) * KPAD + i) * 64 + d0) =
          cvtpk_bf16(r0 * qn0 - r1 * qn1, r1 * qn0 + r0 * qn1);
      // k
      unsigned int kw = *(const unsigned int*)(qkv + base + 1024);
      float k0 = b2f((unsigned short)kw);
      float k1 = b2f((unsigned short)(kw >> 16));
      float ks = k0 * k0 + k1 * k1;
#pragma unroll
      for (int o = 1; o < 32; o <<= 1) ks += __shfl_xor(ks, o);
      float rkn = 1.0f / fmaxf(sqrtf(ks), 1e-12f);
      float kn0 = k0 * rkn, kn1 = k1 * rkn;
      *(unsigned int*)(ko + ((size_t)(b * NHQ + h) * KPAD + i) * 64 + d0) =
          cvtpk_bf16(r0 * kn0 - r1 * kn1, r1 * kn0 + r0 * kn1);
      // v
      unsigned int vw = *(const unsigned int*)(qkv + base + 2048);
      v0 = b2f((unsigned short)vw) + vb2.x;
      v1 = b2f((unsigned short)(vw >> 16)) + vb2.y;
    }
    vtile[d0 * 68 + il] = f2b(v0);
    vtile[(d0 + 1) * 68 + il] = f2b(v1);
  }
  __syncthreads();
  int row = tid >> 2, c0 = (tid & 3) * 16;
  s16x8 o0, o1;
#pragma unroll
  for (int jj = 0; jj < 8; ++jj) {
    o0[jj] = (short)vtile[row * 68 + c0 + jj];
    o1[jj] = (short)vtile[row * 68 + c0 + 8 + jj];
  }
  size_t doff = ((size_t)((b * NHQ + h) * 64 + row)) * KPAD + (size_t)tile * 64 + c0;
  *(s16x8*)(vt + doff) = o0;
  *(s16x8*)(vt + doff + 8) = o1;
}

// ---------------- flash attention ----------------
// 1D grid + XCD-chunk swizzle (each XCD chunk = 12 complete bh-groups -> K/V
// panels L2-resident). z=3 tiles 9/9/8. Loop body = proven R4 structure.
__global__ __launch_bounds__(256, 4) void k_attn(const unsigned short* __restrict__ qb,
                                                 const unsigned short* __restrict__ kb,
                                                 const unsigned short* __restrict__ vtb,
                                                 const float* __restrict__ sml,
                                                 unsigned short* __restrict__ pO,
                                                 float* __restrict__ pl) {
  int bid = blockIdx.x;                     // 1248 = 13*32*3
  int swz = (bid & 7) * 156 + (bid >> 3);   // XCD-contiguous chunks
  int part = swz / 416;                     // 416 = 13*32
  int rem = swz - part * 416;
  int bh = rem / 13;
  int qt = rem - bh * 13;
  int b = bh >> 4, h = bh & 15;
  int t0 = part * 9;
  int t1 = (part == 2) ? 26 : t0 + 9;
  int q0 = qt * 128;
  int tid = threadIdx.x, w = tid >> 6, lane = tid & 63, quad = lane >> 4, l15 = lane & 15;
  float M = __expf(fminf(sml[h], 4.6051702f)) * 1.4426950408889634f;  // log2-domain shift
  __shared__ __align__(16) unsigned short Kt[64 * 72];     //  9216 B
  __shared__ __align__(16) unsigned short Vt[64 * 72];     //  9216 B
  __shared__ __align__(16) unsigned short Pq[4][32 * 72];  // 18432 B (total 36864 -> 4 blk/CU)
  unsigned short* Pw = Pq[w];
  const unsigned short* qbase = qb + (size_t)(b * NHQ + h) * KPAD * 64;
  const unsigned short* kbase = kb + (size_t)(b * NHQ + h) * KPAD * 64;
  const unsigned short* vbase = vtb + (size_t)(b * NHQ + h) * 64 * KPAD;

  // staging geometry: 512 s16x8 chunks per K (and V) tile, 2 per thread
  int r0 = tid >> 3, c0 = tid & 7;            // chunk 0: rows 0..31
  int r1 = 32 + r0, c1 = c0;                  // chunk 1: rows 32..63

  // Q as B-operand: n=l15 -> q row; k = kb2*32 + quad*8
  s16x8 qf[2][2];
#pragma unroll
  for (int qtile = 0; qtile < 2; ++qtile)
#pragma unroll
    for (int kb2 = 0; kb2 < 2; ++kb2) {
      int row = q0 + w * 32 + qtile * 16 + l15;
      qf[qtile][kb2] = *(const s16x8*)(qbase + (size_t)row * 64 + kb2 * 32 + quad * 8);
    }

  float lsum[2] = {0.f, 0.f};
  fx4 oacc[2][4];
#pragma unroll
  for (int qtile = 0; qtile < 2; ++qtile)
#pragma unroll
    for (int dt = 0; dt < 4; ++dt) oacc[qtile][dt] = (fx4){0.f, 0.f, 0.f, 0.f};

  // prologue: issue tile t0's loads (T14 async-STAGE split)
  s16x8 kn0, kn1, vn0, vn1;
  {
    int j0 = t0 * 64;
    kn0 = *(const s16x8*)(kbase + (size_t)(j0 + r0) * 64 + c0 * 8);
    kn1 = *(const s16x8*)(kbase + (size_t)(j0 + r1) * 64 + c1 * 8);
    vn0 = *(const s16x8*)(vbase + (size_t)r0 * KPAD + j0 + c0 * 8);
    vn1 = *(const s16x8*)(vbase + (size_t)r1 * KPAD + j0 + c1 * 8);
  }

  for (int t = t0; t < t1; ++t) {
    int j0 = t * 64;
    bool tail = (j0 + 64 > KSEL);
    __builtin_amdgcn_s_barrier();    // all waves done reading prev Kt/Vt
    *(s16x8*)(Kt + r0 * 72 + c0 * 8) = kn0;
    *(s16x8*)(Kt + r1 * 72 + c1 * 8) = kn1;
    *(s16x8*)(Vt + r0 * 72 + c0 * 8) = vn0;
    *(s16x8*)(Vt + r1 * 72 + c1 * 8) = vn1;
    // issue next tile's loads; they stay in flight under this tile's compute
    if (t + 1 < t1) {
      int jn = (t + 1) * 64;
      kn0 = *(const s16x8*)(kbase + (size_t)(jn + r0) * 64 + c0 * 8);
      kn1 = *(const s16x8*)(kbase + (size_t)(jn + r1) * 64 + c1 * 8);
      vn0 = *(const s16x8*)(vbase + (size_t)r0 * KPAD + jn + c0 * 8);
      vn1 = *(const s16x8*)(vbase + (size_t)r1 * KPAD + jn + c1 * 8);
    }
    asm volatile("s_waitcnt lgkmcnt(0)" ::: "memory");   // ds_writes visible
    __builtin_amdgcn_s_barrier();

    // S^T -> exp2 -> wave-private P -> PV
    fx4 sacc[2][4];
#pragma unroll
    for (int qtile = 0; qtile < 2; ++qtile)
#pragma unroll
      for (int jj = 0; jj < 4; ++jj) sacc[qtile][jj] = (fx4){0.f, 0.f, 0.f, 0.f};
    __builtin_amdgcn_s_setprio(1);
#pragma unroll
    for (int jj = 0; jj < 4; ++jj) {
      int jl = jj * 16 + l15;
      s16x8 kf0 = *(const s16x8*)(Kt + jl * 72 + quad * 8);
      s16x8 kf1 = *(const s16x8*)(Kt + jl * 72 + 32 + quad * 8);
      sacc[0][jj] = MFMA16(kf0, qf[0][0], sacc[0][jj]);
      sacc[1][jj] = MFMA16(kf0, qf[1][0], sacc[1][jj]);
      sacc[0][jj] = MFMA16(kf1, qf[0][1], sacc[0][jj]);
      sacc[1][jj] = MFMA16(kf1, qf[1][1], sacc[1][jj]);
    }
    __builtin_amdgcn_s_setprio(0);
#pragma unroll
    for (int qtile = 0; qtile < 2; ++qtile)
#pragma unroll
      for (int jj = 0; jj < 4; ++jj) {
        int jbase = j0 + jj * 16 + quad * 4;
        fx4 sv = sacc[qtile][jj];
        float p0 = fexp2(sv[0] - M);
        float p1 = fexp2(sv[1] - M);
        float p2 = fexp2(sv[2] - M);
        float p3 = fexp2(sv[3] - M);
        if (tail) {
          if (jbase + 0 >= KSEL) p0 = 0.f;
          if (jbase + 1 >= KSEL) p1 = 0.f;
          if (jbase + 2 >= KSEL) p2 = 0.f;
          if (jbase + 3 >= KSEL) p3 = 0.f;
        }
        lsum[qtile] += (p0 + p1) + (p2 + p3);
        *(uint2*)(Pw + (qtile * 16 + l15) * 72 + jj * 16 + quad * 4) =
            make_uint2(cvtpk_bf16(p0, p1), cvtpk_bf16(p2, p3));
      }
    // PV: A=P (wave-private LDS), B=V (LDS)
    __builtin_amdgcn_s_setprio(1);
#pragma unroll
    for (int js = 0; js < 2; ++js) {
      s16x8 pf0 = *(const s16x8*)(Pw + l15 * 72 + js * 32 + quad * 8);
      s16x8 pf1 = *(const s16x8*)(Pw + (16 + l15) * 72 + js * 32 + quad * 8);
#pragma unroll
      for (int dt = 0; dt < 4; ++dt) {
        s16x8 vf = *(const s16x8*)(Vt + (dt * 16 + l15) * 72 + js * 32 + quad * 8);
        oacc[0][dt] = MFMA16(pf0, vf, oacc[0][dt]);
        oacc[1][dt] = MFMA16(pf1, vf, oacc[1][dt]);
      }
    }
    __builtin_amdgcn_s_setprio(0);
  }

  // combine quad-partitioned j-sums (lanes l15, +16, +32, +48 hold disjoint j sets)
#pragma unroll
  for (int qtile = 0; qtile < 2; ++qtile) {
    float s = lsum[qtile];
    s += __shfl_xor(s, 16);
    s += __shfl_xor(s, 32);
    lsum[qtile] = s;
  }

  size_t pbase = (((size_t)part * 2 + b) * NHQ + h) * KPAD;
#pragma unroll
  for (int qtile = 0; qtile < 2; ++qtile) {
    int gqb = q0 + w * 32 + qtile * 16;
    if (quad == 0) pl[pbase + gqb + l15] = lsum[qtile];
  }

  // transpose O through the (now free) wave-private P buffer -> coalesced stores
#pragma unroll
  for (int qtile = 0; qtile < 2; ++qtile)
#pragma unroll
    for (int dt = 0; dt < 4; ++dt)
#pragma unroll
      for (int r = 0; r < 4; ++r)
        Pw[(qtile * 16 + quad * 4 + r) * 72 + dt * 16 + l15] = f2b(oacc[qtile][dt][r]);
#pragma unroll
  for (int pass = 0; pass < 4; ++pass) {
    int row = pass * 8 + (lane >> 3), chunk = lane & 7;
    s16x8 vv = *(const s16x8*)(Pw + row * 72 + chunk * 8);
    *(s16x8*)(pO + (pbase + q0 + w * 32 + row) * 64 + chunk * 8) = vv;
  }
}

// ---------------- combine the three j-parts (vectorized x8): o = sum(O_p)/sum(l_p) ---------
__global__ __launch_bounds__(256) void k_comb(const unsigned short* __restrict__ pO,
                                              const float* __restrict__ pl,
                                              unsigned short* __restrict__ ob) {
  size_t g8 = (size_t)blockIdx.x * 256 + threadIdx.x;  // 425984 = 3407872/8
  size_t base = g8 * 8;
  int d0 = (int)(base & 63);
  size_t row = base >> 6;           // (b*16+h)*1664 + gq
  int gq = (int)(row % KPAD);
  int bhh = (int)(row / KPAD);
  int b = bhh >> 4, h = bhh & 15;
  uint4 p0 = *(const uint4*)(pO + base);
  uint4 p1 = *(const uint4*)(pO + base + 3407872);
  uint4 p2 = *(const uint4*)(pO + base + 2 * 3407872);
  float ls = pl[row] + pl[row + 53248] + pl[row + 2 * 53248];
  float rc = 1.0f / ls;
  unsigned int pw0[4] = {p0.x, p0.y, p0.z, p0.w};
  unsigned int pw1[4] = {p1.x, p1.y, p1.z, p1.w};
  unsigned int pw2[4] = {p2.x, p2.y, p2.z, p2.w};
  unsigned int ow[4];
#pragma unroll
  for (int j = 0; j < 4; ++j) {
    float lo = (b2f((unsigned short)pw0[j]) + b2f((unsigned short)pw1[j]) +
                b2f((unsigned short)pw2[j])) * rc;
    float hi = (b2f((unsigned short)(pw0[j] >> 16)) + b2f((unsigned short)(pw1[j] >> 16)) +
                b2f((unsigned short)(pw2[j] >> 16))) * rc;
    ow[j] = cvtpk_bf16(lo, hi);
  }
  *(uint4*)(ob + ((size_t)(b * KPAD + gq)) * CQ + h * 64 + d0) =
      make_uint4(ow[0], ow[1], ow[2], ow[3]);
}

extern "C" void kernel_launch(void* const* d_in, const int* in_sizes, int n_in,
                              void* d_out, int out_size, void* d_ws, size_t ws_size,
                              hipStream_t stream) {
  const float* x      = (const float*)d_in[0];
  const float* cached = (const float*)d_in[1];
  const float* wqkv   = (const float*)d_in[2];
  const float* qbias  = (const float*)d_in[3];
  const float* vbias  = (const float*)d_in[4];
  const float* wproj  = (const float*)d_in[5];
  const float* bproj  = (const float*)d_in[6];
  const float* sml    = (const float*)d_in[7];
  const float* rope   = (const float*)d_in[8];
  float* out = (float*)d_out;
  char* ws = (char*)d_ws;

  double* meanpart        = (double*)(ws);                    // 524288
  double* mean            = (double*)(ws + 524288);           // 16384
  double* mse             = (double*)(ws + 540672);           // 65536
  int* idx_sel            = (int*)(ws + 606208);              // 13312 -> 619520
  // overlap zone [619520, 44135424): x_bf + wqkv_bf + qkv (dead after k_normrope)
  unsigned short* x_bf    = (unsigned short*)(ws + 619520);   // 16777216
  unsigned short* wqkv_bf = (unsigned short*)(ws + 17396736); // 6291456
  unsigned short* qkv     = (unsigned short*)(ws + 23688192); // 20447232 -> 44135424
  // attn partials (3 parts) reuse the dead x_bf/wqkv_bf/qkv region
  unsigned short* pO      = (unsigned short*)(ws + 619520);   // 20447232
  float* pl               = (float*)(ws + 21066752);          // 638976 -> 21705728
  unsigned short* wproj_bf= (unsigned short*)(ws + 44135424); // 2097152
  unsigned short* qo      = (unsigned short*)(ws + 46232576); // 6815744
  unsigned short* ko      = (unsigned short*)(ws + 53048320); // 6815744
  unsigned short* vt      = (unsigned short*)(ws + 59864064); // 6815744
  unsigned short* ob      = (unsigned short*)(ws + 66679808); // 6815744 -> 73495552

  hipLaunchKernelGGL(k_mean_part, dim3(256), dim3(256), 0, stream, x, meanpart);
  hipLaunchKernelGGL(k_mean_reduce, dim3(8), dim3(256), 0, stream, meanpart, mean);
  hipLaunchKernelGGL(k_mse_base, dim3(8192), dim3(256), 0, stream, x, cached, mean, mse,
                     out, x_bf);
  hipLaunchKernelGGL(k_topk, dim3(2 + 1024), dim3(1024), 0, stream, mse, idx_sel,
                     wqkv, wproj, wqkv_bf, wproj_bf);
  hipLaunchKernelGGL(k_gemmA, dim3(624), dim3(512), 0, stream,
                     x_bf, wqkv_bf, idx_sel, qkv);
  hipLaunchKernelGGL(k_normrope, dim3(26 * 16 * BQ), dim3(256), 0, stream,
                     qkv, idx_sel, qbias, vbias, sml, rope, qo, ko, vt);
  hipLaunchKernelGGL(k_attn, dim3(1248), dim3(256), 0, stream,
                     qo, ko, vt, sml, pO, pl);
  hipLaunchKernelGGL(k_comb, dim3(1664), dim3(256), 0, stream, pO, pl, ob);
  hipLaunchKernelGGL(k_gemmB, dim3(832), dim3(256), 0, stream,
                     ob, wproj_bf, idx_sel, out, x, bproj);
}